// Round 7
// baseline (1656.724 us; speedup 1.0000x reference)
//
#include <hip/hip_runtime.h>

#define H 128
#define NATOM 50000
#define NEDGE 800000

typedef __attribute__((ext_vector_type(8))) short short8;
typedef __attribute__((ext_vector_type(4))) float f32x4;
typedef __attribute__((ext_vector_type(4))) unsigned int uint4n;  // NT-store-compatible

#define MFMA16(a, b, c) __builtin_amdgcn_mfma_f32_16x16x32_bf16((a), (b), (c), 0, 0, 0)

__device__ __forceinline__ unsigned short f2b(float f) {
  unsigned int u = __float_as_uint(f);
  unsigned int r = (u + 0x7FFFu + ((u >> 16) & 1u)) >> 16;
  return (unsigned short)r;
}
__device__ __forceinline__ float b2f(unsigned short b) {
  return __uint_as_float(((unsigned int)b) << 16);
}

// Packed f32x2 -> bf16x2 (RNE).
#if __has_builtin(__builtin_amdgcn_cvt_pk_bf16_f32)
__device__ __forceinline__ unsigned int f2b2(float lo, float hi) {
  typedef __bf16 bf16x2 __attribute__((ext_vector_type(2)));
  bf16x2 r = __builtin_amdgcn_cvt_pk_bf16_f32(lo, hi);
  union { bf16x2 v; unsigned int u; } c;
  c.v = r;
  return c.u;
}
#else
__device__ __forceinline__ unsigned int f2b2(float lo, float hi) {
  return (unsigned int)f2b(lo) | ((unsigned int)f2b(hi) << 16);
}
#endif

// Fast silu: hardware rcp (~1e-5 rel err, far below bf16 lsb).
__device__ __forceinline__ float silu_f(float x) {
  return x * __builtin_amdgcn_rcpf(1.0f + __expf(-x));
}

// ---------------------------------------------------------------------------
// Weight repack: f32 [128][128] row-major -> bf16 MFMA B-fragment layout.
// ---------------------------------------------------------------------------
struct PackSrc { const float* p[24]; };

__global__ void repack_kernel(PackSrc ps, unsigned short* __restrict__ dst) {
  const float* src = ps.p[blockIdx.x];
  unsigned short* d = dst + (size_t)blockIdx.x * 16384;
  for (int s = threadIdx.x; s < 2048; s += 256) {
    const int ct = s >> 8;
    const int kc = (s >> 6) & 3;
    const int lane = s & 63;
    const int r0 = kc * 32 + (lane >> 4) * 8;
    const int col = ct * 16 + (lane & 15);
    uint4 u;
    u.x = f2b2(src[(r0 + 0) * H + col], src[(r0 + 1) * H + col]);
    u.y = f2b2(src[(r0 + 2) * H + col], src[(r0 + 3) * H + col]);
    u.z = f2b2(src[(r0 + 4) * H + col], src[(r0 + 5) * H + col]);
    u.w = f2b2(src[(r0 + 6) * H + col], src[(r0 + 7) * H + col]);
    *(uint4*)(d + s * 8) = u;
  }
}

__global__ void embed_kernel(const int* __restrict__ atom_num, const float* __restrict__ emb,
                             unsigned short* __restrict__ h0) {
  const int idx = blockIdx.x * 256 + threadIdx.x;  // over NATOM*64
  const int n = idx >> 6;
  const int c = (idx & 63) * 2;
  const float* src = emb + (size_t)atom_num[n] * H + c;
  *(unsigned int*)(h0 + (size_t)n * H + c) = f2b2(src[0], src[1]);
}

__global__ void zero_int_kernel(int4* __restrict__ p, int n4) {
  const int i = blockIdx.x * 256 + threadIdx.x;
  if (i < n4) p[i] = make_int4(0, 0, 0, 0);
}

// ---------------------------------------------------------------------------
// R21 CSR: u-sorted edge order. Cells: [set*NATOM + atom], set in {0,1}.
// degU counts u-endpoints (sorted positions for edges + msg rows);
// degV counts v-endpoints (random-side list). Positions are global in [0,2E).
// ---------------------------------------------------------------------------
__global__ void count_kernel(const int* __restrict__ u1, const int* __restrict__ v1,
                             const int* __restrict__ u2, const int* __restrict__ v2,
                             int* __restrict__ degU, int* __restrict__ degV) {
  const int e = blockIdx.x * 256 + threadIdx.x;
  atomicAdd(degU + u1[e], 1);
  atomicAdd(degU + NATOM + u2[e], 1);
  atomicAdd(degV + v1[e], 1);
  atomicAdd(degV + NATOM + v2[e], 1);
}

// 3-phase parallel scan (unchanged).
__global__ void scan_phase1(const int* __restrict__ deg, int* __restrict__ partials,
                            int ncells) {
  __shared__ int sh[256];
  const int t = threadIdx.x;
  const int base = blockIdx.x * 1024 + t * 4;
  int s = 0;
#pragma unroll
  for (int j = 0; j < 4; ++j) { const int i = base + j; if (i < ncells) s += deg[i]; }
  sh[t] = s;
  __syncthreads();
  for (int off = 128; off > 0; off >>= 1) {
    if (t < off) sh[t] += sh[t + off];
    __syncthreads();
  }
  if (t == 0) partials[blockIdx.x] = sh[0];
}

__global__ void scan_phase2(int* __restrict__ partials, int np) {
  __shared__ int sh[1024];
  const int t = threadIdx.x;
  const int v = t < np ? partials[t] : 0;
  sh[t] = v;
  __syncthreads();
  for (int off = 1; off < 1024; off <<= 1) {
    int x = 0;
    if (t >= off) x = sh[t - off];
    __syncthreads();
    sh[t] += x;
    __syncthreads();
  }
  if (t < np) partials[t] = sh[t] - v;  // exclusive
}

__global__ void scan_phase3(const int* __restrict__ deg, const int* __restrict__ partials,
                            int* __restrict__ start, int* __restrict__ cursor, int ncells) {
  __shared__ int sh[256];
  const int t = threadIdx.x;
  const int base = blockIdx.x * 1024 + t * 4;
  int v[4];
  int s = 0;
#pragma unroll
  for (int j = 0; j < 4; ++j) {
    const int i = base + j;
    v[j] = (i < ncells) ? deg[i] : 0;
    s += v[j];
  }
  sh[t] = s;
  __syncthreads();
  const int own = s;
  for (int off = 1; off < 256; off <<= 1) {
    int x = 0;
    if (t >= off) x = sh[t - off];
    __syncthreads();
    sh[t] += x;
    __syncthreads();
  }
  int o = partials[blockIdx.x] + sh[t] - own;
#pragma unroll
  for (int j = 0; j < 4; ++j) {
    const int i = base + j;
    if (i < ncells) {
      start[i] = o;
      cursor[i] = o;
      o += v[j];
      if (i == ncells - 1) start[ncells] = o;
    }
  }
}

// R21 fused fill: one kernel does both sides. When an edge's u lands in the
// current bucket, compute its u-sorted position su, write the packed payload
// there, AND immediately place su into the v-atom's list (sv cursor).
// Eliminates the ipos array (12.8MB write + 12.8MB gather), fillV's 51.2MB
// re-read of v1/v2, and one kernel launch. v-cursor atomics lose bucketing
// locality but curV (400KB) is L2-resident. Range-bucketed on u (npass=8).
__global__ void fill_fused_kernel(const int* __restrict__ u1, const int* __restrict__ v1,
                                  const float* __restrict__ dis1,
                                  const int* __restrict__ u2, const int* __restrict__ v2,
                                  const float* __restrict__ dis2,
                                  int* __restrict__ curU, int* __restrict__ curV,
                                  unsigned int* __restrict__ uvS,
                                  float* __restrict__ disS, int* __restrict__ listV,
                                  int npass) {
  const int apb = (NATOM + npass - 1) / npass;
  for (int p = 0; p < npass; ++p) {
    const int lo = p * apb, hi = lo + apb;
    for (int e = blockIdx.x * 256 + threadIdx.x; e < NEDGE; e += gridDim.x * 256) {
      int a = __builtin_nontemporal_load(u1 + e);
      if (a >= lo && a < hi) {
        const int v = __builtin_nontemporal_load(v1 + e);
        const int su = atomicAdd(curU + a, 1);
        uvS[su] = (unsigned int)a | ((unsigned int)v << 16);
        disS[su] = __builtin_nontemporal_load(dis1 + e);
        const int sv = atomicAdd(curV + v, 1);
        listV[sv] = su;
      }
      a = __builtin_nontemporal_load(u2 + e);
      if (a >= lo && a < hi) {
        const int v = __builtin_nontemporal_load(v2 + e);
        const int su = atomicAdd(curU + NATOM + a, 1);
        uvS[su] = (unsigned int)a | ((unsigned int)v << 16);
        disS[su] = __builtin_nontemporal_load(dis2 + e);
        const int sv = atomicAdd(curV + NATOM + v, 1);
        listV[sv] = su;
      }
    }
  }
}

// ---------------------------------------------------------------------------
// Fused edge MLP — proven R0 structure (64-row tiles, 2 blocks/CU, NT msg
// stores). R20: u-SORTED packed inputs; consecutive rows share u (avg deg 16)
// so the u-side gather is L1/L2-resident (FETCH 205->107MB measured), and msg
// rows land at sorted positions (contiguous per atom for the agg's u-half).
// ---------------------------------------------------------------------------
__global__ __launch_bounds__(256, 2)
void edge_kernel(const unsigned short* __restrict__ h,
                 const unsigned int* __restrict__ uv,
                 const float* __restrict__ dis,
                 const unsigned short* __restrict__ pWu, const unsigned short* __restrict__ pWv,
                 const unsigned short* __restrict__ pW2, const unsigned short* __restrict__ pW3,
                 const float* __restrict__ Wdis, const float* __restrict__ b1,
                 const float* __restrict__ b2, const float* __restrict__ b3,
                 unsigned short* __restrict__ msg, int eBase, int nTiles) {
  __shared__ __attribute__((aligned(16))) unsigned short sA[2][64][136];
  __shared__ __attribute__((aligned(16))) unsigned short sB[2][64][136];
  __shared__ float sDis[2][64];

  const int tid = threadIdx.x;
  const int wave = tid >> 6;
  const int lane = tid & 63;
  const int l15 = lane & 15;
  const int quad = lane >> 4;

  short8 wWu[2][4], wWv[2][4], wW2[2][4], wW3[2][4];
#pragma unroll
  for (int ct = 0; ct < 2; ++ct) {
#pragma unroll
    for (int kc = 0; kc < 4; ++kc) {
      const int off = (((wave * 2 + ct) * 4 + kc) * 64 + lane) * 8;
      wWu[ct][kc] = *(const short8*)(pWu + off);
      wWv[ct][kc] = *(const short8*)(pWv + off);
      wW2[ct][kc] = *(const short8*)(pW2 + off);
      wW3[ct][kc] = *(const short8*)(pW3 + off);
    }
  }
  float vWd[2], vb1[2], vb2[2], vb3[2];
#pragma unroll
  for (int ct = 0; ct < 2; ++ct) {
    const int col = wave * 32 + ct * 16 + l15;
    vWd[ct] = Wdis[col]; vb1[ct] = b1[col]; vb2[ct] = b2[col]; vb3[ct] = b3[col];
  }

  const int stride = gridDim.x;
  const int r0 = tid >> 4;
  const int ch = tid & 15;
  int tile = blockIdx.x;
  int cur = 0;

  if (tile < nTiles) {  // prologue: stage tile -> buf0
    const int e0 = eBase + tile * 64;
    if (tid < 64) sDis[0][tid] = dis[e0 + tid];
#pragma unroll
    for (int it = 0; it < 4; ++it) {
      const int rr = r0 + it * 16;
      const unsigned int p = uv[e0 + rr];
      *(uint4*)(&sA[0][rr][ch * 8]) = *(const uint4*)(h + (size_t)(p & 0xFFFFu) * H + ch * 8);
      *(uint4*)(&sB[0][rr][ch * 8]) = *(const uint4*)(h + (size_t)(p >> 16) * H + ch * 8);
    }
  }
  __syncthreads();

  for (; tile < nTiles; tile += stride, cur ^= 1) {
    const int nxt = cur ^ 1;
    const int tileN = tile + stride;
    const bool hasNext = tileN < nTiles;
    uint4 pfA[4], pfB[4];
    float pfD = 0.f;
    if (hasNext) {  // issue next tile's gathers (landed after b1)
      const int e0n = eBase + tileN * 64;
      if (tid < 64) pfD = dis[e0n + tid];
#pragma unroll
      for (int it = 0; it < 4; ++it) {
        const int rr = r0 + it * 16;
        const unsigned int p = uv[e0n + rr];
        pfA[it] = *(const uint4*)(h + (size_t)(p & 0xFFFFu) * H + ch * 8);
        pfB[it] = *(const uint4*)(h + (size_t)(p >> 16) * H + ch * 8);
      }
    }

    f32x4 acc[4][2];
#pragma unroll
    for (int rt = 0; rt < 4; ++rt)
#pragma unroll
      for (int ct = 0; ct < 2; ++ct) acc[rt][ct] = (f32x4){0.f, 0.f, 0.f, 0.f};

    // GEMM1: h[u]@Wu + h[v]@Wv
#pragma unroll
    for (int kc = 0; kc < 4; ++kc) {
#pragma unroll
      for (int rt = 0; rt < 4; ++rt) {
        const short8 au = *(const short8*)(&sA[cur][rt * 16 + l15][kc * 32 + quad * 8]);
        const short8 av = *(const short8*)(&sB[cur][rt * 16 + l15][kc * 32 + quad * 8]);
#pragma unroll
        for (int ct = 0; ct < 2; ++ct) {
          acc[rt][ct] = MFMA16(au, wWu[ct][kc], acc[rt][ct]);
          acc[rt][ct] = MFMA16(av, wWv[ct][kc], acc[rt][ct]);
        }
      }
    }
    __syncthreads();  // b1: all waves done reading sA/sB[cur] for GEMM1

    // ep1: t1 = silu(pre + dis*Wdis + b1) -> sA[cur]  (pairwise pk-convert)
#pragma unroll
    for (int rt = 0; rt < 4; ++rt) {
#pragma unroll
      for (int ct = 0; ct < 2; ++ct) {
        const int col = wave * 32 + ct * 16 + l15;
#pragma unroll
        for (int r = 0; r < 4; r += 2) {
          const int row = rt * 16 + quad * 4 + r;
          const float x0 = acc[rt][ct][r] + sDis[cur][row] * vWd[ct] + vb1[ct];
          const float x1 = acc[rt][ct][r + 1] + sDis[cur][row + 1] * vWd[ct] + vb1[ct];
          const unsigned int p = f2b2(silu_f(x0), silu_f(x1));
          sA[cur][row][col] = (unsigned short)p;
          sA[cur][row + 1][col] = (unsigned short)(p >> 16);
        }
      }
    }
    // land prefetched rows into the other buffer
    if (hasNext) {
      if (tid < 64) sDis[nxt][tid] = pfD;
#pragma unroll
      for (int it = 0; it < 4; ++it) {
        const int rr = r0 + it * 16;
        *(uint4*)(&sA[nxt][rr][ch * 8]) = pfA[it];
        *(uint4*)(&sB[nxt][rr][ch * 8]) = pfB[it];
      }
    }
    __syncthreads();  // b2: ep1 + prefetch writes visible

    // GEMM2: t1@W2
#pragma unroll
    for (int rt = 0; rt < 4; ++rt)
#pragma unroll
      for (int ct = 0; ct < 2; ++ct) acc[rt][ct] = (f32x4){0.f, 0.f, 0.f, 0.f};
#pragma unroll
    for (int kc = 0; kc < 4; ++kc) {
#pragma unroll
      for (int rt = 0; rt < 4; ++rt) {
        const short8 a = *(const short8*)(&sA[cur][rt * 16 + l15][kc * 32 + quad * 8]);
#pragma unroll
        for (int ct = 0; ct < 2; ++ct) acc[rt][ct] = MFMA16(a, wW2[ct][kc], acc[rt][ct]);
      }
    }
    // ep2: t2 = silu(acc + b2) -> sB[cur]
#pragma unroll
    for (int rt = 0; rt < 4; ++rt) {
#pragma unroll
      for (int ct = 0; ct < 2; ++ct) {
        const int col = wave * 32 + ct * 16 + l15;
#pragma unroll
        for (int r = 0; r < 4; r += 2) {
          const int row = rt * 16 + quad * 4 + r;
          const unsigned int p = f2b2(silu_f(acc[rt][ct][r] + vb2[ct]),
                                      silu_f(acc[rt][ct][r + 1] + vb2[ct]));
          sB[cur][row][col] = (unsigned short)p;
          sB[cur][row + 1][col] = (unsigned short)(p >> 16);
        }
      }
    }
    __syncthreads();  // b3: ep2 writes visible (GEMM2 done -> sA[cur] dead)

    // GEMM3: t2@W3
#pragma unroll
    for (int rt = 0; rt < 4; ++rt)
#pragma unroll
      for (int ct = 0; ct < 2; ++ct) acc[rt][ct] = (f32x4){0.f, 0.f, 0.f, 0.f};
#pragma unroll
    for (int kc = 0; kc < 4; ++kc) {
#pragma unroll
      for (int rt = 0; rt < 4; ++rt) {
        const short8 a = *(const short8*)(&sB[cur][rt * 16 + l15][kc * 32 + quad * 8]);
#pragma unroll
        for (int ct = 0; ct < 2; ++ct) acc[rt][ct] = MFMA16(a, wW3[ct][kc], acc[rt][ct]);
      }
    }
    // m -> sA[cur] (dead), then cooperative full-row NT stores
#pragma unroll
    for (int rt = 0; rt < 4; ++rt) {
#pragma unroll
      for (int ct = 0; ct < 2; ++ct) {
        const int col = wave * 32 + ct * 16 + l15;
#pragma unroll
        for (int r = 0; r < 4; r += 2) {
          const int row = rt * 16 + quad * 4 + r;
          const unsigned int p = f2b2(acc[rt][ct][r] + vb3[ct],
                                      acc[rt][ct][r + 1] + vb3[ct]);
          sA[cur][row][col] = (unsigned short)p;
          sA[cur][row + 1][col] = (unsigned short)(p >> 16);
        }
      }
    }
    __syncthreads();  // b4: m assembled
#pragma unroll
    for (int it = 0; it < 4; ++it) {
      const int rr = r0 + it * 16;
      __builtin_nontemporal_store(*(const uint4n*)(&sA[cur][rr][ch * 8]),
                                  (uint4n*)(msg + (size_t)(tile * 64 + rr) * H + ch * 8));
    }
  }
}

// ---------------------------------------------------------------------------
// R21 aggregate: u-half streams contiguous msg spans (regular loads, fills
// L3); v-half random gather now uses REGULAR loads too — each msg row is
// read exactly twice (once streaming, once random), and msg (204.8MB) is
// L3-sized, so the v-read can hit the line the u-stream brought in. NT kept
// only on listV (pure stream, no reuse).
// ---------------------------------------------------------------------------
__global__ __launch_bounds__(256)
void aggregate_kernel(const int* __restrict__ startU, const int* __restrict__ startV,
                      const int* __restrict__ listV,
                      const unsigned short* __restrict__ msg, int eBase, int cellBase,
                      unsigned short* __restrict__ aout) {
  const int atom = blockIdx.x * 4 + (threadIdx.x >> 6);
  const int lane = threadIdx.x & 63;
  const int su = startU[cellBase + atom] - eBase;
  const int eu = startU[cellBase + atom + 1] - eBase;
  const int sv = startV[cellBase + atom];
  const int ev = startV[cellBase + atom + 1];
  float ax = 0.f, ay = 0.f;
  const unsigned int* mp = (const unsigned int*)msg;

  // contiguous u-half: streaming, 4 rows in flight
  int p = su;
  for (; p + 3 < eu; p += 4) {
    unsigned int u[4];
#pragma unroll
    for (int j = 0; j < 4; ++j) u[j] = mp[(size_t)(p + j) * 64 + lane];
#pragma unroll
    for (int j = 0; j < 4; ++j) {
      ax += b2f((unsigned short)u[j]);
      ay += b2f((unsigned short)(u[j] >> 16));
    }
  }
  for (; p < eu; ++p) {
    const unsigned int u0 = mp[(size_t)p * 64 + lane];
    ax += b2f((unsigned short)u0);
    ay += b2f((unsigned short)(u0 >> 16));
  }

  // random v-half: 8-deep gather, regular loads (L3 reuse from u-stream)
  int i = sv;
  for (; i + 7 < ev; i += 8) {
    int r[8];
#pragma unroll
    for (int j = 0; j < 8; ++j) r[j] = __builtin_nontemporal_load(listV + i + j) - eBase;
    unsigned int u[8];
#pragma unroll
    for (int j = 0; j < 8; ++j) u[j] = mp[(size_t)r[j] * 64 + lane];
#pragma unroll
    for (int j = 0; j < 8; ++j) {
      ax += b2f((unsigned short)u[j]);
      ay += b2f((unsigned short)(u[j] >> 16));
    }
  }
  for (; i < ev; ++i) {
    const int r = __builtin_nontemporal_load(listV + i) - eBase;
    const unsigned int u0 = mp[(size_t)r * 64 + lane];
    ax += b2f((unsigned short)u0);
    ay += b2f((unsigned short)(u0 >> 16));
  }

  *(unsigned int*)(aout + (size_t)atom * H + lane * 2) = f2b2(ax, ay);
}

// ---------------------------------------------------------------------------
// Atom update: h_new = h + silu(h@Wh + a1@Wa1 + a2@Wa2 + b1)@W2 + b2
// ---------------------------------------------------------------------------
__global__ __launch_bounds__(256, 2)
void update_kernel(const unsigned short* __restrict__ hin,
                   const unsigned short* __restrict__ a1, const unsigned short* __restrict__ a2,
                   const unsigned short* __restrict__ pWh, const unsigned short* __restrict__ pWa1,
                   const unsigned short* __restrict__ pWa2, const unsigned short* __restrict__ pWo,
                   const float* __restrict__ b1, const float* __restrict__ b2,
                   unsigned short* __restrict__ hout) {
  __shared__ __attribute__((aligned(16))) unsigned short sH[64][136];
  __shared__ __attribute__((aligned(16))) unsigned short s1[64][136];
  __shared__ __attribute__((aligned(16))) unsigned short s2[64][136];

  const int tid = threadIdx.x;
  const int wave = tid >> 6;
  const int lane = tid & 63;
  const int l15 = lane & 15;
  const int quad = lane >> 4;

  short8 wWh[2][4], wW1[2][4], wW2m[2][4], wWo[2][4];
#pragma unroll
  for (int ct = 0; ct < 2; ++ct) {
#pragma unroll
    for (int kc = 0; kc < 4; ++kc) {
      const int off = (((wave * 2 + ct) * 4 + kc) * 64 + lane) * 8;
      wWh[ct][kc] = *(const short8*)(pWh + off);
      wW1[ct][kc] = *(const short8*)(pWa1 + off);
      wW2m[ct][kc] = *(const short8*)(pWa2 + off);
      wWo[ct][kc] = *(const short8*)(pWo + off);
    }
  }
  float vb1[2], vb2[2];
#pragma unroll
  for (int ct = 0; ct < 2; ++ct) {
    const int col = wave * 32 + ct * 16 + l15;
    vb1[ct] = b1[col]; vb2[ct] = b2[col];
  }

  const int n0 = blockIdx.x * 64;
#pragma unroll
  for (int it = 0; it < 4; ++it) {
    const int r = (tid >> 4) + it * 16;
    const int ch = tid & 15;
    int g = n0 + r; if (g >= NATOM) g = NATOM - 1;
    *(uint4*)(&sH[r][ch * 8]) = *(const uint4*)(hin + (size_t)g * H + ch * 8);
    *(uint4*)(&s1[r][ch * 8]) = *(const uint4*)(a1 + (size_t)g * H + ch * 8);
    *(uint4*)(&s2[r][ch * 8]) = *(const uint4*)(a2 + (size_t)g * H + ch * 8);
  }
  __syncthreads();

  f32x4 acc[4][2];
#pragma unroll
  for (int rt = 0; rt < 4; ++rt)
#pragma unroll
    for (int ct = 0; ct < 2; ++ct) acc[rt][ct] = (f32x4){0.f, 0.f, 0.f, 0.f};

#pragma unroll
  for (int kc = 0; kc < 4; ++kc) {
#pragma unroll
    for (int rt = 0; rt < 4; ++rt) {
      const short8 ah = *(const short8*)(&sH[rt * 16 + l15][kc * 32 + quad * 8]);
      const short8 aa1 = *(const short8*)(&s1[rt * 16 + l15][kc * 32 + quad * 8]);
      const short8 aa2 = *(const short8*)(&s2[rt * 16 + l15][kc * 32 + quad * 8]);
#pragma unroll
      for (int ct = 0; ct < 2; ++ct) {
        acc[rt][ct] = MFMA16(ah, wWh[ct][kc], acc[rt][ct]);
        acc[rt][ct] = MFMA16(aa1, wW1[ct][kc], acc[rt][ct]);
        acc[rt][ct] = MFMA16(aa2, wW2m[ct][kc], acc[rt][ct]);
      }
    }
  }
  __syncthreads();

#pragma unroll
  for (int rt = 0; rt < 4; ++rt) {
#pragma unroll
    for (int ct = 0; ct < 2; ++ct) {
      const int col = wave * 32 + ct * 16 + l15;
#pragma unroll
      for (int r = 0; r < 4; r += 2) {
        const int row = rt * 16 + quad * 4 + r;
        const unsigned int p = f2b2(silu_f(acc[rt][ct][r] + vb1[ct]),
                                    silu_f(acc[rt][ct][r + 1] + vb1[ct]));
        s1[row][col] = (unsigned short)p;
        s1[row + 1][col] = (unsigned short)(p >> 16);
      }
    }
  }
  __syncthreads();

#pragma unroll
  for (int rt = 0; rt < 4; ++rt)
#pragma unroll
    for (int ct = 0; ct < 2; ++ct) acc[rt][ct] = (f32x4){0.f, 0.f, 0.f, 0.f};
#pragma unroll
  for (int kc = 0; kc < 4; ++kc) {
#pragma unroll
    for (int rt = 0; rt < 4; ++rt) {
      const short8 a = *(const short8*)(&s1[rt * 16 + l15][kc * 32 + quad * 8]);
#pragma unroll
      for (int ct = 0; ct < 2; ++ct) acc[rt][ct] = MFMA16(a, wWo[ct][kc], acc[rt][ct]);
    }
  }
  __syncthreads();
#pragma unroll
  for (int rt = 0; rt < 4; ++rt) {
#pragma unroll
    for (int ct = 0; ct < 2; ++ct) {
      const int col = wave * 32 + ct * 16 + l15;
#pragma unroll
      for (int r = 0; r < 4; r += 2) {
        const int row = rt * 16 + quad * 4 + r;
        const float v0 = b2f(sH[row][col]) + acc[rt][ct][r] + vb2[ct];
        const float v1 = b2f(sH[row + 1][col]) + acc[rt][ct][r + 1] + vb2[ct];
        const unsigned int p = f2b2(v0, v1);
        s2[row][col] = (unsigned short)p;
        s2[row + 1][col] = (unsigned short)(p >> 16);
      }
    }
  }
  __syncthreads();
#pragma unroll
  for (int it = 0; it < 4; ++it) {
    const int r = (tid >> 4) + it * 16;
    const int ch = tid & 15;
    const int g = n0 + r;
    if (g < NATOM)
      *(uint4*)(hout + (size_t)g * H + ch * 8) = *(const uint4*)(&s2[r][ch * 8]);
  }
}

// ---------------------------------------------------------------------------
__global__ void out_kernel(const unsigned short* __restrict__ h,
                           const float* __restrict__ outW, const float* __restrict__ outb,
                           float* __restrict__ out) {
  const int atom = blockIdx.x * 4 + (threadIdx.x >> 6);
  const int lane = threadIdx.x & 63;
  float s0 = 0.f, s1 = 0.f, s2 = 0.f;
#pragma unroll
  for (int kk = 0; kk < 2; ++kk) {
    const int k = lane + kk * 64;
    const float hv = b2f(h[(size_t)atom * H + k]);
    s0 += hv * outW[k * 3 + 0];
    s1 += hv * outW[k * 3 + 1];
    s2 += hv * outW[k * 3 + 2];
  }
#pragma unroll
  for (int off = 32; off > 0; off >>= 1) {
    s0 += __shfl_down(s0, off);
    s1 += __shfl_down(s1, off);
    s2 += __shfl_down(s2, off);
  }
  if (lane == 0) {
    out[atom * 3 + 0] = s0 + outb[0];
    out[atom * 3 + 1] = s1 + outb[1];
    out[atom * 3 + 2] = s2 + outb[2];
  }
}

// ---------------------------------------------------------------------------
// Workspace: pw 0.79 + h0/a1/a2 38.4 + uvS 6.4 + disS 6.4 + listV 6.4 +
// startU/V 0.8 + msg 204.8 = 263.99MB < 268.44MB (256MiB). ipos removed.
// ---------------------------------------------------------------------------
extern "C" void kernel_launch(void* const* d_in, const int* in_sizes, int n_in,
                              void* d_out, int out_size, void* d_ws, size_t ws_size,
                              hipStream_t stream) {
  const int* atom_num = (const int*)d_in[0];
  const float* dis1 = (const float*)d_in[1];
  const float* dis2 = (const float*)d_in[2];
  const int* id1u = (const int*)d_in[3];
  const int* id1v = (const int*)d_in[4];
  const int* id2u = (const int*)d_in[5];
  const int* id2v = (const int*)d_in[6];
  const float* emb = (const float*)d_in[7];
  const float* Wu = (const float*)d_in[8];
  const float* Wv = (const float*)d_in[9];
  const float* Wdis = (const float*)d_in[10];
  const float* eb1 = (const float*)d_in[11];
  const float* eW2 = (const float*)d_in[12];
  const float* eb2 = (const float*)d_in[13];
  const float* eW3 = (const float*)d_in[14];
  const float* eb3 = (const float*)d_in[15];
  const float* Wh = (const float*)d_in[16];
  const float* Wa1 = (const float*)d_in[17];
  const float* Wa2 = (const float*)d_in[18];
  const float* ub1 = (const float*)d_in[19];
  const float* uW2 = (const float*)d_in[20];
  const float* ub2 = (const float*)d_in[21];
  const float* outW = (const float*)d_in[22];
  const float* outb = (const float*)d_in[23];

  auto pad = [](size_t x) { return (x + 255) & ~(size_t)255; };
  const int N2 = 2 * NATOM;                 // cells: [set][atom]
  const int nparts = (N2 + 1023) / 1024;    // = 98

  char* ws = (char*)d_ws;
  size_t off = 0;
  auto take = [&](size_t bytes) { char* p = ws + off; off += pad(bytes); return p; };
  unsigned short* pw   = (unsigned short*)take(786432);
  unsigned short* h0   = (unsigned short*)take((size_t)NATOM * H * 2);
  unsigned short* a1   = (unsigned short*)take((size_t)NATOM * H * 2);
  unsigned short* a2   = (unsigned short*)take((size_t)NATOM * H * 2);
  unsigned int* uvS    = (unsigned int*)take((size_t)2 * NEDGE * 4);  // u|v<<16
  float* disS          = (float*)take((size_t)2 * NEDGE * 4);
  int* listV           = (int*)take((size_t)2 * NEDGE * 4);
  int* startU          = (int*)take(((size_t)N2 + 1) * 4);
  int* startV          = (int*)take(((size_t)N2 + 1) * 4);
  char* ovlRegion      = ws + off;  // msg chunk, overlapped with CSR scratch
  unsigned short* msg  = (unsigned short*)ovlRegion;          // E*256B = 204.8MB
  int* degU            = (int*)ovlRegion;   // scratch dead before edge kernels
  int* degV            = degU + N2;
  int* curU            = degV + N2;
  int* curV            = curU + N2;
  int* partU           = curV + N2;
  int* partV           = partU + 1024;

  PackSrc ps;
  for (int i = 0; i < 4; ++i) {
    ps.p[i] = Wu + i * 16384;
    ps.p[4 + i] = Wv + i * 16384;
    ps.p[8 + i] = eW2 + i * 16384;
    ps.p[12 + i] = eW3 + i * 16384;
  }
  for (int j = 0; j < 2; ++j) {
    ps.p[16 + j] = Wh + j * 16384;
    ps.p[18 + j] = Wa1 + j * 16384;
    ps.p[20 + j] = Wa2 + j * 16384;
    ps.p[22 + j] = uW2 + j * 16384;
  }
  repack_kernel<<<24, 256, 0, stream>>>(ps, pw);
  embed_kernel<<<12500, 256, 0, stream>>>(atom_num, emb, h0);

  // CSR build (u-sorted positions + v-side position lists, fused fill)
  {
    const int n4 = (int)(((size_t)2 * N2 * 4 + 15) / 16);  // zero degU,degV
    zero_int_kernel<<<(n4 + 255) / 256, 256, 0, stream>>>((int4*)degU, n4);
    count_kernel<<<NEDGE / 256, 256, 0, stream>>>(id1u, id1v, id2u, id2v, degU, degV);
    scan_phase1<<<nparts, 256, 0, stream>>>(degU, partU, N2);
    scan_phase2<<<1, 1024, 0, stream>>>(partU, nparts);
    scan_phase3<<<nparts, 256, 0, stream>>>(degU, partU, startU, curU, N2);
    scan_phase1<<<nparts, 256, 0, stream>>>(degV, partV, N2);
    scan_phase2<<<1, 1024, 0, stream>>>(partV, nparts);
    scan_phase3<<<nparts, 256, 0, stream>>>(degV, partV, startV, curV, N2);
    fill_fused_kernel<<<1024, 256, 0, stream>>>(id1u, id1v, dis1, id2u, id2v, dis2,
                                                curU, curV, uvS, disS, listV, 8);
  }

  const int upd_grid = (NATOM + 63) / 64;
  const int AGG_GRID = NATOM / 4;
  const int nTiles = NEDGE / 64;  // 12500

  const unsigned short* pWu_[4] = {pw, pw + 16384, pw + 2 * 16384, pw + 3 * 16384};
  const unsigned short* pWv_[4] = {pw + 4 * 16384, pw + 5 * 16384, pw + 6 * 16384, pw + 7 * 16384};
  const unsigned short* pW2_[4] = {pw + 8 * 16384, pw + 9 * 16384, pw + 10 * 16384, pw + 11 * 16384};
  const unsigned short* pW3_[4] = {pw + 12 * 16384, pw + 13 * 16384, pw + 14 * 16384, pw + 15 * 16384};

  for (int layer = 0; layer < 2; ++layer) {
    for (int set = 0; set < 2; ++set) {
      const int blk = layer * 2 + set;
      const int eBase = set * NEDGE;      // this set's positions: [eBase, eBase+E)
      const int cellBase = set * NATOM;
      unsigned short* aout = set == 0 ? a1 : a2;
      edge_kernel<<<512, 256, 0, stream>>>(h0, uvS, disS,
          pWu_[blk], pWv_[blk], pW2_[blk], pW3_[blk],
          Wdis + blk * H, eb1 + blk * H, eb2 + blk * H, eb3 + blk * H,
          msg, eBase, nTiles);
      aggregate_kernel<<<AGG_GRID, 256, 0, stream>>>(startU, startV, listV, msg,
          eBase, cellBase, aout);
    }
    update_kernel<<<upd_grid, 256, 0, stream>>>(h0, a1, a2,
        pw + (16 + layer) * 16384, pw + (18 + layer) * 16384,
        pw + (20 + layer) * 16384, pw + (22 + layer) * 16384,
        ub1 + layer * H, ub2 + layer * H, h0);
  }

  out_kernel<<<12500, 256, 0, stream>>>(h0, outW, outb, (float*)d_out);
}

// Round 8
// 1634.845 us; speedup vs baseline: 1.0134x; 1.0134x over previous
//
#include <hip/hip_runtime.h>

#define H 128
#define NATOM 50000
#define NEDGE 800000

typedef __attribute__((ext_vector_type(8))) short short8;
typedef __attribute__((ext_vector_type(4))) float f32x4;
typedef __attribute__((ext_vector_type(4))) unsigned int uint4n;  // NT-store-compatible

#define MFMA16(a, b, c) __builtin_amdgcn_mfma_f32_16x16x32_bf16((a), (b), (c), 0, 0, 0)

__device__ __forceinline__ unsigned short f2b(float f) {
  unsigned int u = __float_as_uint(f);
  unsigned int r = (u + 0x7FFFu + ((u >> 16) & 1u)) >> 16;
  return (unsigned short)r;
}
__device__ __forceinline__ float b2f(unsigned short b) {
  return __uint_as_float(((unsigned int)b) << 16);
}

// Packed f32x2 -> bf16x2 (RNE).
#if __has_builtin(__builtin_amdgcn_cvt_pk_bf16_f32)
__device__ __forceinline__ unsigned int f2b2(float lo, float hi) {
  typedef __bf16 bf16x2 __attribute__((ext_vector_type(2)));
  bf16x2 r = __builtin_amdgcn_cvt_pk_bf16_f32(lo, hi);
  union { bf16x2 v; unsigned int u; } c;
  c.v = r;
  return c.u;
}
#else
__device__ __forceinline__ unsigned int f2b2(float lo, float hi) {
  return (unsigned int)f2b(lo) | ((unsigned int)f2b(hi) << 16);
}
#endif

// Fast silu: hardware rcp (~1e-5 rel err, far below bf16 lsb).
__device__ __forceinline__ float silu_f(float x) {
  return x * __builtin_amdgcn_rcpf(1.0f + __expf(-x));
}

// ---------------------------------------------------------------------------
// Weight repack: f32 [128][128] row-major -> bf16 MFMA B-fragment layout.
// ---------------------------------------------------------------------------
struct PackSrc { const float* p[24]; };

__global__ void repack_kernel(PackSrc ps, unsigned short* __restrict__ dst) {
  const float* src = ps.p[blockIdx.x];
  unsigned short* d = dst + (size_t)blockIdx.x * 16384;
  for (int s = threadIdx.x; s < 2048; s += 256) {
    const int ct = s >> 8;
    const int kc = (s >> 6) & 3;
    const int lane = s & 63;
    const int r0 = kc * 32 + (lane >> 4) * 8;
    const int col = ct * 16 + (lane & 15);
    uint4 u;
    u.x = f2b2(src[(r0 + 0) * H + col], src[(r0 + 1) * H + col]);
    u.y = f2b2(src[(r0 + 2) * H + col], src[(r0 + 3) * H + col]);
    u.z = f2b2(src[(r0 + 4) * H + col], src[(r0 + 5) * H + col]);
    u.w = f2b2(src[(r0 + 6) * H + col], src[(r0 + 7) * H + col]);
    *(uint4*)(d + s * 8) = u;
  }
}

__global__ void embed_kernel(const int* __restrict__ atom_num, const float* __restrict__ emb,
                             unsigned short* __restrict__ h0) {
  const int idx = blockIdx.x * 256 + threadIdx.x;  // over NATOM*64
  const int n = idx >> 6;
  const int c = (idx & 63) * 2;
  const float* src = emb + (size_t)atom_num[n] * H + c;
  *(unsigned int*)(h0 + (size_t)n * H + c) = f2b2(src[0], src[1]);
}

__global__ void zero_int_kernel(int4* __restrict__ p, int n4) {
  const int i = blockIdx.x * 256 + threadIdx.x;
  if (i < n4) p[i] = make_int4(0, 0, 0, 0);
}

// ---------------------------------------------------------------------------
// CSR: u-sorted edge order. Cells: [set*NATOM + atom], set in {0,1}.
// degU counts u-endpoints (sorted positions for edges + msg rows);
// degV counts v-endpoints (random-side list). Positions are global in [0,2E).
// ---------------------------------------------------------------------------
__global__ void count_kernel(const int* __restrict__ u1, const int* __restrict__ v1,
                             const int* __restrict__ u2, const int* __restrict__ v2,
                             int* __restrict__ degU, int* __restrict__ degV) {
  const int e = blockIdx.x * 256 + threadIdx.x;
  atomicAdd(degU + u1[e], 1);
  atomicAdd(degU + NATOM + u2[e], 1);
  atomicAdd(degV + v1[e], 1);
  atomicAdd(degV + NATOM + v2[e], 1);
}

// 3-phase parallel scan (unchanged).
__global__ void scan_phase1(const int* __restrict__ deg, int* __restrict__ partials,
                            int ncells) {
  __shared__ int sh[256];
  const int t = threadIdx.x;
  const int base = blockIdx.x * 1024 + t * 4;
  int s = 0;
#pragma unroll
  for (int j = 0; j < 4; ++j) { const int i = base + j; if (i < ncells) s += deg[i]; }
  sh[t] = s;
  __syncthreads();
  for (int off = 128; off > 0; off >>= 1) {
    if (t < off) sh[t] += sh[t + off];
    __syncthreads();
  }
  if (t == 0) partials[blockIdx.x] = sh[0];
}

__global__ void scan_phase2(int* __restrict__ partials, int np) {
  __shared__ int sh[1024];
  const int t = threadIdx.x;
  const int v = t < np ? partials[t] : 0;
  sh[t] = v;
  __syncthreads();
  for (int off = 1; off < 1024; off <<= 1) {
    int x = 0;
    if (t >= off) x = sh[t - off];
    __syncthreads();
    sh[t] += x;
    __syncthreads();
  }
  if (t < np) partials[t] = sh[t] - v;  // exclusive
}

__global__ void scan_phase3(const int* __restrict__ deg, const int* __restrict__ partials,
                            int* __restrict__ start, int* __restrict__ cursor, int ncells) {
  __shared__ int sh[256];
  const int t = threadIdx.x;
  const int base = blockIdx.x * 1024 + t * 4;
  int v[4];
  int s = 0;
#pragma unroll
  for (int j = 0; j < 4; ++j) {
    const int i = base + j;
    v[j] = (i < ncells) ? deg[i] : 0;
    s += v[j];
  }
  sh[t] = s;
  __syncthreads();
  const int own = s;
  for (int off = 1; off < 256; off <<= 1) {
    int x = 0;
    if (t >= off) x = sh[t - off];
    __syncthreads();
    sh[t] += x;
    __syncthreads();
  }
  int o = partials[blockIdx.x] + sh[t] - own;
#pragma unroll
  for (int j = 0; j < 4; ++j) {
    const int i = base + j;
    if (i < ncells) {
      start[i] = o;
      cursor[i] = o;
      o += v[j];
      if (i == ncells - 1) start[ncells] = o;
    }
  }
}

// Fused fill: when an edge's u lands in the current bucket, compute its
// u-sorted position su, write the packed payload there, AND immediately place
// su into the v-atom's list. Eliminates ipos (12.8MB write + 12.8MB gather),
// fillV's 51.2MB re-read, and one launch. Range-bucketed on u (npass=8).
__global__ void fill_fused_kernel(const int* __restrict__ u1, const int* __restrict__ v1,
                                  const float* __restrict__ dis1,
                                  const int* __restrict__ u2, const int* __restrict__ v2,
                                  const float* __restrict__ dis2,
                                  int* __restrict__ curU, int* __restrict__ curV,
                                  unsigned int* __restrict__ uvS,
                                  float* __restrict__ disS, int* __restrict__ listV,
                                  int npass) {
  const int apb = (NATOM + npass - 1) / npass;
  for (int p = 0; p < npass; ++p) {
    const int lo = p * apb, hi = lo + apb;
    for (int e = blockIdx.x * 256 + threadIdx.x; e < NEDGE; e += gridDim.x * 256) {
      int a = __builtin_nontemporal_load(u1 + e);
      if (a >= lo && a < hi) {
        const int v = __builtin_nontemporal_load(v1 + e);
        const int su = atomicAdd(curU + a, 1);
        uvS[su] = (unsigned int)a | ((unsigned int)v << 16);
        disS[su] = __builtin_nontemporal_load(dis1 + e);
        const int sv = atomicAdd(curV + v, 1);
        listV[sv] = su;
      }
      a = __builtin_nontemporal_load(u2 + e);
      if (a >= lo && a < hi) {
        const int v = __builtin_nontemporal_load(v2 + e);
        const int su = atomicAdd(curU + NATOM + a, 1);
        uvS[su] = (unsigned int)a | ((unsigned int)v << 16);
        disS[su] = __builtin_nontemporal_load(dis2 + e);
        const int sv = atomicAdd(curV + NATOM + v, 1);
        listV[sv] = su;
      }
    }
  }
}

// ---------------------------------------------------------------------------
// Fused edge MLP — proven R0 structure (64-row tiles, 2 blocks/CU, NT msg
// stores) + u-SORTED packed inputs (FETCH 205->107MB measured, dur 255->231).
// ---------------------------------------------------------------------------
__global__ __launch_bounds__(256, 2)
void edge_kernel(const unsigned short* __restrict__ h,
                 const unsigned int* __restrict__ uv,
                 const float* __restrict__ dis,
                 const unsigned short* __restrict__ pWu, const unsigned short* __restrict__ pWv,
                 const unsigned short* __restrict__ pW2, const unsigned short* __restrict__ pW3,
                 const float* __restrict__ Wdis, const float* __restrict__ b1,
                 const float* __restrict__ b2, const float* __restrict__ b3,
                 unsigned short* __restrict__ msg, int eBase, int nTiles) {
  __shared__ __attribute__((aligned(16))) unsigned short sA[2][64][136];
  __shared__ __attribute__((aligned(16))) unsigned short sB[2][64][136];
  __shared__ float sDis[2][64];

  const int tid = threadIdx.x;
  const int wave = tid >> 6;
  const int lane = tid & 63;
  const int l15 = lane & 15;
  const int quad = lane >> 4;

  short8 wWu[2][4], wWv[2][4], wW2[2][4], wW3[2][4];
#pragma unroll
  for (int ct = 0; ct < 2; ++ct) {
#pragma unroll
    for (int kc = 0; kc < 4; ++kc) {
      const int off = (((wave * 2 + ct) * 4 + kc) * 64 + lane) * 8;
      wWu[ct][kc] = *(const short8*)(pWu + off);
      wWv[ct][kc] = *(const short8*)(pWv + off);
      wW2[ct][kc] = *(const short8*)(pW2 + off);
      wW3[ct][kc] = *(const short8*)(pW3 + off);
    }
  }
  float vWd[2], vb1[2], vb2[2], vb3[2];
#pragma unroll
  for (int ct = 0; ct < 2; ++ct) {
    const int col = wave * 32 + ct * 16 + l15;
    vWd[ct] = Wdis[col]; vb1[ct] = b1[col]; vb2[ct] = b2[col]; vb3[ct] = b3[col];
  }

  const int stride = gridDim.x;
  const int r0 = tid >> 4;
  const int ch = tid & 15;
  int tile = blockIdx.x;
  int cur = 0;

  if (tile < nTiles) {  // prologue: stage tile -> buf0
    const int e0 = eBase + tile * 64;
    if (tid < 64) sDis[0][tid] = dis[e0 + tid];
#pragma unroll
    for (int it = 0; it < 4; ++it) {
      const int rr = r0 + it * 16;
      const unsigned int p = uv[e0 + rr];
      *(uint4*)(&sA[0][rr][ch * 8]) = *(const uint4*)(h + (size_t)(p & 0xFFFFu) * H + ch * 8);
      *(uint4*)(&sB[0][rr][ch * 8]) = *(const uint4*)(h + (size_t)(p >> 16) * H + ch * 8);
    }
  }
  __syncthreads();

  for (; tile < nTiles; tile += stride, cur ^= 1) {
    const int nxt = cur ^ 1;
    const int tileN = tile + stride;
    const bool hasNext = tileN < nTiles;
    uint4 pfA[4], pfB[4];
    float pfD = 0.f;
    if (hasNext) {  // issue next tile's gathers (landed after b1)
      const int e0n = eBase + tileN * 64;
      if (tid < 64) pfD = dis[e0n + tid];
#pragma unroll
      for (int it = 0; it < 4; ++it) {
        const int rr = r0 + it * 16;
        const unsigned int p = uv[e0n + rr];
        pfA[it] = *(const uint4*)(h + (size_t)(p & 0xFFFFu) * H + ch * 8);
        pfB[it] = *(const uint4*)(h + (size_t)(p >> 16) * H + ch * 8);
      }
    }

    f32x4 acc[4][2];
#pragma unroll
    for (int rt = 0; rt < 4; ++rt)
#pragma unroll
      for (int ct = 0; ct < 2; ++ct) acc[rt][ct] = (f32x4){0.f, 0.f, 0.f, 0.f};

    // GEMM1: h[u]@Wu + h[v]@Wv
#pragma unroll
    for (int kc = 0; kc < 4; ++kc) {
#pragma unroll
      for (int rt = 0; rt < 4; ++rt) {
        const short8 au = *(const short8*)(&sA[cur][rt * 16 + l15][kc * 32 + quad * 8]);
        const short8 av = *(const short8*)(&sB[cur][rt * 16 + l15][kc * 32 + quad * 8]);
#pragma unroll
        for (int ct = 0; ct < 2; ++ct) {
          acc[rt][ct] = MFMA16(au, wWu[ct][kc], acc[rt][ct]);
          acc[rt][ct] = MFMA16(av, wWv[ct][kc], acc[rt][ct]);
        }
      }
    }
    __syncthreads();  // b1: all waves done reading sA/sB[cur] for GEMM1

    // ep1: t1 = silu(pre + dis*Wdis + b1) -> sA[cur]  (pairwise pk-convert)
#pragma unroll
    for (int rt = 0; rt < 4; ++rt) {
#pragma unroll
      for (int ct = 0; ct < 2; ++ct) {
        const int col = wave * 32 + ct * 16 + l15;
#pragma unroll
        for (int r = 0; r < 4; r += 2) {
          const int row = rt * 16 + quad * 4 + r;
          const float x0 = acc[rt][ct][r] + sDis[cur][row] * vWd[ct] + vb1[ct];
          const float x1 = acc[rt][ct][r + 1] + sDis[cur][row + 1] * vWd[ct] + vb1[ct];
          const unsigned int p = f2b2(silu_f(x0), silu_f(x1));
          sA[cur][row][col] = (unsigned short)p;
          sA[cur][row + 1][col] = (unsigned short)(p >> 16);
        }
      }
    }
    // land prefetched rows into the other buffer
    if (hasNext) {
      if (tid < 64) sDis[nxt][tid] = pfD;
#pragma unroll
      for (int it = 0; it < 4; ++it) {
        const int rr = r0 + it * 16;
        *(uint4*)(&sA[nxt][rr][ch * 8]) = pfA[it];
        *(uint4*)(&sB[nxt][rr][ch * 8]) = pfB[it];
      }
    }
    __syncthreads();  // b2: ep1 + prefetch writes visible

    // GEMM2: t1@W2
#pragma unroll
    for (int rt = 0; rt < 4; ++rt)
#pragma unroll
      for (int ct = 0; ct < 2; ++ct) acc[rt][ct] = (f32x4){0.f, 0.f, 0.f, 0.f};
#pragma unroll
    for (int kc = 0; kc < 4; ++kc) {
#pragma unroll
      for (int rt = 0; rt < 4; ++rt) {
        const short8 a = *(const short8*)(&sA[cur][rt * 16 + l15][kc * 32 + quad * 8]);
#pragma unroll
        for (int ct = 0; ct < 2; ++ct) acc[rt][ct] = MFMA16(a, wW2[ct][kc], acc[rt][ct]);
      }
    }
    // ep2: t2 = silu(acc + b2) -> sB[cur]
#pragma unroll
    for (int rt = 0; rt < 4; ++rt) {
#pragma unroll
      for (int ct = 0; ct < 2; ++ct) {
        const int col = wave * 32 + ct * 16 + l15;
#pragma unroll
        for (int r = 0; r < 4; r += 2) {
          const int row = rt * 16 + quad * 4 + r;
          const unsigned int p = f2b2(silu_f(acc[rt][ct][r] + vb2[ct]),
                                      silu_f(acc[rt][ct][r + 1] + vb2[ct]));
          sB[cur][row][col] = (unsigned short)p;
          sB[cur][row + 1][col] = (unsigned short)(p >> 16);
        }
      }
    }
    __syncthreads();  // b3: ep2 writes visible (GEMM2 done -> sA[cur] dead)

    // GEMM3: t2@W3
#pragma unroll
    for (int rt = 0; rt < 4; ++rt)
#pragma unroll
      for (int ct = 0; ct < 2; ++ct) acc[rt][ct] = (f32x4){0.f, 0.f, 0.f, 0.f};
#pragma unroll
    for (int kc = 0; kc < 4; ++kc) {
#pragma unroll
      for (int rt = 0; rt < 4; ++rt) {
        const short8 a = *(const short8*)(&sB[cur][rt * 16 + l15][kc * 32 + quad * 8]);
#pragma unroll
        for (int ct = 0; ct < 2; ++ct) acc[rt][ct] = MFMA16(a, wW3[ct][kc], acc[rt][ct]);
      }
    }
    // m -> sA[cur] (dead), then cooperative full-row NT stores
#pragma unroll
    for (int rt = 0; rt < 4; ++rt) {
#pragma unroll
      for (int ct = 0; ct < 2; ++ct) {
        const int col = wave * 32 + ct * 16 + l15;
#pragma unroll
        for (int r = 0; r < 4; r += 2) {
          const int row = rt * 16 + quad * 4 + r;
          const unsigned int p = f2b2(acc[rt][ct][r] + vb3[ct],
                                      acc[rt][ct][r + 1] + vb3[ct]);
          sA[cur][row][col] = (unsigned short)p;
          sA[cur][row + 1][col] = (unsigned short)(p >> 16);
        }
      }
    }
    __syncthreads();  // b4: m assembled
#pragma unroll
    for (int it = 0; it < 4; ++it) {
      const int rr = r0 + it * 16;
      __builtin_nontemporal_store(*(const uint4n*)(&sA[cur][rr][ch * 8]),
                                  (uint4n*)(msg + (size_t)(tile * 64 + rr) * H + ch * 8));
    }
  }
}

// ---------------------------------------------------------------------------
// Aggregate (R6-proven form): u-half streams contiguous msg spans; v-half is
// the random gather with NT loads (R7's regular v-loads caused L2-allocation
// thrash: one 31.8ms pathological dispatch + net regression — reverted).
// ---------------------------------------------------------------------------
__global__ __launch_bounds__(256)
void aggregate_kernel(const int* __restrict__ startU, const int* __restrict__ startV,
                      const int* __restrict__ listV,
                      const unsigned short* __restrict__ msg, int eBase, int cellBase,
                      unsigned short* __restrict__ aout) {
  const int atom = blockIdx.x * 4 + (threadIdx.x >> 6);
  const int lane = threadIdx.x & 63;
  const int su = startU[cellBase + atom] - eBase;
  const int eu = startU[cellBase + atom + 1] - eBase;
  const int sv = startV[cellBase + atom];
  const int ev = startV[cellBase + atom + 1];
  float ax = 0.f, ay = 0.f;
  const unsigned int* mp = (const unsigned int*)msg;

  // contiguous u-half: streaming, 4 rows in flight
  int p = su;
  for (; p + 3 < eu; p += 4) {
    unsigned int u[4];
#pragma unroll
    for (int j = 0; j < 4; ++j) u[j] = mp[(size_t)(p + j) * 64 + lane];
#pragma unroll
    for (int j = 0; j < 4; ++j) {
      ax += b2f((unsigned short)u[j]);
      ay += b2f((unsigned short)(u[j] >> 16));
    }
  }
  for (; p < eu; ++p) {
    const unsigned int u0 = mp[(size_t)p * 64 + lane];
    ax += b2f((unsigned short)u0);
    ay += b2f((unsigned short)(u0 >> 16));
  }

  // random v-half: 8-deep NT gather
  int i = sv;
  for (; i + 7 < ev; i += 8) {
    int r[8];
#pragma unroll
    for (int j = 0; j < 8; ++j) r[j] = __builtin_nontemporal_load(listV + i + j) - eBase;
    unsigned int u[8];
#pragma unroll
    for (int j = 0; j < 8; ++j) u[j] = __builtin_nontemporal_load(mp + (size_t)r[j] * 64 + lane);
#pragma unroll
    for (int j = 0; j < 8; ++j) {
      ax += b2f((unsigned short)u[j]);
      ay += b2f((unsigned short)(u[j] >> 16));
    }
  }
  for (; i < ev; ++i) {
    const int r = __builtin_nontemporal_load(listV + i) - eBase;
    const unsigned int u0 = __builtin_nontemporal_load(mp + (size_t)r * 64 + lane);
    ax += b2f((unsigned short)u0);
    ay += b2f((unsigned short)(u0 >> 16));
  }

  *(unsigned int*)(aout + (size_t)atom * H + lane * 2) = f2b2(ax, ay);
}

// ---------------------------------------------------------------------------
// Atom update: h_new = h + silu(h@Wh + a1@Wa1 + a2@Wa2 + b1)@W2 + b2
// ---------------------------------------------------------------------------
__global__ __launch_bounds__(256, 2)
void update_kernel(const unsigned short* __restrict__ hin,
                   const unsigned short* __restrict__ a1, const unsigned short* __restrict__ a2,
                   const unsigned short* __restrict__ pWh, const unsigned short* __restrict__ pWa1,
                   const unsigned short* __restrict__ pWa2, const unsigned short* __restrict__ pWo,
                   const float* __restrict__ b1, const float* __restrict__ b2,
                   unsigned short* __restrict__ hout) {
  __shared__ __attribute__((aligned(16))) unsigned short sH[64][136];
  __shared__ __attribute__((aligned(16))) unsigned short s1[64][136];
  __shared__ __attribute__((aligned(16))) unsigned short s2[64][136];

  const int tid = threadIdx.x;
  const int wave = tid >> 6;
  const int lane = tid & 63;
  const int l15 = lane & 15;
  const int quad = lane >> 4;

  short8 wWh[2][4], wW1[2][4], wW2m[2][4], wWo[2][4];
#pragma unroll
  for (int ct = 0; ct < 2; ++ct) {
#pragma unroll
    for (int kc = 0; kc < 4; ++kc) {
      const int off = (((wave * 2 + ct) * 4 + kc) * 64 + lane) * 8;
      wWh[ct][kc] = *(const short8*)(pWh + off);
      wW1[ct][kc] = *(const short8*)(pWa1 + off);
      wW2m[ct][kc] = *(const short8*)(pWa2 + off);
      wWo[ct][kc] = *(const short8*)(pWo + off);
    }
  }
  float vb1[2], vb2[2];
#pragma unroll
  for (int ct = 0; ct < 2; ++ct) {
    const int col = wave * 32 + ct * 16 + l15;
    vb1[ct] = b1[col]; vb2[ct] = b2[col];
  }

  const int n0 = blockIdx.x * 64;
#pragma unroll
  for (int it = 0; it < 4; ++it) {
    const int r = (tid >> 4) + it * 16;
    const int ch = tid & 15;
    int g = n0 + r; if (g >= NATOM) g = NATOM - 1;
    *(uint4*)(&sH[r][ch * 8]) = *(const uint4*)(hin + (size_t)g * H + ch * 8);
    *(uint4*)(&s1[r][ch * 8]) = *(const uint4*)(a1 + (size_t)g * H + ch * 8);
    *(uint4*)(&s2[r][ch * 8]) = *(const uint4*)(a2 + (size_t)g * H + ch * 8);
  }
  __syncthreads();

  f32x4 acc[4][2];
#pragma unroll
  for (int rt = 0; rt < 4; ++rt)
#pragma unroll
    for (int ct = 0; ct < 2; ++ct) acc[rt][ct] = (f32x4){0.f, 0.f, 0.f, 0.f};

#pragma unroll
  for (int kc = 0; kc < 4; ++kc) {
#pragma unroll
    for (int rt = 0; rt < 4; ++rt) {
      const short8 ah = *(const short8*)(&sH[rt * 16 + l15][kc * 32 + quad * 8]);
      const short8 aa1 = *(const short8*)(&s1[rt * 16 + l15][kc * 32 + quad * 8]);
      const short8 aa2 = *(const short8*)(&s2[rt * 16 + l15][kc * 32 + quad * 8]);
#pragma unroll
      for (int ct = 0; ct < 2; ++ct) {
        acc[rt][ct] = MFMA16(ah, wWh[ct][kc], acc[rt][ct]);
        acc[rt][ct] = MFMA16(aa1, wW1[ct][kc], acc[rt][ct]);
        acc[rt][ct] = MFMA16(aa2, wW2m[ct][kc], acc[rt][ct]);
      }
    }
  }
  __syncthreads();

#pragma unroll
  for (int rt = 0; rt < 4; ++rt) {
#pragma unroll
    for (int ct = 0; ct < 2; ++ct) {
      const int col = wave * 32 + ct * 16 + l15;
#pragma unroll
      for (int r = 0; r < 4; r += 2) {
        const int row = rt * 16 + quad * 4 + r;
        const unsigned int p = f2b2(silu_f(acc[rt][ct][r] + vb1[ct]),
                                    silu_f(acc[rt][ct][r + 1] + vb1[ct]));
        s1[row][col] = (unsigned short)p;
        s1[row + 1][col] = (unsigned short)(p >> 16);
      }
    }
  }
  __syncthreads();

#pragma unroll
  for (int rt = 0; rt < 4; ++rt)
#pragma unroll
    for (int ct = 0; ct < 2; ++ct) acc[rt][ct] = (f32x4){0.f, 0.f, 0.f, 0.f};
#pragma unroll
  for (int kc = 0; kc < 4; ++kc) {
#pragma unroll
    for (int rt = 0; rt < 4; ++rt) {
      const short8 a = *(const short8*)(&s1[rt * 16 + l15][kc * 32 + quad * 8]);
#pragma unroll
      for (int ct = 0; ct < 2; ++ct) acc[rt][ct] = MFMA16(a, wWo[ct][kc], acc[rt][ct]);
    }
  }
  __syncthreads();
#pragma unroll
  for (int rt = 0; rt < 4; ++rt) {
#pragma unroll
    for (int ct = 0; ct < 2; ++ct) {
      const int col = wave * 32 + ct * 16 + l15;
#pragma unroll
      for (int r = 0; r < 4; r += 2) {
        const int row = rt * 16 + quad * 4 + r;
        const float v0 = b2f(sH[row][col]) + acc[rt][ct][r] + vb2[ct];
        const float v1 = b2f(sH[row + 1][col]) + acc[rt][ct][r + 1] + vb2[ct];
        const unsigned int p = f2b2(v0, v1);
        s2[row][col] = (unsigned short)p;
        s2[row + 1][col] = (unsigned short)(p >> 16);
      }
    }
  }
  __syncthreads();
#pragma unroll
  for (int it = 0; it < 4; ++it) {
    const int r = (tid >> 4) + it * 16;
    const int ch = tid & 15;
    const int g = n0 + r;
    if (g < NATOM)
      *(uint4*)(hout + (size_t)g * H + ch * 8) = *(const uint4*)(&s2[r][ch * 8]);
  }
}

// ---------------------------------------------------------------------------
__global__ void out_kernel(const unsigned short* __restrict__ h,
                           const float* __restrict__ outW, const float* __restrict__ outb,
                           float* __restrict__ out) {
  const int atom = blockIdx.x * 4 + (threadIdx.x >> 6);
  const int lane = threadIdx.x & 63;
  float s0 = 0.f, s1 = 0.f, s2 = 0.f;
#pragma unroll
  for (int kk = 0; kk < 2; ++kk) {
    const int k = lane + kk * 64;
    const float hv = b2f(h[(size_t)atom * H + k]);
    s0 += hv * outW[k * 3 + 0];
    s1 += hv * outW[k * 3 + 1];
    s2 += hv * outW[k * 3 + 2];
  }
#pragma unroll
  for (int off = 32; off > 0; off >>= 1) {
    s0 += __shfl_down(s0, off);
    s1 += __shfl_down(s1, off);
    s2 += __shfl_down(s2, off);
  }
  if (lane == 0) {
    out[atom * 3 + 0] = s0 + outb[0];
    out[atom * 3 + 1] = s1 + outb[1];
    out[atom * 3 + 2] = s2 + outb[2];
  }
}

// ---------------------------------------------------------------------------
// Workspace: pw 0.79 + h0/a1/a2 38.4 + uvS 6.4 + disS 6.4 + listV 6.4 +
// startU/V 0.8 + msg 204.8 = 263.99MB < 268.44MB (256MiB).
// ---------------------------------------------------------------------------
extern "C" void kernel_launch(void* const* d_in, const int* in_sizes, int n_in,
                              void* d_out, int out_size, void* d_ws, size_t ws_size,
                              hipStream_t stream) {
  const int* atom_num = (const int*)d_in[0];
  const float* dis1 = (const float*)d_in[1];
  const float* dis2 = (const float*)d_in[2];
  const int* id1u = (const int*)d_in[3];
  const int* id1v = (const int*)d_in[4];
  const int* id2u = (const int*)d_in[5];
  const int* id2v = (const int*)d_in[6];
  const float* emb = (const float*)d_in[7];
  const float* Wu = (const float*)d_in[8];
  const float* Wv = (const float*)d_in[9];
  const float* Wdis = (const float*)d_in[10];
  const float* eb1 = (const float*)d_in[11];
  const float* eW2 = (const float*)d_in[12];
  const float* eb2 = (const float*)d_in[13];
  const float* eW3 = (const float*)d_in[14];
  const float* eb3 = (const float*)d_in[15];
  const float* Wh = (const float*)d_in[16];
  const float* Wa1 = (const float*)d_in[17];
  const float* Wa2 = (const float*)d_in[18];
  const float* ub1 = (const float*)d_in[19];
  const float* uW2 = (const float*)d_in[20];
  const float* ub2 = (const float*)d_in[21];
  const float* outW = (const float*)d_in[22];
  const float* outb = (const float*)d_in[23];

  auto pad = [](size_t x) { return (x + 255) & ~(size_t)255; };
  const int N2 = 2 * NATOM;                 // cells: [set][atom]
  const int nparts = (N2 + 1023) / 1024;    // = 98

  char* ws = (char*)d_ws;
  size_t off = 0;
  auto take = [&](size_t bytes) { char* p = ws + off; off += pad(bytes); return p; };
  unsigned short* pw   = (unsigned short*)take(786432);
  unsigned short* h0   = (unsigned short*)take((size_t)NATOM * H * 2);
  unsigned short* a1   = (unsigned short*)take((size_t)NATOM * H * 2);
  unsigned short* a2   = (unsigned short*)take((size_t)NATOM * H * 2);
  unsigned int* uvS    = (unsigned int*)take((size_t)2 * NEDGE * 4);  // u|v<<16
  float* disS          = (float*)take((size_t)2 * NEDGE * 4);
  int* listV           = (int*)take((size_t)2 * NEDGE * 4);
  int* startU          = (int*)take(((size_t)N2 + 1) * 4);
  int* startV          = (int*)take(((size_t)N2 + 1) * 4);
  char* ovlRegion      = ws + off;  // msg chunk, overlapped with CSR scratch
  unsigned short* msg  = (unsigned short*)ovlRegion;          // E*256B = 204.8MB
  int* degU            = (int*)ovlRegion;   // scratch dead before edge kernels
  int* degV            = degU + N2;
  int* curU            = degV + N2;
  int* curV            = curU + N2;
  int* partU           = curV + N2;
  int* partV           = partU + 1024;

  PackSrc ps;
  for (int i = 0; i < 4; ++i) {
    ps.p[i] = Wu + i * 16384;
    ps.p[4 + i] = Wv + i * 16384;
    ps.p[8 + i] = eW2 + i * 16384;
    ps.p[12 + i] = eW3 + i * 16384;
  }
  for (int j = 0; j < 2; ++j) {
    ps.p[16 + j] = Wh + j * 16384;
    ps.p[18 + j] = Wa1 + j * 16384;
    ps.p[20 + j] = Wa2 + j * 16384;
    ps.p[22 + j] = uW2 + j * 16384;
  }
  repack_kernel<<<24, 256, 0, stream>>>(ps, pw);
  embed_kernel<<<12500, 256, 0, stream>>>(atom_num, emb, h0);

  // CSR build (u-sorted positions + v-side position lists, fused fill)
  {
    const int n4 = (int)(((size_t)2 * N2 * 4 + 15) / 16);  // zero degU,degV
    zero_int_kernel<<<(n4 + 255) / 256, 256, 0, stream>>>((int4*)degU, n4);
    count_kernel<<<NEDGE / 256, 256, 0, stream>>>(id1u, id1v, id2u, id2v, degU, degV);
    scan_phase1<<<nparts, 256, 0, stream>>>(degU, partU, N2);
    scan_phase2<<<1, 1024, 0, stream>>>(partU, nparts);
    scan_phase3<<<nparts, 256, 0, stream>>>(degU, partU, startU, curU, N2);
    scan_phase1<<<nparts, 256, 0, stream>>>(degV, partV, N2);
    scan_phase2<<<1, 1024, 0, stream>>>(partV, nparts);
    scan_phase3<<<nparts, 256, 0, stream>>>(degV, partV, startV, curV, N2);
    fill_fused_kernel<<<1024, 256, 0, stream>>>(id1u, id1v, dis1, id2u, id2v, dis2,
                                                curU, curV, uvS, disS, listV, 8);
  }

  const int upd_grid = (NATOM + 63) / 64;
  const int AGG_GRID = NATOM / 4;
  const int nTiles = NEDGE / 64;  // 12500

  const unsigned short* pWu_[4] = {pw, pw + 16384, pw + 2 * 16384, pw + 3 * 16384};
  const unsigned short* pWv_[4] = {pw + 4 * 16384, pw + 5 * 16384, pw + 6 * 16384, pw + 7 * 16384};
  const unsigned short* pW2_[4] = {pw + 8 * 16384, pw + 9 * 16384, pw + 10 * 16384, pw + 11 * 16384};
  const unsigned short* pW3_[4] = {pw + 12 * 16384, pw + 13 * 16384, pw + 14 * 16384, pw + 15 * 16384};

  for (int layer = 0; layer < 2; ++layer) {
    for (int set = 0; set < 2; ++set) {
      const int blk = layer * 2 + set;
      const int eBase = set * NEDGE;      // this set's positions: [eBase, eBase+E)
      const int cellBase = set * NATOM;
      unsigned short* aout = set == 0 ? a1 : a2;
      edge_kernel<<<512, 256, 0, stream>>>(h0, uvS, disS,
          pWu_[blk], pWv_[blk], pW2_[blk], pW3_[blk],
          Wdis + blk * H, eb1 + blk * H, eb2 + blk * H, eb3 + blk * H,
          msg, eBase, nTiles);
      aggregate_kernel<<<AGG_GRID, 256, 0, stream>>>(startU, startV, listV, msg,
          eBase, cellBase, aout);
    }
    update_kernel<<<upd_grid, 256, 0, stream>>>(h0, a1, a2,
        pw + (16 + layer) * 16384, pw + (18 + layer) * 16384,
        pw + (20 + layer) * 16384, pw + (22 + layer) * 16384,
        ub1 + layer * H, ub2 + layer * H, h0);
  }

  out_kernel<<<12500, 256, 0, stream>>>(h0, outW, outb, (float*)d_out);
}

// Round 10
// 1626.160 us; speedup vs baseline: 1.0188x; 1.0053x over previous
//
#include <hip/hip_runtime.h>

#define H 128
#define NATOM 50000
#define NEDGE 800000
#define CE (NEDGE / 2)          // msg chunk: 400000 edges = 102.4MB (nc=2)

typedef __attribute__((ext_vector_type(8))) short short8;
typedef __attribute__((ext_vector_type(4))) float f32x4;
typedef __attribute__((ext_vector_type(4))) unsigned int uint4n;  // NT-store-compatible

#define MFMA16(a, b, c) __builtin_amdgcn_mfma_f32_16x16x32_bf16((a), (b), (c), 0, 0, 0)

__device__ __forceinline__ unsigned short f2b(float f) {
  unsigned int u = __float_as_uint(f);
  unsigned int r = (u + 0x7FFFu + ((u >> 16) & 1u)) >> 16;
  return (unsigned short)r;
}
__device__ __forceinline__ float b2f(unsigned short b) {
  return __uint_as_float(((unsigned int)b) << 16);
}

#if __has_builtin(__builtin_amdgcn_cvt_pk_bf16_f32)
__device__ __forceinline__ unsigned int f2b2(float lo, float hi) {
  typedef __bf16 bf16x2 __attribute__((ext_vector_type(2)));
  bf16x2 r = __builtin_amdgcn_cvt_pk_bf16_f32(lo, hi);
  union { bf16x2 v; unsigned int u; } c;
  c.v = r;
  return c.u;
}
#else
__device__ __forceinline__ unsigned int f2b2(float lo, float hi) {
  return (unsigned int)f2b(lo) | ((unsigned int)f2b(hi) << 16);
}
#endif

__device__ __forceinline__ float silu_f(float x) {
  return x * __builtin_amdgcn_rcpf(1.0f + __expf(-x));
}

// ---------------------------------------------------------------------------
// Weight repack: f32 [128][128] row-major -> bf16 MFMA B-fragment layout.
// ---------------------------------------------------------------------------
struct PackSrc { const float* p[24]; };

__global__ void repack_kernel(PackSrc ps, unsigned short* __restrict__ dst) {
  const float* src = ps.p[blockIdx.x];
  unsigned short* d = dst + (size_t)blockIdx.x * 16384;
  for (int s = threadIdx.x; s < 2048; s += 256) {
    const int ct = s >> 8;
    const int kc = (s >> 6) & 3;
    const int lane = s & 63;
    const int r0 = kc * 32 + (lane >> 4) * 8;
    const int col = ct * 16 + (lane & 15);
    uint4 u;
    u.x = f2b2(src[(r0 + 0) * H + col], src[(r0 + 1) * H + col]);
    u.y = f2b2(src[(r0 + 2) * H + col], src[(r0 + 3) * H + col]);
    u.z = f2b2(src[(r0 + 4) * H + col], src[(r0 + 5) * H + col]);
    u.w = f2b2(src[(r0 + 6) * H + col], src[(r0 + 7) * H + col]);
    *(uint4*)(d + s * 8) = u;
  }
}

__global__ void embed_kernel(const int* __restrict__ atom_num, const float* __restrict__ emb,
                             unsigned short* __restrict__ h0) {
  const int idx = blockIdx.x * 256 + threadIdx.x;
  const int n = idx >> 6;
  const int c = (idx & 63) * 2;
  const float* src = emb + (size_t)atom_num[n] * H + c;
  *(unsigned int*)(h0 + (size_t)n * H + c) = f2b2(src[0], src[1]);
}

__global__ void zero_int_kernel(int4* __restrict__ p, int n4) {
  const int i = blockIdx.x * 256 + threadIdx.x;
  if (i < n4) p[i] = make_int4(0, 0, 0, 0);
}

// ---------------------------------------------------------------------------
// CSR: u-sorted edge order. Cells: [set*NATOM + atom]. Positions in [0,2E).
// ---------------------------------------------------------------------------
__global__ void count_kernel(const int* __restrict__ u1, const int* __restrict__ v1,
                             const int* __restrict__ u2, const int* __restrict__ v2,
                             int* __restrict__ degU, int* __restrict__ degV) {
  const int e = blockIdx.x * 256 + threadIdx.x;
  atomicAdd(degU + u1[e], 1);
  atomicAdd(degU + NATOM + u2[e], 1);
  atomicAdd(degV + v1[e], 1);
  atomicAdd(degV + NATOM + v2[e], 1);
}

__global__ void scan_phase1(const int* __restrict__ deg, int* __restrict__ partials,
                            int ncells) {
  __shared__ int sh[256];
  const int t = threadIdx.x;
  const int base = blockIdx.x * 1024 + t * 4;
  int s = 0;
#pragma unroll
  for (int j = 0; j < 4; ++j) { const int i = base + j; if (i < ncells) s += deg[i]; }
  sh[t] = s;
  __syncthreads();
  for (int off = 128; off > 0; off >>= 1) {
    if (t < off) sh[t] += sh[t + off];
    __syncthreads();
  }
  if (t == 0) partials[blockIdx.x] = sh[0];
}

__global__ void scan_phase2(int* __restrict__ partials, int np) {
  __shared__ int sh[1024];
  const int t = threadIdx.x;
  const int v = t < np ? partials[t] : 0;
  sh[t] = v;
  __syncthreads();
  for (int off = 1; off < 1024; off <<= 1) {
    int x = 0;
    if (t >= off) x = sh[t - off];
    __syncthreads();
    sh[t] += x;
    __syncthreads();
  }
  if (t < np) partials[t] = sh[t] - v;  // exclusive
}

__global__ void scan_phase3(const int* __restrict__ deg, const int* __restrict__ partials,
                            int* __restrict__ start, int* __restrict__ cursor, int ncells) {
  __shared__ int sh[256];
  const int t = threadIdx.x;
  const int base = blockIdx.x * 1024 + t * 4;
  int v[4];
  int s = 0;
#pragma unroll
  for (int j = 0; j < 4; ++j) {
    const int i = base + j;
    v[j] = (i < ncells) ? deg[i] : 0;
    s += v[j];
  }
  sh[t] = s;
  __syncthreads();
  const int own = s;
  for (int off = 1; off < 256; off <<= 1) {
    int x = 0;
    if (t >= off) x = sh[t - off];
    __syncthreads();
    sh[t] += x;
    __syncthreads();
  }
  int o = partials[blockIdx.x] + sh[t] - own;
#pragma unroll
  for (int j = 0; j < 4; ++j) {
    const int i = base + j;
    if (i < ncells) {
      start[i] = o;
      cursor[i] = o;
      o += v[j];
      if (i == ncells - 1) start[ncells] = o;
    }
  }
}

// Fused fill (R8-proven): u-sorted placement + v-list in one pass.
__global__ void fill_fused_kernel(const int* __restrict__ u1, const int* __restrict__ v1,
                                  const float* __restrict__ dis1,
                                  const int* __restrict__ u2, const int* __restrict__ v2,
                                  const float* __restrict__ dis2,
                                  int* __restrict__ curU, int* __restrict__ curV,
                                  unsigned int* __restrict__ uvS,
                                  float* __restrict__ disS, int* __restrict__ listV,
                                  int npass) {
  const int apb = (NATOM + npass - 1) / npass;
  for (int p = 0; p < npass; ++p) {
    const int lo = p * apb, hi = lo + apb;
    for (int e = blockIdx.x * 256 + threadIdx.x; e < NEDGE; e += gridDim.x * 256) {
      int a = __builtin_nontemporal_load(u1 + e);
      if (a >= lo && a < hi) {
        const int v = __builtin_nontemporal_load(v1 + e);
        const int su = atomicAdd(curU + a, 1);
        uvS[su] = (unsigned int)a | ((unsigned int)v << 16);
        disS[su] = __builtin_nontemporal_load(dis1 + e);
        const int sv = atomicAdd(curV + v, 1);
        listV[sv] = su;
      }
      a = __builtin_nontemporal_load(u2 + e);
      if (a >= lo && a < hi) {
        const int v = __builtin_nontemporal_load(v2 + e);
        const int su = atomicAdd(curU + NATOM + a, 1);
        uvS[su] = (unsigned int)a | ((unsigned int)v << 16);
        disS[su] = __builtin_nontemporal_load(dis2 + e);
        const int sv = atomicAdd(curV + NATOM + v, 1);
        listV[sv] = su;
      }
    }
  }
}

// ---------------------------------------------------------------------------
// R22 precompute: hu = h@Wu, hv = h@Wv per atom (bf16 out). Replaces the
// edge kernel's GEMM1 (16x redundant per-edge recompute of per-atom GEMMs).
// Structure cloned from update_kernel's proven GEMM pattern.
// ---------------------------------------------------------------------------
__global__ __launch_bounds__(256, 2)
void pre_kernel(const unsigned short* __restrict__ h,
                const unsigned short* __restrict__ pWu, const unsigned short* __restrict__ pWv,
                unsigned short* __restrict__ hu, unsigned short* __restrict__ hv) {
  __shared__ __attribute__((aligned(16))) unsigned short sH[64][136];
  __shared__ __attribute__((aligned(16))) unsigned short sO[64][136];

  const int tid = threadIdx.x;
  const int wave = tid >> 6;
  const int lane = tid & 63;
  const int l15 = lane & 15;
  const int quad = lane >> 4;
  const int r0 = tid >> 4;
  const int ch = tid & 15;

  short8 wU[2][4], wV[2][4];
#pragma unroll
  for (int ct = 0; ct < 2; ++ct) {
#pragma unroll
    for (int kc = 0; kc < 4; ++kc) {
      const int off = (((wave * 2 + ct) * 4 + kc) * 64 + lane) * 8;
      wU[ct][kc] = *(const short8*)(pWu + off);
      wV[ct][kc] = *(const short8*)(pWv + off);
    }
  }

  const int n0 = blockIdx.x * 64;
#pragma unroll
  for (int it = 0; it < 4; ++it) {
    const int r = r0 + it * 16;
    int g = n0 + r; if (g >= NATOM) g = NATOM - 1;
    *(uint4*)(&sH[r][ch * 8]) = *(const uint4*)(h + (size_t)g * H + ch * 8);
  }
  __syncthreads();

  f32x4 au[4][2], av[4][2];
#pragma unroll
  for (int rt = 0; rt < 4; ++rt)
#pragma unroll
    for (int ct = 0; ct < 2; ++ct) {
      au[rt][ct] = (f32x4){0.f, 0.f, 0.f, 0.f};
      av[rt][ct] = (f32x4){0.f, 0.f, 0.f, 0.f};
    }
#pragma unroll
  for (int kc = 0; kc < 4; ++kc) {
#pragma unroll
    for (int rt = 0; rt < 4; ++rt) {
      const short8 a = *(const short8*)(&sH[rt * 16 + l15][kc * 32 + quad * 8]);
#pragma unroll
      for (int ct = 0; ct < 2; ++ct) {
        au[rt][ct] = MFMA16(a, wU[ct][kc], au[rt][ct]);
        av[rt][ct] = MFMA16(a, wV[ct][kc], av[rt][ct]);
      }
    }
  }
  __syncthreads();

  // hu out
#pragma unroll
  for (int rt = 0; rt < 4; ++rt) {
#pragma unroll
    for (int ct = 0; ct < 2; ++ct) {
      const int col = wave * 32 + ct * 16 + l15;
#pragma unroll
      for (int r = 0; r < 4; r += 2) {
        const int row = rt * 16 + quad * 4 + r;
        const unsigned int p = f2b2(au[rt][ct][r], au[rt][ct][r + 1]);
        sO[row][col] = (unsigned short)p;
        sO[row + 1][col] = (unsigned short)(p >> 16);
      }
    }
  }
  __syncthreads();
#pragma unroll
  for (int it = 0; it < 4; ++it) {
    const int r = r0 + it * 16;
    const int g = n0 + r;
    if (g < NATOM)
      *(uint4*)(hu + (size_t)g * H + ch * 8) = *(const uint4*)(&sO[r][ch * 8]);
  }
  __syncthreads();

  // hv out
#pragma unroll
  for (int rt = 0; rt < 4; ++rt) {
#pragma unroll
    for (int ct = 0; ct < 2; ++ct) {
      const int col = wave * 32 + ct * 16 + l15;
#pragma unroll
      for (int r = 0; r < 4; r += 2) {
        const int row = rt * 16 + quad * 4 + r;
        const unsigned int p = f2b2(av[rt][ct][r], av[rt][ct][r + 1]);
        sO[row][col] = (unsigned short)p;
        sO[row + 1][col] = (unsigned short)(p >> 16);
      }
    }
  }
  __syncthreads();
#pragma unroll
  for (int it = 0; it < 4; ++it) {
    const int r = r0 + it * 16;
    const int g = n0 + r;
    if (g < NATOM)
      *(uint4*)(hv + (size_t)g * H + ch * 8) = *(const uint4*)(&sO[r][ch * 8]);
  }
}

// ---------------------------------------------------------------------------
// R22 edge: GEMM1 replaced by register-level gather-add of precomputed
// hu[u]+hv[v] (ep0: thread-local, no LDS staging, no barrier before it).
// MFMA/wave/tile 128->64; LDS 70->34.8KB -> 3 blocks/CU; wWu/wWv regs freed.
// Same 4-barrier skeleton, NT msg stores, register prefetch of next tile.
// ---------------------------------------------------------------------------
__global__ __launch_bounds__(256, 3)
void edge_kernel(const unsigned short* __restrict__ hu,
                 const unsigned short* __restrict__ hv,
                 const unsigned int* __restrict__ uv,
                 const float* __restrict__ dis,
                 const unsigned short* __restrict__ pW2, const unsigned short* __restrict__ pW3,
                 const float* __restrict__ Wdis, const float* __restrict__ bb1,
                 const float* __restrict__ bb2, const float* __restrict__ bb3,
                 unsigned short* __restrict__ msg, int eBase, int nTiles) {
  __shared__ __attribute__((aligned(16))) unsigned short sA[64][136];
  __shared__ __attribute__((aligned(16))) unsigned short sB[64][136];

  const int tid = threadIdx.x;
  const int wave = tid >> 6;
  const int lane = tid & 63;
  const int l15 = lane & 15;
  const int quad = lane >> 4;
  const int r0 = tid >> 4;
  const int ch = tid & 15;

  short8 wW2[2][4], wW3[2][4];
#pragma unroll
  for (int ct = 0; ct < 2; ++ct) {
#pragma unroll
    for (int kc = 0; kc < 4; ++kc) {
      const int off = (((wave * 2 + ct) * 4 + kc) * 64 + lane) * 8;
      wW2[ct][kc] = *(const short8*)(pW2 + off);
      wW3[ct][kc] = *(const short8*)(pW3 + off);
    }
  }
  // ep0 constants (cols ch*8..ch*8+7)
  float wd8[8], b18[8];
#pragma unroll
  for (int k = 0; k < 8; ++k) { wd8[k] = Wdis[ch * 8 + k]; b18[k] = bb1[ch * 8 + k]; }
  // ep2/m constants (acc layout cols)
  float vb2[2], vb3[2];
#pragma unroll
  for (int ct = 0; ct < 2; ++ct) {
    const int col = wave * 32 + ct * 16 + l15;
    vb2[ct] = bb2[col]; vb3[ct] = bb3[col];
  }

  const int stride = gridDim.x;
  int tile = blockIdx.x;

  uint4 pfU[4], pfV[4];
  float pfD[4];
  if (tile < nTiles) {
    const int e0 = eBase + tile * 64;
#pragma unroll
    for (int it = 0; it < 4; ++it) {
      const int e = e0 + r0 + it * 16;
      const unsigned int p = uv[e];
      pfU[it] = *(const uint4*)(hu + (size_t)(p & 0xFFFFu) * H + ch * 8);
      pfV[it] = *(const uint4*)(hv + (size_t)(p >> 16) * H + ch * 8);
      pfD[it] = dis[e];
    }
  }

  for (; tile < nTiles; tile += stride) {
    // ep0: t1 = silu(hu[u] + hv[v] + dis*wd + b1) -> sA (thread-local rows)
#pragma unroll
    for (int it = 0; it < 4; ++it) {
      const int rr = r0 + it * 16;
      const float d = pfD[it];
      const unsigned int ua[4] = {pfU[it].x, pfU[it].y, pfU[it].z, pfU[it].w};
      const unsigned int va[4] = {pfV[it].x, pfV[it].y, pfV[it].z, pfV[it].w};
#pragma unroll
      for (int j = 0; j < 4; ++j) {
        const float x0 = b2f((unsigned short)ua[j]) + b2f((unsigned short)va[j]) +
                         d * wd8[2 * j] + b18[2 * j];
        const float x1 = b2f((unsigned short)(ua[j] >> 16)) + b2f((unsigned short)(va[j] >> 16)) +
                         d * wd8[2 * j + 1] + b18[2 * j + 1];
        *(unsigned int*)(&sA[rr][ch * 8 + 2 * j]) = f2b2(silu_f(x0), silu_f(x1));
      }
    }
    // issue next tile's gathers (fly during GEMM2/GEMM3)
    const int tileN = tile + stride;
    if (tileN < nTiles) {
      const int e0n = eBase + tileN * 64;
#pragma unroll
      for (int it = 0; it < 4; ++it) {
        const int e = e0n + r0 + it * 16;
        const unsigned int p = uv[e];
        pfU[it] = *(const uint4*)(hu + (size_t)(p & 0xFFFFu) * H + ch * 8);
        pfV[it] = *(const uint4*)(hv + (size_t)(p >> 16) * H + ch * 8);
        pfD[it] = dis[e];
      }
    }
    __syncthreads();  // b1: t1 visible

    // GEMM2: t1@W2
    f32x4 acc[4][2];
#pragma unroll
    for (int rt = 0; rt < 4; ++rt)
#pragma unroll
      for (int ct = 0; ct < 2; ++ct) acc[rt][ct] = (f32x4){0.f, 0.f, 0.f, 0.f};
#pragma unroll
    for (int kc = 0; kc < 4; ++kc) {
#pragma unroll
      for (int rt = 0; rt < 4; ++rt) {
        const short8 a = *(const short8*)(&sA[rt * 16 + l15][kc * 32 + quad * 8]);
#pragma unroll
        for (int ct = 0; ct < 2; ++ct) acc[rt][ct] = MFMA16(a, wW2[ct][kc], acc[rt][ct]);
      }
    }
    // ep2: t2 = silu(acc + b2) -> sB
#pragma unroll
    for (int rt = 0; rt < 4; ++rt) {
#pragma unroll
      for (int ct = 0; ct < 2; ++ct) {
        const int col = wave * 32 + ct * 16 + l15;
#pragma unroll
        for (int r = 0; r < 4; r += 2) {
          const int row = rt * 16 + quad * 4 + r;
          const unsigned int p = f2b2(silu_f(acc[rt][ct][r] + vb2[ct]),
                                      silu_f(acc[rt][ct][r + 1] + vb2[ct]));
          sB[row][col] = (unsigned short)p;
          sB[row + 1][col] = (unsigned short)(p >> 16);
        }
      }
    }
    __syncthreads();  // b2: t2 visible; all GEMM2 reads of sA done

    // GEMM3: t2@W3
#pragma unroll
    for (int rt = 0; rt < 4; ++rt)
#pragma unroll
      for (int ct = 0; ct < 2; ++ct) acc[rt][ct] = (f32x4){0.f, 0.f, 0.f, 0.f};
#pragma unroll
    for (int kc = 0; kc < 4; ++kc) {
#pragma unroll
      for (int rt = 0; rt < 4; ++rt) {
        const short8 a = *(const short8*)(&sB[rt * 16 + l15][kc * 32 + quad * 8]);
#pragma unroll
        for (int ct = 0; ct < 2; ++ct) acc[rt][ct] = MFMA16(a, wW3[ct][kc], acc[rt][ct]);
      }
    }
    // m -> sA (safe: sA reads done at b2)
#pragma unroll
    for (int rt = 0; rt < 4; ++rt) {
#pragma unroll
      for (int ct = 0; ct < 2; ++ct) {
        const int col = wave * 32 + ct * 16 + l15;
#pragma unroll
        for (int r = 0; r < 4; r += 2) {
          const int row = rt * 16 + quad * 4 + r;
          const unsigned int p = f2b2(acc[rt][ct][r] + vb3[ct],
                                      acc[rt][ct][r + 1] + vb3[ct]);
          sA[row][col] = (unsigned short)p;
          sA[row + 1][col] = (unsigned short)(p >> 16);
        }
      }
    }
    __syncthreads();  // b3: m assembled
#pragma unroll
    for (int it = 0; it < 4; ++it) {
      const int rr = r0 + it * 16;
      __builtin_nontemporal_store(*(const uint4n*)(&sA[rr][ch * 8]),
                                  (uint4n*)(msg + (size_t)(tile * 64 + rr) * H + ch * 8));
    }
    __syncthreads();  // b4: stores of sA done before next ep0 overwrites
  }
}

// ---------------------------------------------------------------------------
// R22 aggregate (chunked, R0's af32 partial pattern): u-half streams the
// clipped contiguous span; v-half NT-gathers entries whose position falls in
// this chunk. isFirst inits, isLast finalizes to bf16.
// ---------------------------------------------------------------------------
__global__ __launch_bounds__(256)
void aggregate_kernel(const int* __restrict__ startU, const int* __restrict__ startV,
                      const int* __restrict__ listV,
                      const unsigned short* __restrict__ msg, int chunkBase, int cellBase,
                      float* __restrict__ af32, unsigned short* __restrict__ aout,
                      int isFirst, int isLast) {
  const int atom = blockIdx.x * 4 + (threadIdx.x >> 6);
  const int lane = threadIdx.x & 63;
  float ax = 0.f, ay = 0.f;
  if (!isFirst) {
    const float2 p = *(const float2*)(af32 + (size_t)atom * H + lane * 2);
    ax = p.x; ay = p.y;
  }
  const unsigned int* mp = (const unsigned int*)msg;

  // u-half: contiguous span clipped to this chunk
  const int gsu = startU[cellBase + atom];
  const int geu = startU[cellBase + atom + 1];
  int lo = gsu > chunkBase ? gsu : chunkBase;
  int hi = geu < chunkBase + CE ? geu : chunkBase + CE;
  int p = lo - chunkBase;
  const int pe = hi - chunkBase;
  for (; p + 3 < pe; p += 4) {
    unsigned int u[4];
#pragma unroll
    for (int j = 0; j < 4; ++j) u[j] = mp[(size_t)(p + j) * 64 + lane];
#pragma unroll
    for (int j = 0; j < 4; ++j) {
      ax += b2f((unsigned short)u[j]);
      ay += b2f((unsigned short)(u[j] >> 16));
    }
  }
  for (; p < pe; ++p) {
    const unsigned int u0 = mp[(size_t)p * 64 + lane];
    ax += b2f((unsigned short)u0);
    ay += b2f((unsigned short)(u0 >> 16));
  }

  // v-half: 8-deep NT gather, chunk-membership predicated
  const int sv = startV[cellBase + atom];
  const int ev = startV[cellBase + atom + 1];
  int i = sv;
  for (; i + 7 < ev; i += 8) {
    unsigned int d[8];
#pragma unroll
    for (int j = 0; j < 8; ++j)
      d[j] = (unsigned int)(__builtin_nontemporal_load(listV + i + j) - chunkBase);
    unsigned int u[8];
#pragma unroll
    for (int j = 0; j < 8; ++j) {
      u[j] = 0u;
      if (d[j] < (unsigned int)CE)
        u[j] = __builtin_nontemporal_load(mp + (size_t)d[j] * 64 + lane);
    }
#pragma unroll
    for (int j = 0; j < 8; ++j) {
      ax += b2f((unsigned short)u[j]);
      ay += b2f((unsigned short)(u[j] >> 16));
    }
  }
  for (; i < ev; ++i) {
    const unsigned int d = (unsigned int)(__builtin_nontemporal_load(listV + i) - chunkBase);
    if (d < (unsigned int)CE) {
      const unsigned int u0 = __builtin_nontemporal_load(mp + (size_t)d * 64 + lane);
      ax += b2f((unsigned short)u0);
      ay += b2f((unsigned short)(u0 >> 16));
    }
  }

  if (isLast) {
    *(unsigned int*)(aout + (size_t)atom * H + lane * 2) = f2b2(ax, ay);
  } else {
    *(float2*)(af32 + (size_t)atom * H + lane * 2) = make_float2(ax, ay);
  }
}

// ---------------------------------------------------------------------------
// Atom update: h_new = h + silu(h@Wh + a1@Wa1 + a2@Wa2 + b1)@W2 + b2
// ---------------------------------------------------------------------------
__global__ __launch_bounds__(256, 2)
void update_kernel(const unsigned short* __restrict__ hin,
                   const unsigned short* __restrict__ a1, const unsigned short* __restrict__ a2,
                   const unsigned short* __restrict__ pWh, const unsigned short* __restrict__ pWa1,
                   const unsigned short* __restrict__ pWa2, const unsigned short* __restrict__ pWo,
                   const float* __restrict__ b1, const float* __restrict__ b2,
                   unsigned short* __restrict__ hout) {
  __shared__ __attribute__((aligned(16))) unsigned short sH[64][136];
  __shared__ __attribute__((aligned(16))) unsigned short s1[64][136];
  __shared__ __attribute__((aligned(16))) unsigned short s2[64][136];

  const int tid = threadIdx.x;
  const int wave = tid >> 6;
  const int lane = tid & 63;
  const int l15 = lane & 15;
  const int quad = lane >> 4;

  short8 wWh[2][4], wW1[2][4], wW2m[2][4], wWo[2][4];
#pragma unroll
  for (int ct = 0; ct < 2; ++ct) {
#pragma unroll
    for (int kc = 0; kc < 4; ++kc) {
      const int off = (((wave * 2 + ct) * 4 + kc) * 64 + lane) * 8;
      wWh[ct][kc] = *(const short8*)(pWh + off);
      wW1[ct][kc] = *(const short8*)(pWa1 + off);
      wW2m[ct][kc] = *(const short8*)(pWa2 + off);
      wWo[ct][kc] = *(const short8*)(pWo + off);
    }
  }
  float vb1[2], vb2[2];
#pragma unroll
  for (int ct = 0; ct < 2; ++ct) {
    const int col = wave * 32 + ct * 16 + l15;
    vb1[ct] = b1[col]; vb2[ct] = b2[col];
  }

  const int n0 = blockIdx.x * 64;
#pragma unroll
  for (int it = 0; it < 4; ++it) {
    const int r = (tid >> 4) + it * 16;
    const int ch = tid & 15;
    int g = n0 + r; if (g >= NATOM) g = NATOM - 1;
    *(uint4*)(&sH[r][ch * 8]) = *(const uint4*)(hin + (size_t)g * H + ch * 8);
    *(uint4*)(&s1[r][ch * 8]) = *(const uint4*)(a1 + (size_t)g * H + ch * 8);
    *(uint4*)(&s2[r][ch * 8]) = *(const uint4*)(a2 + (size_t)g * H + ch * 8);
  }
  __syncthreads();

  f32x4 acc[4][2];
#pragma unroll
  for (int rt = 0; rt < 4; ++rt)
#pragma unroll
    for (int ct = 0; ct < 2; ++ct) acc[rt][ct] = (f32x4){0.f, 0.f, 0.f, 0.f};

#pragma unroll
  for (int kc = 0; kc < 4; ++kc) {
#pragma unroll
    for (int rt = 0; rt < 4; ++rt) {
      const short8 ah = *(const short8*)(&sH[rt * 16 + l15][kc * 32 + quad * 8]);
      const short8 aa1 = *(const short8*)(&s1[rt * 16 + l15][kc * 32 + quad * 8]);
      const short8 aa2 = *(const short8*)(&s2[rt * 16 + l15][kc * 32 + quad * 8]);
#pragma unroll
      for (int ct = 0; ct < 2; ++ct) {
        acc[rt][ct] = MFMA16(ah, wWh[ct][kc], acc[rt][ct]);
        acc[rt][ct] = MFMA16(aa1, wW1[ct][kc], acc[rt][ct]);
        acc[rt][ct] = MFMA16(aa2, wW2m[ct][kc], acc[rt][ct]);
      }
    }
  }
  __syncthreads();

#pragma unroll
  for (int rt = 0; rt < 4; ++rt) {
#pragma unroll
    for (int ct = 0; ct < 2; ++ct) {
      const int col = wave * 32 + ct * 16 + l15;
#pragma unroll
      for (int r = 0; r < 4; r += 2) {
        const int row = rt * 16 + quad * 4 + r;
        const unsigned int p = f2b2(silu_f(acc[rt][ct][r] + vb1[ct]),
                                    silu_f(acc[rt][ct][r + 1] + vb1[ct]));
        s1[row][col] = (unsigned short)p;
        s1[row + 1][col] = (unsigned short)(p >> 16);
      }
    }
  }
  __syncthreads();

#pragma unroll
  for (int rt = 0; rt < 4; ++rt)
#pragma unroll
    for (int ct = 0; ct < 2; ++ct) acc[rt][ct] = (f32x4){0.f, 0.f, 0.f, 0.f};
#pragma unroll
  for (int kc = 0; kc < 4; ++kc) {
#pragma unroll
    for (int rt = 0; rt < 4; ++rt) {
      const short8 a = *(const short8*)(&s1[rt * 16 + l15][kc * 32 + quad * 8]);
#pragma unroll
      for (int ct = 0; ct < 2; ++ct) acc[rt][ct] = MFMA16(a, wWo[ct][kc], acc[rt][ct]);
    }
  }
  __syncthreads();
#pragma unroll
  for (int rt = 0; rt < 4; ++rt) {
#pragma unroll
    for (int ct = 0; ct < 2; ++ct) {
      const int col = wave * 32 + ct * 16 + l15;
#pragma unroll
      for (int r = 0; r < 4; r += 2) {
        const int row = rt * 16 + quad * 4 + r;
        const float v0 = b2f(sH[row][col]) + acc[rt][ct][r] + vb2[ct];
        const float v1 = b2f(sH[row + 1][col]) + acc[rt][ct][r + 1] + vb2[ct];
        const unsigned int p = f2b2(v0, v1);
        s2[row][col] = (unsigned short)p;
        s2[row + 1][col] = (unsigned short)(p >> 16);
      }
    }
  }
  __syncthreads();
#pragma unroll
  for (int it = 0; it < 4; ++it) {
    const int r = (tid >> 4) + it * 16;
    const int ch = tid & 15;
    const int g = n0 + r;
    if (g < NATOM)
      *(uint4*)(hout + (size_t)g * H + ch * 8) = *(const uint4*)(&s2[r][ch * 8]);
  }
}

// ---------------------------------------------------------------------------
__global__ void out_kernel(const unsigned short* __restrict__ h,
                           const float* __restrict__ outW, const float* __restrict__ outb,
                           float* __restrict__ out) {
  const int atom = blockIdx.x * 4 + (threadIdx.x >> 6);
  const int lane = threadIdx.x & 63;
  float s0 = 0.f, s1 = 0.f, s2 = 0.f;
#pragma unroll
  for (int kk = 0; kk < 2; ++kk) {
    const int k = lane + kk * 64;
    const float hv = b2f(h[(size_t)atom * H + k]);
    s0 += hv * outW[k * 3 + 0];
    s1 += hv * outW[k * 3 + 1];
    s2 += hv * outW[k * 3 + 2];
  }
#pragma unroll
  for (int off = 32; off > 0; off >>= 1) {
    s0 += __shfl_down(s0, off);
    s1 += __shfl_down(s1, off);
    s2 += __shfl_down(s2, off);
  }
  if (lane == 0) {
    out[atom * 3 + 0] = s0 + outb[0];
    out[atom * 3 + 1] = s1 + outb[1];
    out[atom * 3 + 2] = s2 + outb[2];
  }
}

// ---------------------------------------------------------------------------
// Workspace (nc=2): pw 0.79 + h0/a1/a2 38.4 + hu/hv 25.6 + uvS/disS/listV
// 19.2 + startU/V 0.8 + af32 25.6 + msg 102.4 = 212.8MB < ~268MB limit.
// ---------------------------------------------------------------------------
extern "C" void kernel_launch(void* const* d_in, const int* in_sizes, int n_in,
                              void* d_out, int out_size, void* d_ws, size_t ws_size,
                              hipStream_t stream) {
  const int* atom_num = (const int*)d_in[0];
  const float* dis1 = (const float*)d_in[1];
  const float* dis2 = (const float*)d_in[2];
  const int* id1u = (const int*)d_in[3];
  const int* id1v = (const int*)d_in[4];
  const int* id2u = (const int*)d_in[5];
  const int* id2v = (const int*)d_in[6];
  const float* emb = (const float*)d_in[7];
  const float* Wu = (const float*)d_in[8];
  const float* Wv = (const float*)d_in[9];
  const float* Wdis = (const float*)d_in[10];
  const float* eb1 = (const float*)d_in[11];
  const float* eW2 = (const float*)d_in[12];
  const float* eb2 = (const float*)d_in[13];
  const float* eW3 = (const float*)d_in[14];
  const float* eb3 = (const float*)d_in[15];
  const float* Wh = (const float*)d_in[16];
  const float* Wa1 = (const float*)d_in[17];
  const float* Wa2 = (const float*)d_in[18];
  const float* ub1 = (const float*)d_in[19];
  const float* uW2 = (const float*)d_in[20];
  const float* ub2 = (const float*)d_in[21];
  const float* outW = (const float*)d_in[22];
  const float* outb = (const float*)d_in[23];

  auto pad = [](size_t x) { return (x + 255) & ~(size_t)255; };
  const int N2 = 2 * NATOM;
  const int nparts = (N2 + 1023) / 1024;

  char* ws = (char*)d_ws;
  size_t off = 0;
  auto take = [&](size_t bytes) { char* p = ws + off; off += pad(bytes); return p; };
  unsigned short* pw   = (unsigned short*)take(786432);
  unsigned short* h0   = (unsigned short*)take((size_t)NATOM * H * 2);
  unsigned short* a1   = (unsigned short*)take((size_t)NATOM * H * 2);
  unsigned short* a2   = (unsigned short*)take((size_t)NATOM * H * 2);
  unsigned short* hu   = (unsigned short*)take((size_t)NATOM * H * 2);
  unsigned short* hv   = (unsigned short*)take((size_t)NATOM * H * 2);
  unsigned int* uvS    = (unsigned int*)take((size_t)2 * NEDGE * 4);  // u|v<<16
  float* disS          = (float*)take((size_t)2 * NEDGE * 4);
  int* listV           = (int*)take((size_t)2 * NEDGE * 4);
  int* startU          = (int*)take(((size_t)N2 + 1) * 4);
  int* startV          = (int*)take(((size_t)N2 + 1) * 4);
  float* af32          = (float*)take((size_t)NATOM * H * 4);
  char* ovlRegion      = ws + off;  // msg chunk, overlapped with CSR scratch
  unsigned short* msg  = (unsigned short*)ovlRegion;          // CE*256B = 102.4MB
  int* degU            = (int*)ovlRegion;
  int* degV            = degU + N2;
  int* curU            = degV + N2;
  int* curV            = curU + N2;
  int* partU           = curV + N2;
  int* partV           = partU + 1024;

  PackSrc ps;
  for (int i = 0; i < 4; ++i) {
    ps.p[i] = Wu + i * 16384;
    ps.p[4 + i] = Wv + i * 16384;
    ps.p[8 + i] = eW2 + i * 16384;
    ps.p[12 + i] = eW3 + i * 16384;
  }
  for (int j = 0; j < 2; ++j) {
    ps.p[16 + j] = Wh + j * 16384;
    ps.p[18 + j] = Wa1 + j * 16384;
    ps.p[20 + j] = Wa2 + j * 16384;
    ps.p[22 + j] = uW2 + j * 16384;
  }
  repack_kernel<<<24, 256, 0, stream>>>(ps, pw);
  embed_kernel<<<12500, 256, 0, stream>>>(atom_num, emb, h0);

  // CSR build (u-sorted positions + v-side position lists, fused fill)
  {
    const int n4 = (int)(((size_t)2 * N2 * 4 + 15) / 16);
    zero_int_kernel<<<(n4 + 255) / 256, 256, 0, stream>>>((int4*)degU, n4);
    count_kernel<<<NEDGE / 256, 256, 0, stream>>>(id1u, id1v, id2u, id2v, degU, degV);
    scan_phase1<<<nparts, 256, 0, stream>>>(degU, partU, N2);
    scan_phase2<<<1, 1024, 0, stream>>>(partU, nparts);
    scan_phase3<<<nparts, 256, 0, stream>>>(degU, partU, startU, curU, N2);
    scan_phase1<<<nparts, 256, 0, stream>>>(degV, partV, N2);
    scan_phase2<<<1, 1024, 0, stream>>>(partV, nparts);
    scan_phase3<<<nparts, 256, 0, stream>>>(degV, partV, startV, curV, N2);
    fill_fused_kernel<<<1024, 256, 0, stream>>>(id1u, id1v, dis1, id2u, id2v, dis2,
                                                curU, curV, uvS, disS, listV, 8);
  }

  const int upd_grid = (NATOM + 63) / 64;   // 782
  const int AGG_GRID = NATOM / 4;
  const int tilesPerChunk = CE / 64;        // 6250
  const int EDGE_GRID = tilesPerChunk < 768 ? tilesPerChunk : 768;  // 3 blocks/CU

  const unsigned short* pWu_[4] = {pw, pw + 16384, pw + 2 * 16384, pw + 3 * 16384};
  const unsigned short* pWv_[4] = {pw + 4 * 16384, pw + 5 * 16384, pw + 6 * 16384, pw + 7 * 16384};
  const unsigned short* pW2_[4] = {pw + 8 * 16384, pw + 9 * 16384, pw + 10 * 16384, pw + 11 * 16384};
  const unsigned short* pW3_[4] = {pw + 12 * 16384, pw + 13 * 16384, pw + 14 * 16384, pw + 15 * 16384};

  for (int layer = 0; layer < 2; ++layer) {
    for (int set = 0; set < 2; ++set) {
      const int blk = layer * 2 + set;
      unsigned short* aout = set == 0 ? a1 : a2;
      pre_kernel<<<upd_grid, 256, 0, stream>>>(h0, pWu_[blk], pWv_[blk], hu, hv);
      for (int c = 0; c < 2; ++c) {
        const int chunkBase = set * NEDGE + c * CE;
        edge_kernel<<<EDGE_GRID, 256, 0, stream>>>(hu, hv, uvS, disS,
            pW2_[blk], pW3_[blk],
            Wdis + blk * H, eb1 + blk * H, eb2 + blk * H, eb3 + blk * H,
            msg, chunkBase, tilesPerChunk);
        aggregate_kernel<<<AGG_GRID, 256, 0, stream>>>(startU, startV, listV, msg,
            chunkBase, set * NATOM, af32, aout, c == 0 ? 1 : 0, c == 1 ? 1 : 0);
      }
    }
    update_kernel<<<upd_grid, 256, 0, stream>>>(h0, a1, a2,
        pw + (16 + layer) * 16384, pw + (18 + layer) * 16384,
        pw + (20 + layer) * 16384, pw + (22 + layer) * 16384,
        ub1 + layer * H, ub2 + layer * H, h0);
  }

  out_kernel<<<12500, 256, 0, stream>>>(h0, outW, outb, (float*)d_out);
}

// Round 11
// 1437.369 us; speedup vs baseline: 1.1526x; 1.1313x over previous
//
#include <hip/hip_runtime.h>

#define H 128
#define NATOM 50000
#define NEDGE 800000

typedef __attribute__((ext_vector_type(8))) short short8;
typedef __attribute__((ext_vector_type(4))) float f32x4;
typedef __attribute__((ext_vector_type(2))) float f32x2;
typedef __attribute__((ext_vector_type(2))) unsigned int uint2n;  // 8B NT store

#define MFMA16(a, b, c) __builtin_amdgcn_mfma_f32_16x16x32_bf16((a), (b), (c), 0, 0, 0)

__device__ __forceinline__ unsigned short f2b(float f) {
  unsigned int u = __float_as_uint(f);
  unsigned int r = (u + 0x7FFFu + ((u >> 16) & 1u)) >> 16;
  return (unsigned short)r;
}
__device__ __forceinline__ float b2f(unsigned short b) {
  return __uint_as_float(((unsigned int)b) << 16);
}

#if __has_builtin(__builtin_amdgcn_cvt_pk_bf16_f32)
__device__ __forceinline__ unsigned int f2b2(float lo, float hi) {
  typedef __bf16 bf16x2 __attribute__((ext_vector_type(2)));
  bf16x2 r = __builtin_amdgcn_cvt_pk_bf16_f32(lo, hi);
  union { bf16x2 v; unsigned int u; } c;
  c.v = r;
  return c.u;
}
#else
__device__ __forceinline__ unsigned int f2b2(float lo, float hi) {
  return (unsigned int)f2b(lo) | ((unsigned int)f2b(hi) << 16);
}
#endif

// ---------- fp8 e4m3 (OCP fn) pack/unpack — hw cvt on gfx950, sw fallback ----
#if __has_builtin(__builtin_amdgcn_cvt_pk_fp8_f32) && __has_builtin(__builtin_amdgcn_cvt_pk_f32_fp8)
#define HW_FP8 1
#else
#define HW_FP8 0
#endif

#if !HW_FP8
__device__ __forceinline__ unsigned int enc_e4m3(float f) {  // 1 byte
  unsigned int b = __float_as_uint(f);
  unsigned int s = (b >> 31) << 7;
  float a = fabsf(f);
  if (a >= 448.f) return s | 0x7Eu;               // clamp to max finite
  if (a < 0.015625f) {                            // denormal: m*2^-9
    int m = (int)(a * 512.f + 0.5f);
    if (m > 7) m = 7;
    return s | (unsigned int)m;
  }
  unsigned int ab = b & 0x7FFFFFFFu;
  unsigned int r = ab + 0x7FFFFu + ((ab >> 20) & 1u);  // RNE at bit20
  unsigned int e = (r >> 23) - 127u + 7u;
  unsigned int m = (r >> 20) & 7u;
  if (e >= 16u) { e = 15u; m = 6u; }
  return s | (e << 3) | m;
}
__device__ __forceinline__ float dec_e4m3(unsigned int c) {
  unsigned int s = (c >> 7) & 1u, e = (c >> 3) & 15u, m = c & 7u;
  float v = (e == 0) ? (float)m * 0.001953125f
                     : __uint_as_float(((e - 7u + 127u) << 23) | (m << 20));
  return s ? -v : v;
}
#endif

// pack 8 bf16 (as 4 words) -> 8 fp8 bytes (2 words)
__device__ __forceinline__ void pack8_fp8(const unsigned int w[4], unsigned int out[2]) {
  float f[8];
#pragma unroll
  for (int j = 0; j < 4; ++j) {
    f[2 * j] = b2f((unsigned short)w[j]);
    f[2 * j + 1] = b2f((unsigned short)(w[j] >> 16));
  }
#if HW_FP8
  int w0 = __builtin_amdgcn_cvt_pk_fp8_f32(f[0], f[1], 0, false);
  w0 = __builtin_amdgcn_cvt_pk_fp8_f32(f[2], f[3], w0, true);
  int w1 = __builtin_amdgcn_cvt_pk_fp8_f32(f[4], f[5], 0, false);
  w1 = __builtin_amdgcn_cvt_pk_fp8_f32(f[6], f[7], w1, true);
  out[0] = (unsigned int)w0;
  out[1] = (unsigned int)w1;
#else
  out[0] = enc_e4m3(f[0]) | (enc_e4m3(f[1]) << 8) | (enc_e4m3(f[2]) << 16) | (enc_e4m3(f[3]) << 24);
  out[1] = enc_e4m3(f[4]) | (enc_e4m3(f[5]) << 8) | (enc_e4m3(f[6]) << 16) | (enc_e4m3(f[7]) << 24);
#endif
}

// decode 2 fp8 bytes (packed in ushort) -> 2 floats
__device__ __forceinline__ void unpack2_fp8(unsigned short s, float& x, float& y) {
#if HW_FP8
  f32x2 v = __builtin_amdgcn_cvt_pk_f32_fp8((int)(unsigned int)s, false);
  x = v[0]; y = v[1];
#else
  x = dec_e4m3(s & 0xFFu);
  y = dec_e4m3((s >> 8) & 0xFFu);
#endif
}

__device__ __forceinline__ float silu_f(float x) {
  return x * __builtin_amdgcn_rcpf(1.0f + __expf(-x));
}

// ---------------------------------------------------------------------------
// Weight repack: f32 [128][128] row-major -> bf16 MFMA B-fragment layout.
// ---------------------------------------------------------------------------
struct PackSrc { const float* p[24]; };

__global__ void repack_kernel(PackSrc ps, unsigned short* __restrict__ dst) {
  const float* src = ps.p[blockIdx.x];
  unsigned short* d = dst + (size_t)blockIdx.x * 16384;
  for (int s = threadIdx.x; s < 2048; s += 256) {
    const int ct = s >> 8;
    const int kc = (s >> 6) & 3;
    const int lane = s & 63;
    const int r0 = kc * 32 + (lane >> 4) * 8;
    const int col = ct * 16 + (lane & 15);
    uint4 u;
    u.x = f2b2(src[(r0 + 0) * H + col], src[(r0 + 1) * H + col]);
    u.y = f2b2(src[(r0 + 2) * H + col], src[(r0 + 3) * H + col]);
    u.z = f2b2(src[(r0 + 4) * H + col], src[(r0 + 5) * H + col]);
    u.w = f2b2(src[(r0 + 6) * H + col], src[(r0 + 7) * H + col]);
    *(uint4*)(d + s * 8) = u;
  }
}

__global__ void embed_kernel(const int* __restrict__ atom_num, const float* __restrict__ emb,
                             unsigned short* __restrict__ h0) {
  const int idx = blockIdx.x * 256 + threadIdx.x;
  const int n = idx >> 6;
  const int c = (idx & 63) * 2;
  const float* src = emb + (size_t)atom_num[n] * H + c;
  *(unsigned int*)(h0 + (size_t)n * H + c) = f2b2(src[0], src[1]);
}

__global__ void zero_int_kernel(int4* __restrict__ p, int n4) {
  const int i = blockIdx.x * 256 + threadIdx.x;
  if (i < n4) p[i] = make_int4(0, 0, 0, 0);
}

// ---------------------------------------------------------------------------
// CSR: u-sorted edge order. Cells: [set*NATOM + atom]. Positions in [0,2E).
// ---------------------------------------------------------------------------
__global__ void count_kernel(const int* __restrict__ u1, const int* __restrict__ v1,
                             const int* __restrict__ u2, const int* __restrict__ v2,
                             int* __restrict__ degU, int* __restrict__ degV) {
  const int e = blockIdx.x * 256 + threadIdx.x;
  atomicAdd(degU + u1[e], 1);
  atomicAdd(degU + NATOM + u2[e], 1);
  atomicAdd(degV + v1[e], 1);
  atomicAdd(degV + NATOM + v2[e], 1);
}

__global__ void scan_phase1(const int* __restrict__ deg, int* __restrict__ partials,
                            int ncells) {
  __shared__ int sh[256];
  const int t = threadIdx.x;
  const int base = blockIdx.x * 1024 + t * 4;
  int s = 0;
#pragma unroll
  for (int j = 0; j < 4; ++j) { const int i = base + j; if (i < ncells) s += deg[i]; }
  sh[t] = s;
  __syncthreads();
  for (int off = 128; off > 0; off >>= 1) {
    if (t < off) sh[t] += sh[t + off];
    __syncthreads();
  }
  if (t == 0) partials[blockIdx.x] = sh[0];
}

__global__ void scan_phase2(int* __restrict__ partials, int np) {
  __shared__ int sh[1024];
  const int t = threadIdx.x;
  const int v = t < np ? partials[t] : 0;
  sh[t] = v;
  __syncthreads();
  for (int off = 1; off < 1024; off <<= 1) {
    int x = 0;
    if (t >= off) x = sh[t - off];
    __syncthreads();
    sh[t] += x;
    __syncthreads();
  }
  if (t < np) partials[t] = sh[t] - v;  // exclusive
}

__global__ void scan_phase3(const int* __restrict__ deg, const int* __restrict__ partials,
                            int* __restrict__ start, int* __restrict__ cursor, int ncells) {
  __shared__ int sh[256];
  const int t = threadIdx.x;
  const int base = blockIdx.x * 1024 + t * 4;
  int v[4];
  int s = 0;
#pragma unroll
  for (int j = 0; j < 4; ++j) {
    const int i = base + j;
    v[j] = (i < ncells) ? deg[i] : 0;
    s += v[j];
  }
  sh[t] = s;
  __syncthreads();
  const int own = s;
  for (int off = 1; off < 256; off <<= 1) {
    int x = 0;
    if (t >= off) x = sh[t - off];
    __syncthreads();
    sh[t] += x;
    __syncthreads();
  }
  int o = partials[blockIdx.x] + sh[t] - own;
#pragma unroll
  for (int j = 0; j < 4; ++j) {
    const int i = base + j;
    if (i < ncells) {
      start[i] = o;
      cursor[i] = o;
      o += v[j];
      if (i == ncells - 1) start[ncells] = o;
    }
  }
}

// Fused fill (R8-proven): u-sorted placement + v-list in one pass.
__global__ void fill_fused_kernel(const int* __restrict__ u1, const int* __restrict__ v1,
                                  const float* __restrict__ dis1,
                                  const int* __restrict__ u2, const int* __restrict__ v2,
                                  const float* __restrict__ dis2,
                                  int* __restrict__ curU, int* __restrict__ curV,
                                  unsigned int* __restrict__ uvS,
                                  float* __restrict__ disS, int* __restrict__ listV,
                                  int npass) {
  const int apb = (NATOM + npass - 1) / npass;
  for (int p = 0; p < npass; ++p) {
    const int lo = p * apb, hi = lo + apb;
    for (int e = blockIdx.x * 256 + threadIdx.x; e < NEDGE; e += gridDim.x * 256) {
      int a = __builtin_nontemporal_load(u1 + e);
      if (a >= lo && a < hi) {
        const int v = __builtin_nontemporal_load(v1 + e);
        const int su = atomicAdd(curU + a, 1);
        uvS[su] = (unsigned int)a | ((unsigned int)v << 16);
        disS[su] = __builtin_nontemporal_load(dis1 + e);
        const int sv = atomicAdd(curV + v, 1);
        listV[sv] = su;
      }
      a = __builtin_nontemporal_load(u2 + e);
      if (a >= lo && a < hi) {
        const int v = __builtin_nontemporal_load(v2 + e);
        const int su = atomicAdd(curU + NATOM + a, 1);
        uvS[su] = (unsigned int)a | ((unsigned int)v << 16);
        disS[su] = __builtin_nontemporal_load(dis2 + e);
        const int sv = atomicAdd(curV + NATOM + v, 1);
        listV[sv] = su;
      }
    }
  }
}

// ---------------------------------------------------------------------------
// Precompute: hu = h@Wu, hv = h@Wv per atom (bf16 out). 16x less FLOP than
// recomputing per edge (R10-verified correct).
// ---------------------------------------------------------------------------
__global__ __launch_bounds__(256, 2)
void pre_kernel(const unsigned short* __restrict__ h,
                const unsigned short* __restrict__ pWu, const unsigned short* __restrict__ pWv,
                unsigned short* __restrict__ hu, unsigned short* __restrict__ hv) {
  __shared__ __attribute__((aligned(16))) unsigned short sH[64][136];
  __shared__ __attribute__((aligned(16))) unsigned short sO[64][136];

  const int tid = threadIdx.x;
  const int wave = tid >> 6;
  const int lane = tid & 63;
  const int l15 = lane & 15;
  const int quad = lane >> 4;
  const int r0 = tid >> 4;
  const int ch = tid & 15;

  short8 wU[2][4], wV[2][4];
#pragma unroll
  for (int ct = 0; ct < 2; ++ct) {
#pragma unroll
    for (int kc = 0; kc < 4; ++kc) {
      const int off = (((wave * 2 + ct) * 4 + kc) * 64 + lane) * 8;
      wU[ct][kc] = *(const short8*)(pWu + off);
      wV[ct][kc] = *(const short8*)(pWv + off);
    }
  }

  const int n0 = blockIdx.x * 64;
#pragma unroll
  for (int it = 0; it < 4; ++it) {
    const int r = r0 + it * 16;
    int g = n0 + r; if (g >= NATOM) g = NATOM - 1;
    *(uint4*)(&sH[r][ch * 8]) = *(const uint4*)(h + (size_t)g * H + ch * 8);
  }
  __syncthreads();

  f32x4 au[4][2], av[4][2];
#pragma unroll
  for (int rt = 0; rt < 4; ++rt)
#pragma unroll
    for (int ct = 0; ct < 2; ++ct) {
      au[rt][ct] = (f32x4){0.f, 0.f, 0.f, 0.f};
      av[rt][ct] = (f32x4){0.f, 0.f, 0.f, 0.f};
    }
#pragma unroll
  for (int kc = 0; kc < 4; ++kc) {
#pragma unroll
    for (int rt = 0; rt < 4; ++rt) {
      const short8 a = *(const short8*)(&sH[rt * 16 + l15][kc * 32 + quad * 8]);
#pragma unroll
      for (int ct = 0; ct < 2; ++ct) {
        au[rt][ct] = MFMA16(a, wU[ct][kc], au[rt][ct]);
        av[rt][ct] = MFMA16(a, wV[ct][kc], av[rt][ct]);
      }
    }
  }
  __syncthreads();

  // hu out
#pragma unroll
  for (int rt = 0; rt < 4; ++rt) {
#pragma unroll
    for (int ct = 0; ct < 2; ++ct) {
      const int col = wave * 32 + ct * 16 + l15;
#pragma unroll
      for (int r = 0; r < 4; r += 2) {
        const int row = rt * 16 + quad * 4 + r;
        const unsigned int p = f2b2(au[rt][ct][r], au[rt][ct][r + 1]);
        sO[row][col] = (unsigned short)p;
        sO[row + 1][col] = (unsigned short)(p >> 16);
      }
    }
  }
  __syncthreads();
#pragma unroll
  for (int it = 0; it < 4; ++it) {
    const int r = r0 + it * 16;
    const int g = n0 + r;
    if (g < NATOM)
      *(uint4*)(hu + (size_t)g * H + ch * 8) = *(const uint4*)(&sO[r][ch * 8]);
  }
  __syncthreads();

  // hv out
#pragma unroll
  for (int rt = 0; rt < 4; ++rt) {
#pragma unroll
    for (int ct = 0; ct < 2; ++ct) {
      const int col = wave * 32 + ct * 16 + l15;
#pragma unroll
      for (int r = 0; r < 4; r += 2) {
        const int row = rt * 16 + quad * 4 + r;
        const unsigned int p = f2b2(av[rt][ct][r], av[rt][ct][r + 1]);
        sO[row][col] = (unsigned short)p;
        sO[row + 1][col] = (unsigned short)(p >> 16);
      }
    }
  }
  __syncthreads();
#pragma unroll
  for (int it = 0; it < 4; ++it) {
    const int r = r0 + it * 16;
    const int g = n0 + r;
    if (g < NATOM)
      *(uint4*)(hv + (size_t)g * H + ch * 8) = *(const uint4*)(&sO[r][ch * 8]);
  }
}

// ---------------------------------------------------------------------------
// R23 edge: ep0 gather-add (hu[u]+hv[v]) + GEMM2 + GEMM3; msg stored as FP8
// e4m3 (halves the dominant write stream: 205->102MB ideal per set). nc=1.
// ---------------------------------------------------------------------------
__global__ __launch_bounds__(256, 3)
void edge_kernel(const unsigned short* __restrict__ hu,
                 const unsigned short* __restrict__ hv,
                 const unsigned int* __restrict__ uv,
                 const float* __restrict__ dis,
                 const unsigned short* __restrict__ pW2, const unsigned short* __restrict__ pW3,
                 const float* __restrict__ Wdis, const float* __restrict__ bb1,
                 const float* __restrict__ bb2, const float* __restrict__ bb3,
                 unsigned char* __restrict__ msg, int eBase, int nTiles) {
  __shared__ __attribute__((aligned(16))) unsigned short sA[64][136];
  __shared__ __attribute__((aligned(16))) unsigned short sB[64][136];

  const int tid = threadIdx.x;
  const int wave = tid >> 6;
  const int lane = tid & 63;
  const int l15 = lane & 15;
  const int quad = lane >> 4;
  const int r0 = tid >> 4;
  const int ch = tid & 15;

  short8 wW2[2][4], wW3[2][4];
#pragma unroll
  for (int ct = 0; ct < 2; ++ct) {
#pragma unroll
    for (int kc = 0; kc < 4; ++kc) {
      const int off = (((wave * 2 + ct) * 4 + kc) * 64 + lane) * 8;
      wW2[ct][kc] = *(const short8*)(pW2 + off);
      wW3[ct][kc] = *(const short8*)(pW3 + off);
    }
  }
  float wd8[8], b18[8];
#pragma unroll
  for (int k = 0; k < 8; ++k) { wd8[k] = Wdis[ch * 8 + k]; b18[k] = bb1[ch * 8 + k]; }
  float vb2[2], vb3[2];
#pragma unroll
  for (int ct = 0; ct < 2; ++ct) {
    const int col = wave * 32 + ct * 16 + l15;
    vb2[ct] = bb2[col]; vb3[ct] = bb3[col];
  }

  const int stride = gridDim.x;
  int tile = blockIdx.x;

  uint4 pfU[4], pfV[4];
  float pfD[4];
  if (tile < nTiles) {
    const int e0 = eBase + tile * 64;
#pragma unroll
    for (int it = 0; it < 4; ++it) {
      const int e = e0 + r0 + it * 16;
      const unsigned int p = uv[e];
      pfU[it] = *(const uint4*)(hu + (size_t)(p & 0xFFFFu) * H + ch * 8);
      pfV[it] = *(const uint4*)(hv + (size_t)(p >> 16) * H + ch * 8);
      pfD[it] = dis[e];
    }
  }

  for (; tile < nTiles; tile += stride) {
    // ep0: t1 = silu(hu[u] + hv[v] + dis*wd + b1) -> sA (thread-local rows)
#pragma unroll
    for (int it = 0; it < 4; ++it) {
      const int rr = r0 + it * 16;
      const float d = pfD[it];
      const unsigned int ua[4] = {pfU[it].x, pfU[it].y, pfU[it].z, pfU[it].w};
      const unsigned int va[4] = {pfV[it].x, pfV[it].y, pfV[it].z, pfV[it].w};
#pragma unroll
      for (int j = 0; j < 4; ++j) {
        const float x0 = b2f((unsigned short)ua[j]) + b2f((unsigned short)va[j]) +
                         d * wd8[2 * j] + b18[2 * j];
        const float x1 = b2f((unsigned short)(ua[j] >> 16)) + b2f((unsigned short)(va[j] >> 16)) +
                         d * wd8[2 * j + 1] + b18[2 * j + 1];
        *(unsigned int*)(&sA[rr][ch * 8 + 2 * j]) = f2b2(silu_f(x0), silu_f(x1));
      }
    }
    // issue next tile's gathers (fly during GEMM2/GEMM3)
    const int tileN = tile + stride;
    if (tileN < nTiles) {
      const int e0n = eBase + tileN * 64;
#pragma unroll
      for (int it = 0; it < 4; ++it) {
        const int e = e0n + r0 + it * 16;
        const unsigned int p = uv[e];
        pfU[it] = *(const uint4*)(hu + (size_t)(p & 0xFFFFu) * H + ch * 8);
        pfV[it] = *(const uint4*)(hv + (size_t)(p >> 16) * H + ch * 8);
        pfD[it] = dis[e];
      }
    }
    __syncthreads();  // b1: t1 visible

    // GEMM2: t1@W2
    f32x4 acc[4][2];
#pragma unroll
    for (int rt = 0; rt < 4; ++rt)
#pragma unroll
      for (int ct = 0; ct < 2; ++ct) acc[rt][ct] = (f32x4){0.f, 0.f, 0.f, 0.f};
#pragma unroll
    for (int kc = 0; kc < 4; ++kc) {
#pragma unroll
      for (int rt = 0; rt < 4; ++rt) {
        const short8 a = *(const short8*)(&sA[rt * 16 + l15][kc * 32 + quad * 8]);
#pragma unroll
        for (int ct = 0; ct < 2; ++ct) acc[rt][ct] = MFMA16(a, wW2[ct][kc], acc[rt][ct]);
      }
    }
    // ep2: t2 = silu(acc + b2) -> sB
#pragma unroll
    for (int rt = 0; rt < 4; ++rt) {
#pragma unroll
      for (int ct = 0; ct < 2; ++ct) {
        const int col = wave * 32 + ct * 16 + l15;
#pragma unroll
        for (int r = 0; r < 4; r += 2) {
          const int row = rt * 16 + quad * 4 + r;
          const unsigned int p = f2b2(silu_f(acc[rt][ct][r] + vb2[ct]),
                                      silu_f(acc[rt][ct][r + 1] + vb2[ct]));
          sB[row][col] = (unsigned short)p;
          sB[row + 1][col] = (unsigned short)(p >> 16);
        }
      }
    }
    __syncthreads();  // b2: t2 visible; GEMM2 reads of sA done

    // GEMM3: t2@W3
#pragma unroll
    for (int rt = 0; rt < 4; ++rt)
#pragma unroll
      for (int ct = 0; ct < 2; ++ct) acc[rt][ct] = (f32x4){0.f, 0.f, 0.f, 0.f};
#pragma unroll
    for (int kc = 0; kc < 4; ++kc) {
#pragma unroll
      for (int rt = 0; rt < 4; ++rt) {
        const short8 a = *(const short8*)(&sB[rt * 16 + l15][kc * 32 + quad * 8]);
#pragma unroll
        for (int ct = 0; ct < 2; ++ct) acc[rt][ct] = MFMA16(a, wW3[ct][kc], acc[rt][ct]);
      }
    }
    // m -> sA (bf16 staging; fp8 conversion happens at the cooperative store)
#pragma unroll
    for (int rt = 0; rt < 4; ++rt) {
#pragma unroll
      for (int ct = 0; ct < 2; ++ct) {
        const int col = wave * 32 + ct * 16 + l15;
#pragma unroll
        for (int r = 0; r < 4; r += 2) {
          const int row = rt * 16 + quad * 4 + r;
          const unsigned int p = f2b2(acc[rt][ct][r] + vb3[ct],
                                      acc[rt][ct][r + 1] + vb3[ct]);
          sA[row][col] = (unsigned short)p;
          sA[row + 1][col] = (unsigned short)(p >> 16);
        }
      }
    }
    __syncthreads();  // b3: m assembled
#pragma unroll
    for (int it = 0; it < 4; ++it) {
      const int rr = r0 + it * 16;
      unsigned int w[4], o[2];
      *(uint4*)w = *(const uint4*)(&sA[rr][ch * 8]);
      pack8_fp8(w, o);
      uint2n ov; ov.x = o[0]; ov.y = o[1];
      __builtin_nontemporal_store(ov,
          (uint2n*)(msg + (size_t)(tile * 64 + rr) * H + ch * 8));
    }
    __syncthreads();  // b4: sA reads done before next ep0 overwrites
  }
}

// ---------------------------------------------------------------------------
// R23 aggregate (nc=1, fp8 msg): u-half streams contiguous 128B rows; v-half
// NT-gathers. Each lane owns 2 cols (2 fp8 bytes/row). Accum f32.
// ---------------------------------------------------------------------------
__global__ __launch_bounds__(256)
void aggregate_kernel(const int* __restrict__ startU, const int* __restrict__ startV,
                      const int* __restrict__ listV,
                      const unsigned char* __restrict__ msg, int eBase, int cellBase,
                      unsigned short* __restrict__ aout) {
  const int atom = blockIdx.x * 4 + (threadIdx.x >> 6);
  const int lane = threadIdx.x & 63;
  const int su = startU[cellBase + atom] - eBase;
  const int eu = startU[cellBase + atom + 1] - eBase;
  const int sv = startV[cellBase + atom];
  const int ev = startV[cellBase + atom + 1];
  float ax = 0.f, ay = 0.f;
  const unsigned char* mp = msg + lane * 2;

  // contiguous u-half: 4 rows in flight
  int p = su;
  for (; p + 3 < eu; p += 4) {
    unsigned short s[4];
#pragma unroll
    for (int j = 0; j < 4; ++j) s[j] = *(const unsigned short*)(mp + (size_t)(p + j) * H);
#pragma unroll
    for (int j = 0; j < 4; ++j) {
      float x, y; unpack2_fp8(s[j], x, y);
      ax += x; ay += y;
    }
  }
  for (; p < eu; ++p) {
    const unsigned short s0 = *(const unsigned short*)(mp + (size_t)p * H);
    float x, y; unpack2_fp8(s0, x, y);
    ax += x; ay += y;
  }

  // random v-half: 8-deep NT gather
  int i = sv;
  for (; i + 7 < ev; i += 8) {
    int r[8];
#pragma unroll
    for (int j = 0; j < 8; ++j) r[j] = __builtin_nontemporal_load(listV + i + j) - eBase;
    unsigned short s[8];
#pragma unroll
    for (int j = 0; j < 8; ++j)
      s[j] = __builtin_nontemporal_load((const unsigned short*)(mp + (size_t)r[j] * H));
#pragma unroll
    for (int j = 0; j < 8; ++j) {
      float x, y; unpack2_fp8(s[j], x, y);
      ax += x; ay += y;
    }
  }
  for (; i < ev; ++i) {
    const int r = __builtin_nontemporal_load(listV + i) - eBase;
    const unsigned short s0 =
        __builtin_nontemporal_load((const unsigned short*)(mp + (size_t)r * H));
    float x, y; unpack2_fp8(s0, x, y);
    ax += x; ay += y;
  }

  *(unsigned int*)(aout + (size_t)atom * H + lane * 2) = f2b2(ax, ay);
}

// ---------------------------------------------------------------------------
// Atom update: h_new = h + silu(h@Wh + a1@Wa1 + a2@Wa2 + b1)@W2 + b2
// ---------------------------------------------------------------------------
__global__ __launch_bounds__(256, 2)
void update_kernel(const unsigned short* __restrict__ hin,
                   const unsigned short* __restrict__ a1, const unsigned short* __restrict__ a2,
                   const unsigned short* __restrict__ pWh, const unsigned short* __restrict__ pWa1,
                   const unsigned short* __restrict__ pWa2, const unsigned short* __restrict__ pWo,
                   const float* __restrict__ b1, const float* __restrict__ b2,
                   unsigned short* __restrict__ hout) {
  __shared__ __attribute__((aligned(16))) unsigned short sH[64][136];
  __shared__ __attribute__((aligned(16))) unsigned short s1[64][136];
  __shared__ __attribute__((aligned(16))) unsigned short s2[64][136];

  const int tid = threadIdx.x;
  const int wave = tid >> 6;
  const int lane = tid & 63;
  const int l15 = lane & 15;
  const int quad = lane >> 4;

  short8 wWh[2][4], wW1[2][4], wW2m[2][4], wWo[2][4];
#pragma unroll
  for (int ct = 0; ct < 2; ++ct) {
#pragma unroll
    for (int kc = 0; kc < 4; ++kc) {
      const int off = (((wave * 2 + ct) * 4 + kc) * 64 + lane) * 8;
      wWh[ct][kc] = *(const short8*)(pWh + off);
      wW1[ct][kc] = *(const short8*)(pWa1 + off);
      wW2m[ct][kc] = *(const short8*)(pWa2 + off);
      wWo[ct][kc] = *(const short8*)(pWo + off);
    }
  }
  float vb1[2], vb2[2];
#pragma unroll
  for (int ct = 0; ct < 2; ++ct) {
    const int col = wave * 32 + ct * 16 + l15;
    vb1[ct] = b1[col]; vb2[ct] = b2[col];
  }

  const int n0 = blockIdx.x * 64;
#pragma unroll
  for (int it = 0; it < 4; ++it) {
    const int r = (tid >> 4) + it * 16;
    const int ch = tid & 15;
    int g = n0 + r; if (g >= NATOM) g = NATOM - 1;
    *(uint4*)(&sH[r][ch * 8]) = *(const uint4*)(hin + (size_t)g * H + ch * 8);
    *(uint4*)(&s1[r][ch * 8]) = *(const uint4*)(a1 + (size_t)g * H + ch * 8);
    *(uint4*)(&s2[r][ch * 8]) = *(const uint4*)(a2 + (size_t)g * H + ch * 8);
  }
  __syncthreads();

  f32x4 acc[4][2];
#pragma unroll
  for (int rt = 0; rt < 4; ++rt)
#pragma unroll
    for (int ct = 0; ct < 2; ++ct) acc[rt][ct] = (f32x4){0.f, 0.f, 0.f, 0.f};

#pragma unroll
  for (int kc = 0; kc < 4; ++kc) {
#pragma unroll
    for (int rt = 0; rt < 4; ++rt) {
      const short8 ah = *(const short8*)(&sH[rt * 16 + l15][kc * 32 + quad * 8]);
      const short8 aa1 = *(const short8*)(&s1[rt * 16 + l15][kc * 32 + quad * 8]);
      const short8 aa2 = *(const short8*)(&s2[rt * 16 + l15][kc * 32 + quad * 8]);
#pragma unroll
      for (int ct = 0; ct < 2; ++ct) {
        acc[rt][ct] = MFMA16(ah, wWh[ct][kc], acc[rt][ct]);
        acc[rt][ct] = MFMA16(aa1, wW1[ct][kc], acc[rt][ct]);
        acc[rt][ct] = MFMA16(aa2, wW2m[ct][kc], acc[rt][ct]);
      }
    }
  }
  __syncthreads();

#pragma unroll
  for (int rt = 0; rt < 4; ++rt) {
#pragma unroll
    for (int ct = 0; ct < 2; ++ct) {
      const int col = wave * 32 + ct * 16 + l15;
#pragma unroll
      for (int r = 0; r < 4; r += 2) {
        const int row = rt * 16 + quad * 4 + r;
        const unsigned int p = f2b2(silu_f(acc[rt][ct][r] + vb1[ct]),
                                    silu_f(acc[rt][ct][r + 1] + vb1[ct]));
        s1[row][col] = (unsigned short)p;
        s1[row + 1][col] = (unsigned short)(p >> 16);
      }
    }
  }
  __syncthreads();

#pragma unroll
  for (int rt = 0; rt < 4; ++rt)
#pragma unroll
    for (int ct = 0; ct < 2; ++ct) acc[rt][ct] = (f32x4){0.f, 0.f, 0.f, 0.f};
#pragma unroll
  for (int kc = 0; kc < 4; ++kc) {
#pragma unroll
    for (int rt = 0; rt < 4; ++rt) {
      const short8 a = *(const short8*)(&s1[rt * 16 + l15][kc * 32 + quad * 8]);
#pragma unroll
      for (int ct = 0; ct < 2; ++ct) acc[rt][ct] = MFMA16(a, wWo[ct][kc], acc[rt][ct]);
    }
  }
  __syncthreads();
#pragma unroll
  for (int rt = 0; rt < 4; ++rt) {
#pragma unroll
    for (int ct = 0; ct < 2; ++ct) {
      const int col = wave * 32 + ct * 16 + l15;
#pragma unroll
      for (int r = 0; r < 4; r += 2) {
        const int row = rt * 16 + quad * 4 + r;
        const float v0 = b2f(sH[row][col]) + acc[rt][ct][r] + vb2[ct];
        const float v1 = b2f(sH[row + 1][col]) + acc[rt][ct][r + 1] + vb2[ct];
        const unsigned int p = f2b2(v0, v1);
        s2[row][col] = (unsigned short)p;
        s2[row + 1][col] = (unsigned short)(p >> 16);
      }
    }
  }
  __syncthreads();
#pragma unroll
  for (int it = 0; it < 4; ++it) {
    const int r = (tid >> 4) + it * 16;
    const int ch = tid & 15;
    const int g = n0 + r;
    if (g < NATOM)
      *(uint4*)(hout + (size_t)g * H + ch * 8) = *(const uint4*)(&s2[r][ch * 8]);
  }
}

// ---------------------------------------------------------------------------
__global__ void out_kernel(const unsigned short* __restrict__ h,
                           const float* __restrict__ outW, const float* __restrict__ outb,
                           float* __restrict__ out) {
  const int atom = blockIdx.x * 4 + (threadIdx.x >> 6);
  const int lane = threadIdx.x & 63;
  float s0 = 0.f, s1 = 0.f, s2 = 0.f;
#pragma unroll
  for (int kk = 0; kk < 2; ++kk) {
    const int k = lane + kk * 64;
    const float hv = b2f(h[(size_t)atom * H + k]);
    s0 += hv * outW[k * 3 + 0];
    s1 += hv * outW[k * 3 + 1];
    s2 += hv * outW[k * 3 + 2];
  }
#pragma unroll
  for (int off = 32; off > 0; off >>= 1) {
    s0 += __shfl_down(s0, off);
    s1 += __shfl_down(s1, off);
    s2 += __shfl_down(s2, off);
  }
  if (lane == 0) {
    out[atom * 3 + 0] = s0 + outb[0];
    out[atom * 3 + 1] = s1 + outb[1];
    out[atom * 3 + 2] = s2 + outb[2];
  }
}

// ---------------------------------------------------------------------------
// Workspace (nc=1, fp8 msg): pw 0.79 + h0/a1/a2 38.4 + hu/hv 25.6 +
// uvS/disS/listV 19.2 + startU/V 0.8 + msg(fp8) 102.4 = 187.2MB << 256MiB.
// ---------------------------------------------------------------------------
extern "C" void kernel_launch(void* const* d_in, const int* in_sizes, int n_in,
                              void* d_out, int out_size, void* d_ws, size_t ws_size,
                              hipStream_t stream) {
  const int* atom_num = (const int*)d_in[0];
  const float* dis1 = (const float*)d_in[1];
  const float* dis2 = (const float*)d_in[2];
  const int* id1u = (const int*)d_in[3];
  const int* id1v = (const int*)d_in[4];
  const int* id2u = (const int*)d_in[5];
  const int* id2v = (const int*)d_in[6];
  const float* emb = (const float*)d_in[7];
  const float* Wu = (const float*)d_in[8];
  const float* Wv = (const float*)d_in[9];
  const float* Wdis = (const float*)d_in[10];
  const float* eb1 = (const float*)d_in[11];
  const float* eW2 = (const float*)d_in[12];
  const float* eb2 = (const float*)d_in[13];
  const float* eW3 = (const float*)d_in[14];
  const float* eb3 = (const float*)d_in[15];
  const float* Wh = (const float*)d_in[16];
  const float* Wa1 = (const float*)d_in[17];
  const float* Wa2 = (const float*)d_in[18];
  const float* ub1 = (const float*)d_in[19];
  const float* uW2 = (const float*)d_in[20];
  const float* ub2 = (const float*)d_in[21];
  const float* outW = (const float*)d_in[22];
  const float* outb = (const float*)d_in[23];

  auto pad = [](size_t x) { return (x + 255) & ~(size_t)255; };
  const int N2 = 2 * NATOM;
  const int nparts = (N2 + 1023) / 1024;

  char* ws = (char*)d_ws;
  size_t off = 0;
  auto take = [&](size_t bytes) { char* p = ws + off; off += pad(bytes); return p; };
  unsigned short* pw   = (unsigned short*)take(786432);
  unsigned short* h0   = (unsigned short*)take((size_t)NATOM * H * 2);
  unsigned short* a1   = (unsigned short*)take((size_t)NATOM * H * 2);
  unsigned short* a2   = (unsigned short*)take((size_t)NATOM * H * 2);
  unsigned short* hu   = (unsigned short*)take((size_t)NATOM * H * 2);
  unsigned short* hv   = (unsigned short*)take((size_t)NATOM * H * 2);
  unsigned int* uvS    = (unsigned int*)take((size_t)2 * NEDGE * 4);  // u|v<<16
  float* disS          = (float*)take((size_t)2 * NEDGE * 4);
  int* listV           = (int*)take((size_t)2 * NEDGE * 4);
  int* startU          = (int*)take(((size_t)N2 + 1) * 4);
  int* startV          = (int*)take(((size_t)N2 + 1) * 4);
  char* ovlRegion      = ws + off;  // fp8 msg, overlapped with CSR scratch
  unsigned char* msg   = (unsigned char*)ovlRegion;           // E*128B = 102.4MB
  int* degU            = (int*)ovlRegion;
  int* degV            = degU + N2;
  int* curU            = degV + N2;
  int* curV            = curU + N2;
  int* partU           = curV + N2;
  int* partV           = partU + 1024;

  PackSrc ps;
  for (int i = 0; i < 4; ++i) {
    ps.p[i] = Wu + i * 16384;
    ps.p[4 + i] = Wv + i * 16384;
    ps.p[8 + i] = eW2 + i * 16384;
    ps.p[12 + i] = eW3 + i * 16384;
  }
  for (int j = 0; j < 2; ++j) {
    ps.p[16 + j] = Wh + j * 16384;
    ps.p[18 + j] = Wa1 + j * 16384;
    ps.p[20 + j] = Wa2 + j * 16384;
    ps.p[22 + j] = uW2 + j * 16384;
  }
  repack_kernel<<<24, 256, 0, stream>>>(ps, pw);
  embed_kernel<<<12500, 256, 0, stream>>>(atom_num, emb, h0);

  // CSR build (u-sorted positions + v-side position lists, fused fill)
  {
    const int n4 = (int)(((size_t)2 * N2 * 4 + 15) / 16);
    zero_int_kernel<<<(n4 + 255) / 256, 256, 0, stream>>>((int4*)degU, n4);
    count_kernel<<<NEDGE / 256, 256, 0, stream>>>(id1u, id1v, id2u, id2v, degU, degV);
    scan_phase1<<<nparts, 256, 0, stream>>>(degU, partU, N2);
    scan_phase2<<<1, 1024, 0, stream>>>(partU, nparts);
    scan_phase3<<<nparts, 256, 0, stream>>>(degU, partU, startU, curU, N2);
    scan_phase1<<<nparts, 256, 0, stream>>>(degV, partV, N2);
    scan_phase2<<<1, 1024, 0, stream>>>(partV, nparts);
    scan_phase3<<<nparts, 256, 0, stream>>>(degV, partV, startV, curV, N2);
    fill_fused_kernel<<<1024, 256, 0, stream>>>(id1u, id1v, dis1, id2u, id2v, dis2,
                                                curU, curV, uvS, disS, listV, 8);
  }

  const int upd_grid = (NATOM + 63) / 64;   // 782
  const int AGG_GRID = NATOM / 4;
  const int nTiles = NEDGE / 64;            // 12500
  const int EDGE_GRID = 768;                // 3 blocks/CU

  const unsigned short* pWu_[4] = {pw, pw + 16384, pw + 2 * 16384, pw + 3 * 16384};
  const unsigned short* pWv_[4] = {pw + 4 * 16384, pw + 5 * 16384, pw + 6 * 16384, pw + 7 * 16384};
  const unsigned short* pW2_[4] = {pw + 8 * 16384, pw + 9 * 16384, pw + 10 * 16384, pw + 11 * 16384};
  const unsigned short* pW3_[4] = {pw + 12 * 16384, pw + 13 * 16384, pw + 14 * 16384, pw + 15 * 16384};

  for (int layer = 0; layer < 2; ++layer) {
    for (int set = 0; set < 2; ++set) {
      const int blk = layer * 2 + set;
      const int eBase = set * NEDGE;
      const int cellBase = set * NATOM;
      unsigned short* aout = set == 0 ? a1 : a2;
      pre_kernel<<<upd_grid, 256, 0, stream>>>(h0, pWu_[blk], pWv_[blk], hu, hv);
      edge_kernel<<<EDGE_GRID, 256, 0, stream>>>(hu, hv, uvS, disS,
          pW2_[blk], pW3_[blk],
          Wdis + blk * H, eb1 + blk * H, eb2 + blk * H, eb3 + blk * H,
          msg, eBase, nTiles);
      aggregate_kernel<<<AGG_GRID, 256, 0, stream>>>(startU, startV, listV, msg,
          eBase, cellBase, aout);
    }
    update_kernel<<<upd_grid, 256, 0, stream>>>(h0, a1, a2,
        pw + (16 + layer) * 16384, pw + (18 + layer) * 16384,
        pw + (20 + layer) * 16384, pw + (22 + layer) * 16384,
        ub1 + layer * H, ub2 + layer * H, h0);
  }

  out_kernel<<<12500, 256, 0, stream>>>(h0, outW, outb, (float*)d_out);
}

// Round 13
// 1337.257 us; speedup vs baseline: 1.2389x; 1.0749x over previous
//
#include <hip/hip_runtime.h>

#define H 128
#define NATOM 50000
#define NEDGE 800000

typedef __attribute__((ext_vector_type(8))) short short8;
typedef __attribute__((ext_vector_type(4))) float f32x4;
typedef __attribute__((ext_vector_type(2))) float f32x2;
typedef __attribute__((ext_vector_type(4))) unsigned int uint4n;  // 16B NT store

#define MFMA16(a, b, c) __builtin_amdgcn_mfma_f32_16x16x32_bf16((a), (b), (c), 0, 0, 0)

__device__ __forceinline__ unsigned short f2b(float f) {
  unsigned int u = __float_as_uint(f);
  unsigned int r = (u + 0x7FFFu + ((u >> 16) & 1u)) >> 16;
  return (unsigned short)r;
}
__device__ __forceinline__ float b2f(unsigned short b) {
  return __uint_as_float(((unsigned int)b) << 16);
}

#if __has_builtin(__builtin_amdgcn_cvt_pk_bf16_f32)
__device__ __forceinline__ unsigned int f2b2(float lo, float hi) {
  typedef __bf16 bf16x2 __attribute__((ext_vector_type(2)));
  bf16x2 r = __builtin_amdgcn_cvt_pk_bf16_f32(lo, hi);
  union { bf16x2 v; unsigned int u; } c;
  c.v = r;
  return c.u;
}
#else
__device__ __forceinline__ unsigned int f2b2(float lo, float hi) {
  return (unsigned int)f2b(lo) | ((unsigned int)f2b(hi) << 16);
}
#endif

// ---------- fp8 e4m3 (OCP fn) pack/unpack — hw cvt on gfx950, sw fallback ----
#if __has_builtin(__builtin_amdgcn_cvt_pk_fp8_f32) && __has_builtin(__builtin_amdgcn_cvt_pk_f32_fp8)
#define HW_FP8 1
#else
#define HW_FP8 0
#endif

#if !HW_FP8
__device__ __forceinline__ unsigned int enc_e4m3(float f) {  // 1 byte
  unsigned int b = __float_as_uint(f);
  unsigned int s = (b >> 31) << 7;
  float a = fabsf(f);
  if (a >= 448.f) return s | 0x7Eu;               // clamp to max finite
  if (a < 0.015625f) {                            // denormal: m*2^-9
    int m = (int)(a * 512.f + 0.5f);
    if (m > 7) m = 7;
    return s | (unsigned int)m;
  }
  unsigned int ab = b & 0x7FFFFFFFu;
  unsigned int r = ab + 0x7FFFFu + ((ab >> 20) & 1u);  // RNE at bit20
  unsigned int e = (r >> 23) - 127u + 7u;
  unsigned int m = (r >> 20) & 7u;
  if (e >= 16u) { e = 15u; m = 6u; }
  return s | (e << 3) | m;
}
__device__ __forceinline__ float dec_e4m3(unsigned int c) {
  unsigned int s = (c >> 7) & 1u, e = (c >> 3) & 15u, m = c & 7u;
  float v = (e == 0) ? (float)m * 0.001953125f
                     : __uint_as_float(((e - 7u + 127u) << 23) | (m << 20));
  return s ? -v : v;
}
#endif

// pack 8 bf16 (as 4 words) -> 8 fp8 bytes (2 words)
__device__ __forceinline__ void pack8_fp8(const unsigned int w[4], unsigned int out[2]) {
  float f[8];
#pragma unroll
  for (int j = 0; j < 4; ++j) {
    f[2 * j] = b2f((unsigned short)w[j]);
    f[2 * j + 1] = b2f((unsigned short)(w[j] >> 16));
  }
#if HW_FP8
  int w0 = __builtin_amdgcn_cvt_pk_fp8_f32(f[0], f[1], 0, false);
  w0 = __builtin_amdgcn_cvt_pk_fp8_f32(f[2], f[3], w0, true);
  int w1 = __builtin_amdgcn_cvt_pk_fp8_f32(f[4], f[5], 0, false);
  w1 = __builtin_amdgcn_cvt_pk_fp8_f32(f[6], f[7], w1, true);
  out[0] = (unsigned int)w0;
  out[1] = (unsigned int)w1;
#else
  out[0] = enc_e4m3(f[0]) | (enc_e4m3(f[1]) << 8) | (enc_e4m3(f[2]) << 16) | (enc_e4m3(f[3]) << 24);
  out[1] = enc_e4m3(f[4]) | (enc_e4m3(f[5]) << 8) | (enc_e4m3(f[6]) << 16) | (enc_e4m3(f[7]) << 24);
#endif
}

// decode 2 fp8 bytes (packed in ushort) -> 2 floats
__device__ __forceinline__ void unpack2_fp8(unsigned short s, float& x, float& y) {
#if HW_FP8
  f32x2 v = __builtin_amdgcn_cvt_pk_f32_fp8((int)(unsigned int)s, false);
  x = v[0]; y = v[1];
#else
  x = dec_e4m3(s & 0xFFu);
  y = dec_e4m3((s >> 8) & 0xFFu);
#endif
}

__device__ __forceinline__ float silu_f(float x) {
  return x * __builtin_amdgcn_rcpf(1.0f + __expf(-x));
}

// ---------------------------------------------------------------------------
// Weight repack: f32 [128][128] row-major -> bf16 MFMA B-fragment layout.
// ---------------------------------------------------------------------------
struct PackSrc { const float* p[24]; };

__global__ void repack_kernel(PackSrc ps, unsigned short* __restrict__ dst) {
  const float* src = ps.p[blockIdx.x];
  unsigned short* d = dst + (size_t)blockIdx.x * 16384;
  for (int s = threadIdx.x; s < 2048; s += 256) {
    const int ct = s >> 8;
    const int kc = (s >> 6) & 3;
    const int lane = s & 63;
    const int r0 = kc * 32 + (lane >> 4) * 8;
    const int col = ct * 16 + (lane & 15);
    uint4 u;
    u.x = f2b2(src[(r0 + 0) * H + col], src[(r0 + 1) * H + col]);
    u.y = f2b2(src[(r0 + 2) * H + col], src[(r0 + 3) * H + col]);
    u.z = f2b2(src[(r0 + 4) * H + col], src[(r0 + 5) * H + col]);
    u.w = f2b2(src[(r0 + 6) * H + col], src[(r0 + 7) * H + col]);
    *(uint4*)(d + s * 8) = u;
  }
}

__global__ void embed_kernel(const int* __restrict__ atom_num, const float* __restrict__ emb,
                             unsigned short* __restrict__ h0) {
  const int idx = blockIdx.x * 256 + threadIdx.x;
  const int n = idx >> 6;
  const int c = (idx & 63) * 2;
  const float* src = emb + (size_t)atom_num[n] * H + c;
  *(unsigned int*)(h0 + (size_t)n * H + c) = f2b2(src[0], src[1]);
}

__global__ void zero_int_kernel(int4* __restrict__ p, int n4) {
  const int i = blockIdx.x * 256 + threadIdx.x;
  if (i < n4) p[i] = make_int4(0, 0, 0, 0);
}

// ---------------------------------------------------------------------------
// CSR: u-sorted edge order. Cells: [set*NATOM + atom]. Positions in [0,2E).
// ---------------------------------------------------------------------------
__global__ void count_kernel(const int* __restrict__ u1, const int* __restrict__ v1,
                             const int* __restrict__ u2, const int* __restrict__ v2,
                             int* __restrict__ degU, int* __restrict__ degV) {
  const int e = blockIdx.x * 256 + threadIdx.x;
  atomicAdd(degU + u1[e], 1);
  atomicAdd(degU + NATOM + u2[e], 1);
  atomicAdd(degV + v1[e], 1);
  atomicAdd(degV + NATOM + v2[e], 1);
}

__global__ void scan_phase1(const int* __restrict__ deg, int* __restrict__ partials,
                            int ncells) {
  __shared__ int sh[256];
  const int t = threadIdx.x;
  const int base = blockIdx.x * 1024 + t * 4;
  int s = 0;
#pragma unroll
  for (int j = 0; j < 4; ++j) { const int i = base + j; if (i < ncells) s += deg[i]; }
  sh[t] = s;
  __syncthreads();
  for (int off = 128; off > 0; off >>= 1) {
    if (t < off) sh[t] += sh[t + off];
    __syncthreads();
  }
  if (t == 0) partials[blockIdx.x] = sh[0];
}

__global__ void scan_phase2(int* __restrict__ partials, int np) {
  __shared__ int sh[1024];
  const int t = threadIdx.x;
  const int v = t < np ? partials[t] : 0;
  sh[t] = v;
  __syncthreads();
  for (int off = 1; off < 1024; off <<= 1) {
    int x = 0;
    if (t >= off) x = sh[t - off];
    __syncthreads();
    sh[t] += x;
    __syncthreads();
  }
  if (t < np) partials[t] = sh[t] - v;  // exclusive
}

__global__ void scan_phase3(const int* __restrict__ deg, const int* __restrict__ partials,
                            int* __restrict__ start, int* __restrict__ cursor, int ncells) {
  __shared__ int sh[256];
  const int t = threadIdx.x;
  const int base = blockIdx.x * 1024 + t * 4;
  int v[4];
  int s = 0;
#pragma unroll
  for (int j = 0; j < 4; ++j) {
    const int i = base + j;
    v[j] = (i < ncells) ? deg[i] : 0;
    s += v[j];
  }
  sh[t] = s;
  __syncthreads();
  const int own = s;
  for (int off = 1; off < 256; off <<= 1) {
    int x = 0;
    if (t >= off) x = sh[t - off];
    __syncthreads();
    sh[t] += x;
    __syncthreads();
  }
  int o = partials[blockIdx.x] + sh[t] - own;
#pragma unroll
  for (int j = 0; j < 4; ++j) {
    const int i = base + j;
    if (i < ncells) {
      start[i] = o;
      cursor[i] = o;
      o += v[j];
      if (i == ncells - 1) start[ncells] = o;
    }
  }
}

// Fused fill: u-sorted placement + v-list in one pass. npass=4 (uvS/disS
// write-merge locality is per-atom, preserved at any npass).
__global__ void fill_fused_kernel(const int* __restrict__ u1, const int* __restrict__ v1,
                                  const float* __restrict__ dis1,
                                  const int* __restrict__ u2, const int* __restrict__ v2,
                                  const float* __restrict__ dis2,
                                  int* __restrict__ curU, int* __restrict__ curV,
                                  unsigned int* __restrict__ uvS,
                                  float* __restrict__ disS, int* __restrict__ listV,
                                  int npass) {
  const int apb = (NATOM + npass - 1) / npass;
  for (int p = 0; p < npass; ++p) {
    const int lo = p * apb, hi = lo + apb;
    for (int e = blockIdx.x * 256 + threadIdx.x; e < NEDGE; e += gridDim.x * 256) {
      int a = __builtin_nontemporal_load(u1 + e);
      if (a >= lo && a < hi) {
        const int v = __builtin_nontemporal_load(v1 + e);
        const int su = atomicAdd(curU + a, 1);
        uvS[su] = (unsigned int)a | ((unsigned int)v << 16);
        disS[su] = __builtin_nontemporal_load(dis1 + e);
        const int sv = atomicAdd(curV + v, 1);
        listV[sv] = su;
      }
      a = __builtin_nontemporal_load(u2 + e);
      if (a >= lo && a < hi) {
        const int v = __builtin_nontemporal_load(v2 + e);
        const int su = atomicAdd(curU + NATOM + a, 1);
        uvS[su] = (unsigned int)a | ((unsigned int)v << 16);
        disS[su] = __builtin_nontemporal_load(dis2 + e);
        const int sv = atomicAdd(curV + NATOM + v, 1);
        listV[sv] = su;
      }
    }
  }
}

// ---------------------------------------------------------------------------
// Precompute: hu = h@Wu, hv = h@Wv per atom (bf16 out). 16x less FLOP than
// recomputing per edge (R10/R11-verified).
// ---------------------------------------------------------------------------
__global__ __launch_bounds__(256, 2)
void pre_kernel(const unsigned short* __restrict__ h,
                const unsigned short* __restrict__ pWu, const unsigned short* __restrict__ pWv,
                unsigned short* __restrict__ hu, unsigned short* __restrict__ hv) {
  __shared__ __attribute__((aligned(16))) unsigned short sH[64][136];
  __shared__ __attribute__((aligned(16))) unsigned short sO[64][136];

  const int tid = threadIdx.x;
  const int wave = tid >> 6;
  const int lane = tid & 63;
  const int l15 = lane & 15;
  const int quad = lane >> 4;
  const int r0 = tid >> 4;
  const int ch = tid & 15;

  short8 wU[2][4], wV[2][4];
#pragma unroll
  for (int ct = 0; ct < 2; ++ct) {
#pragma unroll
    for (int kc = 0; kc < 4; ++kc) {
      const int off = (((wave * 2 + ct) * 4 + kc) * 64 + lane) * 8;
      wU[ct][kc] = *(const short8*)(pWu + off);
      wV[ct][kc] = *(const short8*)(pWv + off);
    }
  }

  const int n0 = blockIdx.x * 64;
#pragma unroll
  for (int it = 0; it < 4; ++it) {
    const int r = r0 + it * 16;
    int g = n0 + r; if (g >= NATOM) g = NATOM - 1;
    *(uint4*)(&sH[r][ch * 8]) = *(const uint4*)(h + (size_t)g * H + ch * 8);
  }
  __syncthreads();

  f32x4 au[4][2], av[4][2];
#pragma unroll
  for (int rt = 0; rt < 4; ++rt)
#pragma unroll
    for (int ct = 0; ct < 2; ++ct) {
      au[rt][ct] = (f32x4){0.f, 0.f, 0.f, 0.f};
      av[rt][ct] = (f32x4){0.f, 0.f, 0.f, 0.f};
    }
#pragma unroll
  for (int kc = 0; kc < 4; ++kc) {
#pragma unroll
    for (int rt = 0; rt < 4; ++rt) {
      const short8 a = *(const short8*)(&sH[rt * 16 + l15][kc * 32 + quad * 8]);
#pragma unroll
      for (int ct = 0; ct < 2; ++ct) {
        au[rt][ct] = MFMA16(a, wU[ct][kc], au[rt][ct]);
        av[rt][ct] = MFMA16(a, wV[ct][kc], av[rt][ct]);
      }
    }
  }
  __syncthreads();

  // hu out
#pragma unroll
  for (int rt = 0; rt < 4; ++rt) {
#pragma unroll
    for (int ct = 0; ct < 2; ++ct) {
      const int col = wave * 32 + ct * 16 + l15;
#pragma unroll
      for (int r = 0; r < 4; r += 2) {
        const int row = rt * 16 + quad * 4 + r;
        const unsigned int p = f2b2(au[rt][ct][r], au[rt][ct][r + 1]);
        sO[row][col] = (unsigned short)p;
        sO[row + 1][col] = (unsigned short)(p >> 16);
      }
    }
  }
  __syncthreads();
#pragma unroll
  for (int it = 0; it < 4; ++it) {
    const int r = r0 + it * 16;
    const int g = n0 + r;
    if (g < NATOM)
      *(uint4*)(hu + (size_t)g * H + ch * 8) = *(const uint4*)(&sO[r][ch * 8]);
  }
  __syncthreads();

  // hv out
#pragma unroll
  for (int rt = 0; rt < 4; ++rt) {
#pragma unroll
    for (int ct = 0; ct < 2; ++ct) {
      const int col = wave * 32 + ct * 16 + l15;
#pragma unroll
      for (int r = 0; r < 4; r += 2) {
        const int row = rt * 16 + quad * 4 + r;
        const unsigned int p = f2b2(av[rt][ct][r], av[rt][ct][r + 1]);
        sO[row][col] = (unsigned short)p;
        sO[row + 1][col] = (unsigned short)(p >> 16);
      }
    }
  }
  __syncthreads();
#pragma unroll
  for (int it = 0; it < 4; ++it) {
    const int r = r0 + it * 16;
    const int g = n0 + r;
    if (g < NATOM)
      *(uint4*)(hv + (size_t)g * H + ch * 8) = *(const uint4*)(&sO[r][ch * 8]);
  }
}

// ---------------------------------------------------------------------------
// Edge: ep0 gather-add + GEMM2 + GEMM3; fp8 msg. Store remap: each thread
// packs 16 fp8 bytes and issues ONE 16B NT store (8 threads/row, 2 iters of
// 256) — 16B/lane bursts instead of 8B.
// ---------------------------------------------------------------------------
__global__ __launch_bounds__(256, 3)
void edge_kernel(const unsigned short* __restrict__ hu,
                 const unsigned short* __restrict__ hv,
                 const unsigned int* __restrict__ uv,
                 const float* __restrict__ dis,
                 const unsigned short* __restrict__ pW2, const unsigned short* __restrict__ pW3,
                 const float* __restrict__ Wdis, const float* __restrict__ bb1,
                 const float* __restrict__ bb2, const float* __restrict__ bb3,
                 unsigned char* __restrict__ msg, int eBase, int nTiles) {
  __shared__ __attribute__((aligned(16))) unsigned short sA[64][136];
  __shared__ __attribute__((aligned(16))) unsigned short sB[64][136];

  const int tid = threadIdx.x;
  const int wave = tid >> 6;
  const int lane = tid & 63;
  const int l15 = lane & 15;
  const int quad = lane >> 4;
  const int r0 = tid >> 4;
  const int ch = tid & 15;

  short8 wW2[2][4], wW3[2][4];
#pragma unroll
  for (int ct = 0; ct < 2; ++ct) {
#pragma unroll
    for (int kc = 0; kc < 4; ++kc) {
      const int off = (((wave * 2 + ct) * 4 + kc) * 64 + lane) * 8;
      wW2[ct][kc] = *(const short8*)(pW2 + off);
      wW3[ct][kc] = *(const short8*)(pW3 + off);
    }
  }
  float wd8[8], b18[8];
#pragma unroll
  for (int k = 0; k < 8; ++k) { wd8[k] = Wdis[ch * 8 + k]; b18[k] = bb1[ch * 8 + k]; }
  float vb2[2], vb3[2];
#pragma unroll
  for (int ct = 0; ct < 2; ++ct) {
    const int col = wave * 32 + ct * 16 + l15;
    vb2[ct] = bb2[col]; vb3[ct] = bb3[col];
  }

  const int stride = gridDim.x;
  int tile = blockIdx.x;

  uint4 pfU[4], pfV[4];
  float pfD[4];
  if (tile < nTiles) {
    const int e0 = eBase + tile * 64;
#pragma unroll
    for (int it = 0; it < 4; ++it) {
      const int e = e0 + r0 + it * 16;
      const unsigned int p = uv[e];
      pfU[it] = *(const uint4*)(hu + (size_t)(p & 0xFFFFu) * H + ch * 8);
      pfV[it] = *(const uint4*)(hv + (size_t)(p >> 16) * H + ch * 8);
      pfD[it] = dis[e];
    }
  }

  for (; tile < nTiles; tile += stride) {
    // ep0: t1 = silu(hu[u] + hv[v] + dis*wd + b1) -> sA (thread-local rows)
#pragma unroll
    for (int it = 0; it < 4; ++it) {
      const int rr = r0 + it * 16;
      const float d = pfD[it];
      const unsigned int ua[4] = {pfU[it].x, pfU[it].y, pfU[it].z, pfU[it].w};
      const unsigned int va[4] = {pfV[it].x, pfV[it].y, pfV[it].z, pfV[it].w};
#pragma unroll
      for (int j = 0; j < 4; ++j) {
        const float x0 = b2f((unsigned short)ua[j]) + b2f((unsigned short)va[j]) +
                         d * wd8[2 * j] + b18[2 * j];
        const float x1 = b2f((unsigned short)(ua[j] >> 16)) + b2f((unsigned short)(va[j] >> 16)) +
                         d * wd8[2 * j + 1] + b18[2 * j + 1];
        *(unsigned int*)(&sA[rr][ch * 8 + 2 * j]) = f2b2(silu_f(x0), silu_f(x1));
      }
    }
    // issue next tile's gathers (fly during GEMM2/GEMM3)
    const int tileN = tile + stride;
    if (tileN < nTiles) {
      const int e0n = eBase + tileN * 64;
#pragma unroll
      for (int it = 0; it < 4; ++it) {
        const int e = e0n + r0 + it * 16;
        const unsigned int p = uv[e];
        pfU[it] = *(const uint4*)(hu + (size_t)(p & 0xFFFFu) * H + ch * 8);
        pfV[it] = *(const uint4*)(hv + (size_t)(p >> 16) * H + ch * 8);
        pfD[it] = dis[e];
      }
    }
    __syncthreads();  // b1: t1 visible

    // GEMM2: t1@W2
    f32x4 acc[4][2];
#pragma unroll
    for (int rt = 0; rt < 4; ++rt)
#pragma unroll
      for (int ct = 0; ct < 2; ++ct) acc[rt][ct] = (f32x4){0.f, 0.f, 0.f, 0.f};
#pragma unroll
    for (int kc = 0; kc < 4; ++kc) {
#pragma unroll
      for (int rt = 0; rt < 4; ++rt) {
        const short8 a = *(const short8*)(&sA[rt * 16 + l15][kc * 32 + quad * 8]);
#pragma unroll
        for (int ct = 0; ct < 2; ++ct) acc[rt][ct] = MFMA16(a, wW2[ct][kc], acc[rt][ct]);
      }
    }
    // ep2: t2 = silu(acc + b2) -> sB
#pragma unroll
    for (int rt = 0; rt < 4; ++rt) {
#pragma unroll
      for (int ct = 0; ct < 2; ++ct) {
        const int col = wave * 32 + ct * 16 + l15;
#pragma unroll
        for (int r = 0; r < 4; r += 2) {
          const int row = rt * 16 + quad * 4 + r;
          const unsigned int p = f2b2(silu_f(acc[rt][ct][r] + vb2[ct]),
                                      silu_f(acc[rt][ct][r + 1] + vb2[ct]));
          sB[row][col] = (unsigned short)p;
          sB[row + 1][col] = (unsigned short)(p >> 16);
        }
      }
    }
    __syncthreads();  // b2: t2 visible; GEMM2 reads of sA done

    // GEMM3: t2@W3
#pragma unroll
    for (int rt = 0; rt < 4; ++rt)
#pragma unroll
      for (int ct = 0; ct < 2; ++ct) acc[rt][ct] = (f32x4){0.f, 0.f, 0.f, 0.f};
#pragma unroll
    for (int kc = 0; kc < 4; ++kc) {
#pragma unroll
      for (int rt = 0; rt < 4; ++rt) {
        const short8 a = *(const short8*)(&sB[rt * 16 + l15][kc * 32 + quad * 8]);
#pragma unroll
        for (int ct = 0; ct < 2; ++ct) acc[rt][ct] = MFMA16(a, wW3[ct][kc], acc[rt][ct]);
      }
    }
    // m -> sA (bf16 staging)
#pragma unroll
    for (int rt = 0; rt < 4; ++rt) {
#pragma unroll
      for (int ct = 0; ct < 2; ++ct) {
        const int col = wave * 32 + ct * 16 + l15;
#pragma unroll
        for (int r = 0; r < 4; r += 2) {
          const int row = rt * 16 + quad * 4 + r;
          const unsigned int p = f2b2(acc[rt][ct][r] + vb3[ct],
                                      acc[rt][ct][r + 1] + vb3[ct]);
          sA[row][col] = (unsigned short)p;
          sA[row + 1][col] = (unsigned short)(p >> 16);
        }
      }
    }
    __syncthreads();  // b3: m assembled
    // cooperative fp8 stores: 16B/lane (8 threads/row; 2 x 256 threads)
#pragma unroll
    for (int it = 0; it < 2; ++it) {
      const int idx = tid + it * 256;
      const int row = idx >> 3;          // [0,64)
      const int b = (idx & 7) * 16;      // fp8 byte offset in row
      unsigned int w[8], o[4];
      *(uint4*)w       = *(const uint4*)(&sA[row][b]);
      *(uint4*)(w + 4) = *(const uint4*)(&sA[row][b + 8]);
      pack8_fp8(w, o);
      pack8_fp8(w + 4, o + 2);
      uint4n ov; ov.x = o[0]; ov.y = o[1]; ov.z = o[2]; ov.w = o[3];
      __builtin_nontemporal_store(ov,
          (uint4n*)(msg + (size_t)(tile * 64 + row) * H + b));
    }
    __syncthreads();  // b4: sA reads done before next ep0 overwrites
  }
}

// ---------------------------------------------------------------------------
// Aggregate (nc=1, fp8 msg): u-half streams contiguous 128B rows; v-half
// NT-gathers. Each lane owns 2 cols (2 fp8 bytes/row). Accum f32.
// ---------------------------------------------------------------------------
__global__ __launch_bounds__(256)
void aggregate_kernel(const int* __restrict__ startU, const int* __restrict__ startV,
                      const int* __restrict__ listV,
                      const unsigned char* __restrict__ msg, int eBase, int cellBase,
                      unsigned short* __restrict__ aout) {
  const int atom = blockIdx.x * 4 + (threadIdx.x >> 6);
  const int lane = threadIdx.x & 63;
  const int su = startU[cellBase + atom] - eBase;
  const int eu = startU[cellBase + atom + 1] - eBase;
  const int sv = startV[cellBase + atom];
  const int ev = startV[cellBase + atom + 1];
  float ax = 0.f, ay = 0.f;
  const unsigned char* mp = msg + lane * 2;

  // contiguous u-half: 4 rows in flight
  int p = su;
  for (; p + 3 < eu; p += 4) {
    unsigned short s[4];
#pragma unroll
    for (int j = 0; j < 4; ++j) s[j] = *(const unsigned short*)(mp + (size_t)(p + j) * H);
#pragma unroll
    for (int j = 0; j < 4; ++j) {
      float x, y; unpack2_fp8(s[j], x, y);
      ax += x; ay += y;
    }
  }
  for (; p < eu; ++p) {
    const unsigned short s0 = *(const unsigned short*)(mp + (size_t)p * H);
    float x, y; unpack2_fp8(s0, x, y);
    ax += x; ay += y;
  }

  // random v-half: 8-deep NT gather
  int i = sv;
  for (; i + 7 < ev; i += 8) {
    int r[8];
#pragma unroll
    for (int j = 0; j < 8; ++j) r[j] = __builtin_nontemporal_load(listV + i + j) - eBase;
    unsigned short s[8];
#pragma unroll
    for (int j = 0; j < 8; ++j)
      s[j] = __builtin_nontemporal_load((const unsigned short*)(mp + (size_t)r[j] * H));
#pragma unroll
    for (int j = 0; j < 8; ++j) {
      float x, y; unpack2_fp8(s[j], x, y);
      ax += x; ay += y;
    }
  }
  for (; i < ev; ++i) {
    const int r = __builtin_nontemporal_load(listV + i) - eBase;
    const unsigned short s0 =
        __builtin_nontemporal_load((const unsigned short*)(mp + (size_t)r * H));
    float x, y; unpack2_fp8(s0, x, y);
    ax += x; ay += y;
  }

  *(unsigned int*)(aout + (size_t)atom * H + lane * 2) = f2b2(ax, ay);
}

// ---------------------------------------------------------------------------
// Atom update: h_new = h + silu(h@Wh + a1@Wa1 + a2@Wa2 + b1)@W2 + b2
// ---------------------------------------------------------------------------
__global__ __launch_bounds__(256, 2)
void update_kernel(const unsigned short* __restrict__ hin,
                   const unsigned short* __restrict__ a1, const unsigned short* __restrict__ a2,
                   const unsigned short* __restrict__ pWh, const unsigned short* __restrict__ pWa1,
                   const unsigned short* __restrict__ pWa2, const unsigned short* __restrict__ pWo,
                   const float* __restrict__ b1, const float* __restrict__ b2,
                   unsigned short* __restrict__ hout) {
  __shared__ __attribute__((aligned(16))) unsigned short sH[64][136];
  __shared__ __attribute__((aligned(16))) unsigned short s1[64][136];
  __shared__ __attribute__((aligned(16))) unsigned short s2[64][136];

  const int tid = threadIdx.x;
  const int wave = tid >> 6;
  const int lane = tid & 63;
  const int l15 = lane & 15;
  const int quad = lane >> 4;

  short8 wWh[2][4], wW1[2][4], wW2m[2][4], wWo[2][4];
#pragma unroll
  for (int ct = 0; ct < 2; ++ct) {
#pragma unroll
    for (int kc = 0; kc < 4; ++kc) {
      const int off = (((wave * 2 + ct) * 4 + kc) * 64 + lane) * 8;
      wWh[ct][kc] = *(const short8*)(pWh + off);
      wW1[ct][kc] = *(const short8*)(pWa1 + off);
      wW2m[ct][kc] = *(const short8*)(pWa2 + off);
      wWo[ct][kc] = *(const short8*)(pWo + off);
    }
  }
  float vb1[2], vb2[2];
#pragma unroll
  for (int ct = 0; ct < 2; ++ct) {
    const int col = wave * 32 + ct * 16 + l15;
    vb1[ct] = b1[col]; vb2[ct] = b2[col];
  }

  const int n0 = blockIdx.x * 64;
#pragma unroll
  for (int it = 0; it < 4; ++it) {
    const int r = (tid >> 4) + it * 16;
    const int ch = tid & 15;
    int g = n0 + r; if (g >= NATOM) g = NATOM - 1;
    *(uint4*)(&sH[r][ch * 8]) = *(const uint4*)(hin + (size_t)g * H + ch * 8);
    *(uint4*)(&s1[r][ch * 8]) = *(const uint4*)(a1 + (size_t)g * H + ch * 8);
    *(uint4*)(&s2[r][ch * 8]) = *(const uint4*)(a2 + (size_t)g * H + ch * 8);
  }
  __syncthreads();

  f32x4 acc[4][2];
#pragma unroll
  for (int rt = 0; rt < 4; ++rt)
#pragma unroll
    for (int ct = 0; ct < 2; ++ct) acc[rt][ct] = (f32x4){0.f, 0.f, 0.f, 0.f};

#pragma unroll
  for (int kc = 0; kc < 4; ++kc) {
#pragma unroll
    for (int rt = 0; rt < 4; ++rt) {
      const short8 ah = *(const short8*)(&sH[rt * 16 + l15][kc * 32 + quad * 8]);
      const short8 aa1 = *(const short8*)(&s1[rt * 16 + l15][kc * 32 + quad * 8]);
      const short8 aa2 = *(const short8*)(&s2[rt * 16 + l15][kc * 32 + quad * 8]);
#pragma unroll
      for (int ct = 0; ct < 2; ++ct) {
        acc[rt][ct] = MFMA16(ah, wWh[ct][kc], acc[rt][ct]);
        acc[rt][ct] = MFMA16(aa1, wW1[ct][kc], acc[rt][ct]);
        acc[rt][ct] = MFMA16(aa2, wW2m[ct][kc], acc[rt][ct]);
      }
    }
  }
  __syncthreads();

#pragma unroll
  for (int rt = 0; rt < 4; ++rt) {
#pragma unroll
    for (int ct = 0; ct < 2; ++ct) {
      const int col = wave * 32 + ct * 16 + l15;
#pragma unroll
      for (int r = 0; r < 4; r += 2) {
        const int row = rt * 16 + quad * 4 + r;
        const unsigned int p = f2b2(silu_f(acc[rt][ct][r] + vb1[ct]),
                                    silu_f(acc[rt][ct][r + 1] + vb1[ct]));
        s1[row][col] = (unsigned short)p;
        s1[row + 1][col] = (unsigned short)(p >> 16);
      }
    }
  }
  __syncthreads();

#pragma unroll
  for (int rt = 0; rt < 4; ++rt)
#pragma unroll
    for (int ct = 0; ct < 2; ++ct) acc[rt][ct] = (f32x4){0.f, 0.f, 0.f, 0.f};
#pragma unroll
  for (int kc = 0; kc < 4; ++kc) {
#pragma unroll
    for (int rt = 0; rt < 4; ++rt) {
      const short8 a = *(const short8*)(&s1[rt * 16 + l15][kc * 32 + quad * 8]);
#pragma unroll
      for (int ct = 0; ct < 2; ++ct) acc[rt][ct] = MFMA16(a, wWo[ct][kc], acc[rt][ct]);
    }
  }
  __syncthreads();
#pragma unroll
  for (int rt = 0; rt < 4; ++rt) {
#pragma unroll
    for (int ct = 0; ct < 2; ++ct) {
      const int col = wave * 32 + ct * 16 + l15;
#pragma unroll
      for (int r = 0; r < 4; r += 2) {
        const int row = rt * 16 + quad * 4 + r;
        const float v0 = b2f(sH[row][col]) + acc[rt][ct][r] + vb2[ct];
        const float v1 = b2f(sH[row + 1][col]) + acc[rt][ct][r + 1] + vb2[ct];
        const unsigned int p = f2b2(v0, v1);
        s2[row][col] = (unsigned short)p;
        s2[row + 1][col] = (unsigned short)(p >> 16);
      }
    }
  }
  __syncthreads();
#pragma unroll
  for (int it = 0; it < 4; ++it) {
    const int r = (tid >> 4) + it * 16;
    const int ch = tid & 15;
    const int g = n0 + r;
    if (g < NATOM)
      *(uint4*)(hout + (size_t)g * H + ch * 8) = *(const uint4*)(&s2[r][ch * 8]);
  }
}

// ---------------------------------------------------------------------------
__global__ void out_kernel(const unsigned short* __restrict__ h,
                           const float* __restrict__ outW, const float* __restrict__ outb,
                           float* __restrict__ out) {
  const int atom = blockIdx.x * 4 + (threadIdx.x >> 6);
  const int lane = threadIdx.x & 63;
  float s0 = 0.f, s1 = 0.f, s2 = 0.f;
#pragma unroll
  for (int kk = 0; kk < 2; ++kk) {
    const int k = lane + kk * 64;
    const float hv = b2f(h[(size_t)atom * H + k]);
    s0 += hv * outW[k * 3 + 0];
    s1 += hv * outW[k * 3 + 1];
    s2 += hv * outW[k * 3 + 2];
  }
#pragma unroll
  for (int off = 32; off > 0; off >>= 1) {
    s0 += __shfl_down(s0, off);
    s1 += __shfl_down(s1, off);
    s2 += __shfl_down(s2, off);
  }
  if (lane == 0) {
    out[atom * 3 + 0] = s0 + outb[0];
    out[atom * 3 + 1] = s1 + outb[1];
    out[atom * 3 + 2] = s2 + outb[2];
  }
}

// ---------------------------------------------------------------------------
// Workspace (nc=1, fp8 msg): pw 0.79 + h0/a1/a2 38.4 + hu/hv 25.6 +
// uvS/disS/listV 19.2 + startU/V 0.8 + msg(fp8) 102.4 = 187.2MB << 256MiB.
// ---------------------------------------------------------------------------
extern "C" void kernel_launch(void* const* d_in, const int* in_sizes, int n_in,
                              void* d_out, int out_size, void* d_ws, size_t ws_size,
                              hipStream_t stream) {
  const int* atom_num = (const int*)d_in[0];
  const float* dis1 = (const float*)d_in[1];
  const float* dis2 = (const float*)d_in[2];
  const int* id1u = (const int*)d_in[3];
  const int* id1v = (const int*)d_in[4];
  const int* id2u = (const int*)d_in[5];
  const int* id2v = (const int*)d_in[6];
  const float* emb = (const float*)d_in[7];
  const float* Wu = (const float*)d_in[8];
  const float* Wv = (const float*)d_in[9];
  const float* Wdis = (const float*)d_in[10];
  const float* eb1 = (const float*)d_in[11];
  const float* eW2 = (const float*)d_in[12];
  const float* eb2 = (const float*)d_in[13];
  const float* eW3 = (const float*)d_in[14];
  const float* eb3 = (const float*)d_in[15];
  const float* Wh = (const float*)d_in[16];
  const float* Wa1 = (const float*)d_in[17];
  const float* Wa2 = (const float*)d_in[18];
  const float* ub1 = (const float*)d_in[19];
  const float* uW2 = (const float*)d_in[20];
  const float* ub2 = (const float*)d_in[21];
  const float* outW = (const float*)d_in[22];
  const float* outb = (const float*)d_in[23];

  auto pad = [](size_t x) { return (x + 255) & ~(size_t)255; };
  const int N2 = 2 * NATOM;
  const int nparts = (N2 + 1023) / 1024;

  char* ws = (char*)d_ws;
  size_t off = 0;
  auto take = [&](size_t bytes) { char* p = ws + off; off += pad(bytes); return p; };
  unsigned short* pw   = (unsigned short*)take(786432);
  unsigned short* h0   = (unsigned short*)take((size_t)NATOM * H * 2);
  unsigned short* a1   = (unsigned short*)take((size_t)NATOM * H * 2);
  unsigned short* a2   = (unsigned short*)take((size_t)NATOM * H * 2);
  unsigned short* hu   = (unsigned short*)take((size_t)NATOM * H * 2);
  unsigned short* hv   = (unsigned short*)take((size_t)NATOM * H * 2);
  unsigned int* uvS    = (unsigned int*)take((size_t)2 * NEDGE * 4);  // u|v<<16
  float* disS          = (float*)take((size_t)2 * NEDGE * 4);
  int* listV           = (int*)take((size_t)2 * NEDGE * 4);
  int* startU          = (int*)take(((size_t)N2 + 1) * 4);
  int* startV          = (int*)take(((size_t)N2 + 1) * 4);
  char* ovlRegion      = ws + off;  // fp8 msg, overlapped with CSR scratch
  unsigned char* msg   = (unsigned char*)ovlRegion;           // E*128B = 102.4MB
  int* degU            = (int*)ovlRegion;
  int* degV            = degU + N2;
  int* curU            = degV + N2;
  int* curV            = curU + N2;
  int* partU           = curV + N2;
  int* partV           = partU + 1024;

  PackSrc ps;
  for (int i = 0; i < 4; ++i) {
    ps.p[i] = Wu + i * 16384;
    ps.p[4 + i] = Wv + i * 16384;
    ps.p[8 + i] = eW2 + i * 16384;
    ps.p[12 + i] = eW3 + i * 16384;
  }
  for (int j = 0; j < 2; ++j) {
    ps.p[16 + j] = Wh + j * 16384;
    ps.p[18 + j] = Wa1 + j * 16384;
    ps.p[20 + j] = Wa2 + j * 16384;
    ps.p[22 + j] = uW2 + j * 16384;
  }
  repack_kernel<<<24, 256, 0, stream>>>(ps, pw);
  embed_kernel<<<12500, 256, 0, stream>>>(atom_num, emb, h0);

  // CSR build (u-sorted positions + v-side position lists, fused fill)
  {
    const int n4 = (int)(((size_t)2 * N2 * 4 + 15) / 16);
    zero_int_kernel<<<(n4 + 255) / 256, 256, 0, stream>>>((int4*)degU, n4);
    count_kernel<<<NEDGE / 256, 256, 0, stream>>>(id1u, id1v, id2u, id2v, degU, degV);
    scan_phase1<<<nparts, 256, 0, stream>>>(degU, partU, N2);
    scan_phase2<<<1, 1024, 0, stream>>>(partU, nparts);
    scan_phase3<<<nparts, 256, 0, stream>>>(degU, partU, startU, curU, N2);
    scan_phase1<<<nparts, 256, 0, stream>>>(degV, partV, N2);
    scan_phase2<<<1, 1024, 0, stream>>>(partV, nparts);
    scan_phase3<<<nparts, 256, 0, stream>>>(degV, partV, startV, curV, N2);
    fill_fused_kernel<<<1024, 256, 0, stream>>>(id1u, id1v, dis1, id2u, id2v, dis2,
                                                curU, curV, uvS, disS, listV, 4);
  }

  const int upd_grid = (NATOM + 63) / 64;   // 782
  const int AGG_GRID = NATOM / 4;
  const int nTiles = NEDGE / 64;            // 12500
  const int EDGE_GRID = 768;                // 3 blocks/CU

  const unsigned short* pWu_[4] = {pw, pw + 16384, pw + 2 * 16384, pw + 3 * 16384};
  const unsigned short* pWv_[4] = {pw + 4 * 16384, pw + 5 * 16384, pw + 6 * 16384, pw + 7 * 16384};
  const unsigned short* pW2_[4] = {pw + 8 * 16384, pw + 9 * 16384, pw + 10 * 16384, pw + 11 * 16384};
  const unsigned short* pW3_[4] = {pw + 12 * 16384, pw + 13 * 16384, pw + 14 * 16384, pw + 15 * 16384};

  for (int layer = 0; layer < 2; ++layer) {
    for (int set = 0; set < 2; ++set) {
      const int blk = layer * 2 + set;
      const int eBase = set * NEDGE;
      const int cellBase = set * NATOM;
      unsigned short* aout = set == 0 ? a1 : a2;
      pre_kernel<<<upd_grid, 256, 0, stream>>>(h0, pWu_[blk], pWv_[blk], hu, hv);
      edge_kernel<<<EDGE_GRID, 256, 0, stream>>>(hu, hv, uvS, disS,
          pW2_[blk], pW3_[blk],
          Wdis + blk * H, eb1 + blk * H, eb2 + blk * H, eb3 + blk * H,
          msg, eBase, nTiles);
      aggregate_kernel<<<AGG_GRID, 256, 0, stream>>>(startU, startV, listV, msg,
          eBase, cellBase, aout);
    }
    update_kernel<<<upd_grid, 256, 0, stream>>>(h0, a1, a2,
        pw + (16 + layer) * 16384, pw + (18 + layer) * 16384,
        pw + (20 + layer) * 16384, pw + (22 + layer) * 16384,
        ub1 + layer * H, ub2 + layer * H, h0);
  }

  out_kernel<<<12500, 256, 0, stream>>>(h0, outW, outb, (float*)d_out);
}

// Round 15
// 1302.344 us; speedup vs baseline: 1.2721x; 1.0268x over previous
//
#include <hip/hip_runtime.h>

#define H 128
#define NATOM 50000
#define NEDGE 800000

typedef __attribute__((ext_vector_type(8))) short short8;
typedef __attribute__((ext_vector_type(4))) float f32x4;
typedef __attribute__((ext_vector_type(2))) float f32x2;
typedef __attribute__((ext_vector_type(4))) unsigned int uint4n;  // 16B NT store

#define MFMA16(a, b, c) __builtin_amdgcn_mfma_f32_16x16x32_bf16((a), (b), (c), 0, 0, 0)

__device__ __forceinline__ unsigned short f2b(float f) {
  unsigned int u = __float_as_uint(f);
  unsigned int r = (u + 0x7FFFu + ((u >> 16) & 1u)) >> 16;
  return (unsigned short)r;
}
__device__ __forceinline__ float b2f(unsigned short b) {
  return __uint_as_float(((unsigned int)b) << 16);
}

#if __has_builtin(__builtin_amdgcn_cvt_pk_bf16_f32)
__device__ __forceinline__ unsigned int f2b2(float lo, float hi) {
  typedef __bf16 bf16x2 __attribute__((ext_vector_type(2)));
  bf16x2 r = __builtin_amdgcn_cvt_pk_bf16_f32(lo, hi);
  union { bf16x2 v; unsigned int u; } c;
  c.v = r;
  return c.u;
}
#else
__device__ __forceinline__ unsigned int f2b2(float lo, float hi) {
  return (unsigned int)f2b(lo) | ((unsigned int)f2b(hi) << 16);
}
#endif

// ---------- fp8 e4m3 (OCP fn) pack/unpack — hw cvt on gfx950, sw fallback ----
#if __has_builtin(__builtin_amdgcn_cvt_pk_fp8_f32) && __has_builtin(__builtin_amdgcn_cvt_pk_f32_fp8)
#define HW_FP8 1
#else
#define HW_FP8 0
#endif

#if !HW_FP8
__device__ __forceinline__ unsigned int enc_e4m3(float f) {  // 1 byte
  unsigned int b = __float_as_uint(f);
  unsigned int s = (b >> 31) << 7;
  float a = fabsf(f);
  if (a >= 448.f) return s | 0x7Eu;               // clamp to max finite
  if (a < 0.015625f) {                            // denormal: m*2^-9
    int m = (int)(a * 512.f + 0.5f);
    if (m > 7) m = 7;
    return s | (unsigned int)m;
  }
  unsigned int ab = b & 0x7FFFFFFFu;
  unsigned int r = ab + 0x7FFFFu + ((ab >> 20) & 1u);  // RNE at bit20
  unsigned int e = (r >> 23) - 127u + 7u;
  unsigned int m = (r >> 20) & 7u;
  if (e >= 16u) { e = 15u; m = 6u; }
  return s | (e << 3) | m;
}
__device__ __forceinline__ float dec_e4m3(unsigned int c) {
  unsigned int s = (c >> 7) & 1u, e = (c >> 3) & 15u, m = c & 7u;
  float v = (e == 0) ? (float)m * 0.001953125f
                     : __uint_as_float(((e - 7u + 127u) << 23) | (m << 20));
  return s ? -v : v;
}
#endif

// pack 8 bf16 (as 4 words) -> 8 fp8 bytes (2 words)
__device__ __forceinline__ void pack8_fp8(const unsigned int w[4], unsigned int out[2]) {
  float f[8];
#pragma unroll
  for (int j = 0; j < 4; ++j) {
    f[2 * j] = b2f((unsigned short)w[j]);
    f[2 * j + 1] = b2f((unsigned short)(w[j] >> 16));
  }
#if HW_FP8
  int w0 = __builtin_amdgcn_cvt_pk_fp8_f32(f[0], f[1], 0, false);
  w0 = __builtin_amdgcn_cvt_pk_fp8_f32(f[2], f[3], w0, true);
  int w1 = __builtin_amdgcn_cvt_pk_fp8_f32(f[4], f[5], 0, false);
  w1 = __builtin_amdgcn_cvt_pk_fp8_f32(f[6], f[7], w1, true);
  out[0] = (unsigned int)w0;
  out[1] = (unsigned int)w1;
#else
  out[0] = enc_e4m3(f[0]) | (enc_e4m3(f[1]) << 8) | (enc_e4m3(f[2]) << 16) | (enc_e4m3(f[3]) << 24);
  out[1] = enc_e4m3(f[4]) | (enc_e4m3(f[5]) << 8) | (enc_e4m3(f[6]) << 16) | (enc_e4m3(f[7]) << 24);
#endif
}

// decode 2 fp8 bytes (packed in ushort) -> 2 floats
__device__ __forceinline__ void unpack2_fp8(unsigned short s, float& x, float& y) {
#if HW_FP8
  f32x2 v = __builtin_amdgcn_cvt_pk_f32_fp8((int)(unsigned int)s, false);
  x = v[0]; y = v[1];
#else
  x = dec_e4m3(s & 0xFFu);
  y = dec_e4m3((s >> 8) & 0xFFu);
#endif
}

__device__ __forceinline__ float silu_f(float x) {
  return x * __builtin_amdgcn_rcpf(1.0f + __expf(-x));
}

// ---------------------------------------------------------------------------
// Weight repack: f32 [128][128] row-major -> bf16 MFMA B-fragment layout.
// ---------------------------------------------------------------------------
struct PackSrc { const float* p[24]; };

__global__ void repack_kernel(PackSrc ps, unsigned short* __restrict__ dst) {
  const float* src = ps.p[blockIdx.x];
  unsigned short* d = dst + (size_t)blockIdx.x * 16384;
  for (int s = threadIdx.x; s < 2048; s += 256) {
    const int ct = s >> 8;
    const int kc = (s >> 6) & 3;
    const int lane = s & 63;
    const int r0 = kc * 32 + (lane >> 4) * 8;
    const int col = ct * 16 + (lane & 15);
    uint4 u;
    u.x = f2b2(src[(r0 + 0) * H + col], src[(r0 + 1) * H + col]);
    u.y = f2b2(src[(r0 + 2) * H + col], src[(r0 + 3) * H + col]);
    u.z = f2b2(src[(r0 + 4) * H + col], src[(r0 + 5) * H + col]);
    u.w = f2b2(src[(r0 + 6) * H + col], src[(r0 + 7) * H + col]);
    *(uint4*)(d + s * 8) = u;
  }
}

__global__ void embed_kernel(const int* __restrict__ atom_num, const float* __restrict__ emb,
                             unsigned short* __restrict__ h0) {
  const int idx = blockIdx.x * 256 + threadIdx.x;
  const int n = idx >> 6;
  const int c = (idx & 63) * 2;
  const float* src = emb + (size_t)atom_num[n] * H + c;
  *(unsigned int*)(h0 + (size_t)n * H + c) = f2b2(src[0], src[1]);
}

__global__ void zero_int_kernel(int4* __restrict__ p, int n4) {
  const int i = blockIdx.x * 256 + threadIdx.x;
  if (i < n4) p[i] = make_int4(0, 0, 0, 0);
}

// ---------------------------------------------------------------------------
// CSR: u-sorted edge order. Cells: [set*NATOM + atom]. Positions in [0,2E).
// ---------------------------------------------------------------------------
__global__ void count_kernel(const int* __restrict__ u1, const int* __restrict__ v1,
                             const int* __restrict__ u2, const int* __restrict__ v2,
                             int* __restrict__ degU, int* __restrict__ degV) {
  const int e = blockIdx.x * 256 + threadIdx.x;
  atomicAdd(degU + u1[e], 1);
  atomicAdd(degU + NATOM + u2[e], 1);
  atomicAdd(degV + v1[e], 1);
  atomicAdd(degV + NATOM + v2[e], 1);
}

__global__ void scan_phase1(const int* __restrict__ deg, int* __restrict__ partials,
                            int ncells) {
  __shared__ int sh[256];
  const int t = threadIdx.x;
  const int base = blockIdx.x * 1024 + t * 4;
  int s = 0;
#pragma unroll
  for (int j = 0; j < 4; ++j) { const int i = base + j; if (i < ncells) s += deg[i]; }
  sh[t] = s;
  __syncthreads();
  for (int off = 128; off > 0; off >>= 1) {
    if (t < off) sh[t] += sh[t + off];
    __syncthreads();
  }
  if (t == 0) partials[blockIdx.x] = sh[0];
}

__global__ void scan_phase2(int* __restrict__ partials, int np) {
  __shared__ int sh[1024];
  const int t = threadIdx.x;
  const int v = t < np ? partials[t] : 0;
  sh[t] = v;
  __syncthreads();
  for (int off = 1; off < 1024; off <<= 1) {
    int x = 0;
    if (t >= off) x = sh[t - off];
    __syncthreads();
    sh[t] += x;
    __syncthreads();
  }
  if (t < np) partials[t] = sh[t] - v;  // exclusive
}

__global__ void scan_phase3(const int* __restrict__ deg, const int* __restrict__ partials,
                            int* __restrict__ start, int* __restrict__ cursor, int ncells) {
  __shared__ int sh[256];
  const int t = threadIdx.x;
  const int base = blockIdx.x * 1024 + t * 4;
  int v[4];
  int s = 0;
#pragma unroll
  for (int j = 0; j < 4; ++j) {
    const int i = base + j;
    v[j] = (i < ncells) ? deg[i] : 0;
    s += v[j];
  }
  sh[t] = s;
  __syncthreads();
  const int own = s;
  for (int off = 1; off < 256; off <<= 1) {
    int x = 0;
    if (t >= off) x = sh[t - off];
    __syncthreads();
    sh[t] += x;
    __syncthreads();
  }
  int o = partials[blockIdx.x] + sh[t] - own;
#pragma unroll
  for (int j = 0; j < 4; ++j) {
    const int i = base + j;
    if (i < ncells) {
      start[i] = o;
      cursor[i] = o;
      o += v[j];
      if (i == ncells - 1) start[ncells] = o;
    }
  }
}

// Fused fill, R25: uv+dis combined into ONE 8B record store (was two 4B
// stores to two arrays — 13x write amplification measured: WRITE 256MB for
// 19.2MB payload; scattered partial-line stores cost >=32B each). npass=4.
__global__ void fill_fused_kernel(const int* __restrict__ u1, const int* __restrict__ v1,
                                  const float* __restrict__ dis1,
                                  const int* __restrict__ u2, const int* __restrict__ v2,
                                  const float* __restrict__ dis2,
                                  int* __restrict__ curU, int* __restrict__ curV,
                                  uint2* __restrict__ euv, int* __restrict__ listV,
                                  int npass) {
  const int apb = (NATOM + npass - 1) / npass;
  for (int p = 0; p < npass; ++p) {
    const int lo = p * apb, hi = lo + apb;
    for (int e = blockIdx.x * 256 + threadIdx.x; e < NEDGE; e += gridDim.x * 256) {
      int a = __builtin_nontemporal_load(u1 + e);
      if (a >= lo && a < hi) {
        const int v = __builtin_nontemporal_load(v1 + e);
        const int su = atomicAdd(curU + a, 1);
        uint2 rec;
        rec.x = (unsigned int)a | ((unsigned int)v << 16);
        rec.y = __float_as_uint(__builtin_nontemporal_load(dis1 + e));
        euv[su] = rec;
        const int sv = atomicAdd(curV + v, 1);
        listV[sv] = su;
      }
      a = __builtin_nontemporal_load(u2 + e);
      if (a >= lo && a < hi) {
        const int v = __builtin_nontemporal_load(v2 + e);
        const int su = atomicAdd(curU + NATOM + a, 1);
        uint2 rec;
        rec.x = (unsigned int)a | ((unsigned int)v << 16);
        rec.y = __float_as_uint(__builtin_nontemporal_load(dis2 + e));
        euv[su] = rec;
        const int sv = atomicAdd(curV + NATOM + v, 1);
        listV[sv] = su;
      }
    }
  }
}

// ---------------------------------------------------------------------------
// Precompute: hu = h@Wu, hv = h@Wv per atom (bf16 out). 16x less FLOP than
// recomputing per edge (R10/R11-verified).
// ---------------------------------------------------------------------------
__global__ __launch_bounds__(256, 2)
void pre_kernel(const unsigned short* __restrict__ h,
                const unsigned short* __restrict__ pWu, const unsigned short* __restrict__ pWv,
                unsigned short* __restrict__ hu, unsigned short* __restrict__ hv) {
  __shared__ __attribute__((aligned(16))) unsigned short sH[64][136];
  __shared__ __attribute__((aligned(16))) unsigned short sO[64][136];

  const int tid = threadIdx.x;
  const int wave = tid >> 6;
  const int lane = tid & 63;
  const int l15 = lane & 15;
  const int quad = lane >> 4;
  const int r0 = tid >> 4;
  const int ch = tid & 15;

  short8 wU[2][4], wV[2][4];
#pragma unroll
  for (int ct = 0; ct < 2; ++ct) {
#pragma unroll
    for (int kc = 0; kc < 4; ++kc) {
      const int off = (((wave * 2 + ct) * 4 + kc) * 64 + lane) * 8;
      wU[ct][kc] = *(const short8*)(pWu + off);
      wV[ct][kc] = *(const short8*)(pWv + off);
    }
  }

  const int n0 = blockIdx.x * 64;
#pragma unroll
  for (int it = 0; it < 4; ++it) {
    const int r = r0 + it * 16;
    int g = n0 + r; if (g >= NATOM) g = NATOM - 1;
    *(uint4*)(&sH[r][ch * 8]) = *(const uint4*)(h + (size_t)g * H + ch * 8);
  }
  __syncthreads();

  f32x4 au[4][2], av[4][2];
#pragma unroll
  for (int rt = 0; rt < 4; ++rt)
#pragma unroll
    for (int ct = 0; ct < 2; ++ct) {
      au[rt][ct] = (f32x4){0.f, 0.f, 0.f, 0.f};
      av[rt][ct] = (f32x4){0.f, 0.f, 0.f, 0.f};
    }
#pragma unroll
  for (int kc = 0; kc < 4; ++kc) {
#pragma unroll
    for (int rt = 0; rt < 4; ++rt) {
      const short8 a = *(const short8*)(&sH[rt * 16 + l15][kc * 32 + quad * 8]);
#pragma unroll
      for (int ct = 0; ct < 2; ++ct) {
        au[rt][ct] = MFMA16(a, wU[ct][kc], au[rt][ct]);
        av[rt][ct] = MFMA16(a, wV[ct][kc], av[rt][ct]);
      }
    }
  }
  __syncthreads();

  // hu out
#pragma unroll
  for (int rt = 0; rt < 4; ++rt) {
#pragma unroll
    for (int ct = 0; ct < 2; ++ct) {
      const int col = wave * 32 + ct * 16 + l15;
#pragma unroll
      for (int r = 0; r < 4; r += 2) {
        const int row = rt * 16 + quad * 4 + r;
        const unsigned int p = f2b2(au[rt][ct][r], au[rt][ct][r + 1]);
        sO[row][col] = (unsigned short)p;
        sO[row + 1][col] = (unsigned short)(p >> 16);
      }
    }
  }
  __syncthreads();
#pragma unroll
  for (int it = 0; it < 4; ++it) {
    const int r = r0 + it * 16;
    const int g = n0 + r;
    if (g < NATOM)
      *(uint4*)(hu + (size_t)g * H + ch * 8) = *(const uint4*)(&sO[r][ch * 8]);
  }
  __syncthreads();

  // hv out
#pragma unroll
  for (int rt = 0; rt < 4; ++rt) {
#pragma unroll
    for (int ct = 0; ct < 2; ++ct) {
      const int col = wave * 32 + ct * 16 + l15;
#pragma unroll
      for (int r = 0; r < 4; r += 2) {
        const int row = rt * 16 + quad * 4 + r;
        const unsigned int p = f2b2(av[rt][ct][r], av[rt][ct][r + 1]);
        sO[row][col] = (unsigned short)p;
        sO[row + 1][col] = (unsigned short)(p >> 16);
      }
    }
  }
  __syncthreads();
#pragma unroll
  for (int it = 0; it < 4; ++it) {
    const int r = r0 + it * 16;
    const int g = n0 + r;
    if (g < NATOM)
      *(uint4*)(hv + (size_t)g * H + ch * 8) = *(const uint4*)(&sO[r][ch * 8]);
  }
}

// ---------------------------------------------------------------------------
// Edge: ep0 gather-add + GEMM2 + GEMM3; fp8 msg with 16B/lane NT stores.
// R25: uv+dis fused into one uint2 record load per edge.
// ---------------------------------------------------------------------------
__global__ __launch_bounds__(256, 3)
void edge_kernel(const unsigned short* __restrict__ hu,
                 const unsigned short* __restrict__ hv,
                 const uint2* __restrict__ euv,
                 const unsigned short* __restrict__ pW2, const unsigned short* __restrict__ pW3,
                 const float* __restrict__ Wdis, const float* __restrict__ bb1,
                 const float* __restrict__ bb2, const float* __restrict__ bb3,
                 unsigned char* __restrict__ msg, int eBase, int nTiles) {
  __shared__ __attribute__((aligned(16))) unsigned short sA[64][136];
  __shared__ __attribute__((aligned(16))) unsigned short sB[64][136];

  const int tid = threadIdx.x;
  const int wave = tid >> 6;
  const int lane = tid & 63;
  const int l15 = lane & 15;
  const int quad = lane >> 4;
  const int r0 = tid >> 4;
  const int ch = tid & 15;

  short8 wW2[2][4], wW3[2][4];
#pragma unroll
  for (int ct = 0; ct < 2; ++ct) {
#pragma unroll
    for (int kc = 0; kc < 4; ++kc) {
      const int off = (((wave * 2 + ct) * 4 + kc) * 64 + lane) * 8;
      wW2[ct][kc] = *(const short8*)(pW2 + off);
      wW3[ct][kc] = *(const short8*)(pW3 + off);
    }
  }
  float wd8[8], b18[8];
#pragma unroll
  for (int k = 0; k < 8; ++k) { wd8[k] = Wdis[ch * 8 + k]; b18[k] = bb1[ch * 8 + k]; }
  float vb2[2], vb3[2];
#pragma unroll
  for (int ct = 0; ct < 2; ++ct) {
    const int col = wave * 32 + ct * 16 + l15;
    vb2[ct] = bb2[col]; vb3[ct] = bb3[col];
  }

  const int stride = gridDim.x;
  int tile = blockIdx.x;

  uint4 pfU[4], pfV[4];
  float pfD[4];
  if (tile < nTiles) {
    const int e0 = eBase + tile * 64;
#pragma unroll
    for (int it = 0; it < 4; ++it) {
      const uint2 r = euv[e0 + r0 + it * 16];
      pfU[it] = *(const uint4*)(hu + (size_t)(r.x & 0xFFFFu) * H + ch * 8);
      pfV[it] = *(const uint4*)(hv + (size_t)(r.x >> 16) * H + ch * 8);
      pfD[it] = __uint_as_float(r.y);
    }
  }

  for (; tile < nTiles; tile += stride) {
    // ep0: t1 = silu(hu[u] + hv[v] + dis*wd + b1) -> sA (thread-local rows)
#pragma unroll
    for (int it = 0; it < 4; ++it) {
      const int rr = r0 + it * 16;
      const float d = pfD[it];
      const unsigned int ua[4] = {pfU[it].x, pfU[it].y, pfU[it].z, pfU[it].w};
      const unsigned int va[4] = {pfV[it].x, pfV[it].y, pfV[it].z, pfV[it].w};
#pragma unroll
      for (int j = 0; j < 4; ++j) {
        const float x0 = b2f((unsigned short)ua[j]) + b2f((unsigned short)va[j]) +
                         d * wd8[2 * j] + b18[2 * j];
        const float x1 = b2f((unsigned short)(ua[j] >> 16)) + b2f((unsigned short)(va[j] >> 16)) +
                         d * wd8[2 * j + 1] + b18[2 * j + 1];
        *(unsigned int*)(&sA[rr][ch * 8 + 2 * j]) = f2b2(silu_f(x0), silu_f(x1));
      }
    }
    // issue next tile's gathers (fly during GEMM2/GEMM3)
    const int tileN = tile + stride;
    if (tileN < nTiles) {
      const int e0n = eBase + tileN * 64;
#pragma unroll
      for (int it = 0; it < 4; ++it) {
        const uint2 r = euv[e0n + r0 + it * 16];
        pfU[it] = *(const uint4*)(hu + (size_t)(r.x & 0xFFFFu) * H + ch * 8);
        pfV[it] = *(const uint4*)(hv + (size_t)(r.x >> 16) * H + ch * 8);
        pfD[it] = __uint_as_float(r.y);
      }
    }
    __syncthreads();  // b1: t1 visible

    // GEMM2: t1@W2
    f32x4 acc[4][2];
#pragma unroll
    for (int rt = 0; rt < 4; ++rt)
#pragma unroll
      for (int ct = 0; ct < 2; ++ct) acc[rt][ct] = (f32x4){0.f, 0.f, 0.f, 0.f};
#pragma unroll
    for (int kc = 0; kc < 4; ++kc) {
#pragma unroll
      for (int rt = 0; rt < 4; ++rt) {
        const short8 a = *(const short8*)(&sA[rt * 16 + l15][kc * 32 + quad * 8]);
#pragma unroll
        for (int ct = 0; ct < 2; ++ct) acc[rt][ct] = MFMA16(a, wW2[ct][kc], acc[rt][ct]);
      }
    }
    // ep2: t2 = silu(acc + b2) -> sB
#pragma unroll
    for (int rt = 0; rt < 4; ++rt) {
#pragma unroll
      for (int ct = 0; ct < 2; ++ct) {
        const int col = wave * 32 + ct * 16 + l15;
#pragma unroll
        for (int r = 0; r < 4; r += 2) {
          const int row = rt * 16 + quad * 4 + r;
          const unsigned int p = f2b2(silu_f(acc[rt][ct][r] + vb2[ct]),
                                      silu_f(acc[rt][ct][r + 1] + vb2[ct]));
          sB[row][col] = (unsigned short)p;
          sB[row + 1][col] = (unsigned short)(p >> 16);
        }
      }
    }
    __syncthreads();  // b2: t2 visible; GEMM2 reads of sA done

    // GEMM3: t2@W3
#pragma unroll
    for (int rt = 0; rt < 4; ++rt)
#pragma unroll
      for (int ct = 0; ct < 2; ++ct) acc[rt][ct] = (f32x4){0.f, 0.f, 0.f, 0.f};
#pragma unroll
    for (int kc = 0; kc < 4; ++kc) {
#pragma unroll
      for (int rt = 0; rt < 4; ++rt) {
        const short8 a = *(const short8*)(&sB[rt * 16 + l15][kc * 32 + quad * 8]);
#pragma unroll
        for (int ct = 0; ct < 2; ++ct) acc[rt][ct] = MFMA16(a, wW3[ct][kc], acc[rt][ct]);
      }
    }
    // m -> sA (bf16 staging)
#pragma unroll
    for (int rt = 0; rt < 4; ++rt) {
#pragma unroll
      for (int ct = 0; ct < 2; ++ct) {
        const int col = wave * 32 + ct * 16 + l15;
#pragma unroll
        for (int r = 0; r < 4; r += 2) {
          const int row = rt * 16 + quad * 4 + r;
          const unsigned int p = f2b2(acc[rt][ct][r] + vb3[ct],
                                      acc[rt][ct][r + 1] + vb3[ct]);
          sA[row][col] = (unsigned short)p;
          sA[row + 1][col] = (unsigned short)(p >> 16);
        }
      }
    }
    __syncthreads();  // b3: m assembled
    // cooperative fp8 stores: 16B/lane (8 threads/row; 2 x 256 threads)
#pragma unroll
    for (int it = 0; it < 2; ++it) {
      const int idx = tid + it * 256;
      const int row = idx >> 3;          // [0,64)
      const int b = (idx & 7) * 16;      // fp8 byte offset in row
      unsigned int w[8], o[4];
      *(uint4*)w       = *(const uint4*)(&sA[row][b]);
      *(uint4*)(w + 4) = *(const uint4*)(&sA[row][b + 8]);
      pack8_fp8(w, o);
      pack8_fp8(w + 4, o + 2);
      uint4n ov; ov.x = o[0]; ov.y = o[1]; ov.z = o[2]; ov.w = o[3];
      __builtin_nontemporal_store(ov,
          (uint4n*)(msg + (size_t)(tile * 64 + row) * H + b));
    }
    __syncthreads();  // b4: sA reads done before next ep0 overwrites
  }
}

// ---------------------------------------------------------------------------
// Aggregate (nc=1, fp8 msg): u-half streams contiguous 128B rows; v-half
// NT-gathers. Each lane owns 2 cols (2 fp8 bytes/row). Accum f32.
// ---------------------------------------------------------------------------
__global__ __launch_bounds__(256)
void aggregate_kernel(const int* __restrict__ startU, const int* __restrict__ startV,
                      const int* __restrict__ listV,
                      const unsigned char* __restrict__ msg, int eBase, int cellBase,
                      unsigned short* __restrict__ aout) {
  const int atom = blockIdx.x * 4 + (threadIdx.x >> 6);
  const int lane = threadIdx.x & 63;
  const int su = startU[cellBase + atom] - eBase;
  const int eu = startU[cellBase + atom + 1] - eBase;
  const int sv = startV[cellBase + atom];
  const int ev = startV[cellBase + atom + 1];
  float ax = 0.f, ay = 0.f;
  const unsigned char* mp = msg + lane * 2;

  // contiguous u-half: 4 rows in flight
  int p = su;
  for (; p + 3 < eu; p += 4) {
    unsigned short s[4];
#pragma unroll
    for (int j = 0; j < 4; ++j) s[j] = *(const unsigned short*)(mp + (size_t)(p + j) * H);
#pragma unroll
    for (int j = 0; j < 4; ++j) {
      float x, y; unpack2_fp8(s[j], x, y);
      ax += x; ay += y;
    }
  }
  for (; p < eu; ++p) {
    const unsigned short s0 = *(const unsigned short*)(mp + (size_t)p * H);
    float x, y; unpack2_fp8(s0, x, y);
    ax += x; ay += y;
  }

  // random v-half: 8-deep NT gather
  int i = sv;
  for (; i + 7 < ev; i += 8) {
    int r[8];
#pragma unroll
    for (int j = 0; j < 8; ++j) r[j] = __builtin_nontemporal_load(listV + i + j) - eBase;
    unsigned short s[8];
#pragma unroll
    for (int j = 0; j < 8; ++j)
      s[j] = __builtin_nontemporal_load((const unsigned short*)(mp + (size_t)r[j] * H));
#pragma unroll
    for (int j = 0; j < 8; ++j) {
      float x, y; unpack2_fp8(s[j], x, y);
      ax += x; ay += y;
    }
  }
  for (; i < ev; ++i) {
    const int r = __builtin_nontemporal_load(listV + i) - eBase;
    const unsigned short s0 =
        __builtin_nontemporal_load((const unsigned short*)(mp + (size_t)r * H));
    float x, y; unpack2_fp8(s0, x, y);
    ax += x; ay += y;
  }

  *(unsigned int*)(aout + (size_t)atom * H + lane * 2) = f2b2(ax, ay);
}

// ---------------------------------------------------------------------------
// Atom update: h_new = h + silu(h@Wh + a1@Wa1 + a2@Wa2 + b1)@W2 + b2
// ---------------------------------------------------------------------------
__global__ __launch_bounds__(256, 2)
void update_kernel(const unsigned short* __restrict__ hin,
                   const unsigned short* __restrict__ a1, const unsigned short* __restrict__ a2,
                   const unsigned short* __restrict__ pWh, const unsigned short* __restrict__ pWa1,
                   const unsigned short* __restrict__ pWa2, const unsigned short* __restrict__ pWo,
                   const float* __restrict__ b1, const float* __restrict__ b2,
                   unsigned short* __restrict__ hout) {
  __shared__ __attribute__((aligned(16))) unsigned short sH[64][136];
  __shared__ __attribute__((aligned(16))) unsigned short s1[64][136];
  __shared__ __attribute__((aligned(16))) unsigned short s2[64][136];

  const int tid = threadIdx.x;
  const int wave = tid >> 6;
  const int lane = tid & 63;
  const int l15 = lane & 15;
  const int quad = lane >> 4;

  short8 wWh[2][4], wW1[2][4], wW2m[2][4], wWo[2][4];
#pragma unroll
  for (int ct = 0; ct < 2; ++ct) {
#pragma unroll
    for (int kc = 0; kc < 4; ++kc) {
      const int off = (((wave * 2 + ct) * 4 + kc) * 64 + lane) * 8;
      wWh[ct][kc] = *(const short8*)(pWh + off);
      wW1[ct][kc] = *(const short8*)(pWa1 + off);
      wW2m[ct][kc] = *(const short8*)(pWa2 + off);
      wWo[ct][kc] = *(const short8*)(pWo + off);
    }
  }
  float vb1[2], vb2[2];
#pragma unroll
  for (int ct = 0; ct < 2; ++ct) {
    const int col = wave * 32 + ct * 16 + l15;
    vb1[ct] = b1[col]; vb2[ct] = b2[col];
  }

  const int n0 = blockIdx.x * 64;
#pragma unroll
  for (int it = 0; it < 4; ++it) {
    const int r = (tid >> 4) + it * 16;
    const int ch = tid & 15;
    int g = n0 + r; if (g >= NATOM) g = NATOM - 1;
    *(uint4*)(&sH[r][ch * 8]) = *(const uint4*)(hin + (size_t)g * H + ch * 8);
    *(uint4*)(&s1[r][ch * 8]) = *(const uint4*)(a1 + (size_t)g * H + ch * 8);
    *(uint4*)(&s2[r][ch * 8]) = *(const uint4*)(a2 + (size_t)g * H + ch * 8);
  }
  __syncthreads();

  f32x4 acc[4][2];
#pragma unroll
  for (int rt = 0; rt < 4; ++rt)
#pragma unroll
    for (int ct = 0; ct < 2; ++ct) acc[rt][ct] = (f32x4){0.f, 0.f, 0.f, 0.f};

#pragma unroll
  for (int kc = 0; kc < 4; ++kc) {
#pragma unroll
    for (int rt = 0; rt < 4; ++rt) {
      const short8 ah = *(const short8*)(&sH[rt * 16 + l15][kc * 32 + quad * 8]);
      const short8 aa1 = *(const short8*)(&s1[rt * 16 + l15][kc * 32 + quad * 8]);
      const short8 aa2 = *(const short8*)(&s2[rt * 16 + l15][kc * 32 + quad * 8]);
#pragma unroll
      for (int ct = 0; ct < 2; ++ct) {
        acc[rt][ct] = MFMA16(ah, wWh[ct][kc], acc[rt][ct]);
        acc[rt][ct] = MFMA16(aa1, wW1[ct][kc], acc[rt][ct]);
        acc[rt][ct] = MFMA16(aa2, wW2m[ct][kc], acc[rt][ct]);
      }
    }
  }
  __syncthreads();

#pragma unroll
  for (int rt = 0; rt < 4; ++rt) {
#pragma unroll
    for (int ct = 0; ct < 2; ++ct) {
      const int col = wave * 32 + ct * 16 + l15;
#pragma unroll
      for (int r = 0; r < 4; r += 2) {
        const int row = rt * 16 + quad * 4 + r;
        const unsigned int p = f2b2(silu_f(acc[rt][ct][r] + vb1[ct]),
                                    silu_f(acc[rt][ct][r + 1] + vb1[ct]));
        s1[row][col] = (unsigned short)p;
        s1[row + 1][col] = (unsigned short)(p >> 16);
      }
    }
  }
  __syncthreads();

#pragma unroll
  for (int rt = 0; rt < 4; ++rt)
#pragma unroll
    for (int ct = 0; ct < 2; ++ct) acc[rt][ct] = (f32x4){0.f, 0.f, 0.f, 0.f};
#pragma unroll
  for (int kc = 0; kc < 4; ++kc) {
#pragma unroll
    for (int rt = 0; rt < 4; ++rt) {
      const short8 a = *(const short8*)(&s1[rt * 16 + l15][kc * 32 + quad * 8]);
#pragma unroll
      for (int ct = 0; ct < 2; ++ct) acc[rt][ct] = MFMA16(a, wWo[ct][kc], acc[rt][ct]);
    }
  }
  __syncthreads();
#pragma unroll
  for (int rt = 0; rt < 4; ++rt) {
#pragma unroll
    for (int ct = 0; ct < 2; ++ct) {
      const int col = wave * 32 + ct * 16 + l15;
#pragma unroll
      for (int r = 0; r < 4; r += 2) {
        const int row = rt * 16 + quad * 4 + r;
        const float v0 = b2f(sH[row][col]) + acc[rt][ct][r] + vb2[ct];
        const float v1 = b2f(sH[row + 1][col]) + acc[rt][ct][r + 1] + vb2[ct];
        const unsigned int p = f2b2(v0, v1);
        s2[row][col] = (unsigned short)p;
        s2[row + 1][col] = (unsigned short)(p >> 16);
      }
    }
  }
  __syncthreads();
#pragma unroll
  for (int it = 0; it < 4; ++it) {
    const int r = (tid >> 4) + it * 16;
    const int ch = tid & 15;
    const int g = n0 + r;
    if (g < NATOM)
      *(uint4*)(hout + (size_t)g * H + ch * 8) = *(const uint4*)(&s2[r][ch * 8]);
  }
}

// ---------------------------------------------------------------------------
__global__ void out_kernel(const unsigned short* __restrict__ h,
                           const float* __restrict__ outW, const float* __restrict__ outb,
                           float* __restrict__ out) {
  const int atom = blockIdx.x * 4 + (threadIdx.x >> 6);
  const int lane = threadIdx.x & 63;
  float s0 = 0.f, s1 = 0.f, s2 = 0.f;
#pragma unroll
  for (int kk = 0; kk < 2; ++kk) {
    const int k = lane + kk * 64;
    const float hv = b2f(h[(size_t)atom * H + k]);
    s0 += hv * outW[k * 3 + 0];
    s1 += hv * outW[k * 3 + 1];
    s2 += hv * outW[k * 3 + 2];
  }
#pragma unroll
  for (int off = 32; off > 0; off >>= 1) {
    s0 += __shfl_down(s0, off);
    s1 += __shfl_down(s1, off);
    s2 += __shfl_down(s2, off);
  }
  if (lane == 0) {
    out[atom * 3 + 0] = s0 + outb[0];
    out[atom * 3 + 1] = s1 + outb[1];
    out[atom * 3 + 2] = s2 + outb[2];
  }
}

// ---------------------------------------------------------------------------
// Workspace (nc=1, fp8 msg, euv records): pw 0.79 + h0/a1/a2 38.4 + hu/hv
// 25.6 + euv 12.8 + listV 6.4 + startU/V 0.8 + msg(fp8) 102.4 = 187.2MB.
// ---------------------------------------------------------------------------
extern "C" void kernel_launch(void* const* d_in, const int* in_sizes, int n_in,
                              void* d_out, int out_size, void* d_ws, size_t ws_size,
                              hipStream_t stream) {
  const int* atom_num = (const int*)d_in[0];
  const float* dis1 = (const float*)d_in[1];
  const float* dis2 = (const float*)d_in[2];
  const int* id1u = (const int*)d_in[3];
  const int* id1v = (const int*)d_in[4];
  const int* id2u = (const int*)d_in[5];
  const int* id2v = (const int*)d_in[6];
  const float* emb = (const float*)d_in[7];
  const float* Wu = (const float*)d_in[8];
  const float* Wv = (const float*)d_in[9];
  const float* Wdis = (const float*)d_in[10];
  const float* eb1 = (const float*)d_in[11];
  const float* eW2 = (const float*)d_in[12];
  const float* eb2 = (const float*)d_in[13];
  const float* eW3 = (const float*)d_in[14];
  const float* eb3 = (const float*)d_in[15];
  const float* Wh = (const float*)d_in[16];
  const float* Wa1 = (const float*)d_in[17];
  const float* Wa2 = (const float*)d_in[18];
  const float* ub1 = (const float*)d_in[19];
  const float* uW2 = (const float*)d_in[20];
  const float* ub2 = (const float*)d_in[21];
  const float* outW = (const float*)d_in[22];
  const float* outb = (const float*)d_in[23];

  auto pad = [](size_t x) { return (x + 255) & ~(size_t)255; };
  const int N2 = 2 * NATOM;
  const int nparts = (N2 + 1023) / 1024;

  char* ws = (char*)d_ws;
  size_t off = 0;
  auto take = [&](size_t bytes) { char* p = ws + off; off += pad(bytes); return p; };
  unsigned short* pw   = (unsigned short*)take(786432);
  unsigned short* h0   = (unsigned short*)take((size_t)NATOM * H * 2);
  unsigned short* a1   = (unsigned short*)take((size_t)NATOM * H * 2);
  unsigned short* a2   = (unsigned short*)take((size_t)NATOM * H * 2);
  unsigned short* hu   = (unsigned short*)take((size_t)NATOM * H * 2);
  unsigned short* hv   = (unsigned short*)take((size_t)NATOM * H * 2);
  uint2* euv           = (uint2*)take((size_t)2 * NEDGE * 8);  // (u|v<<16, dis)
  int* listV           = (int*)take((size_t)2 * NEDGE * 4);
  int* startU          = (int*)take(((size_t)N2 + 1) * 4);
  int* startV          = (int*)take(((size_t)N2 + 1) * 4);
  char* ovlRegion      = ws + off;  // fp8 msg, overlapped with CSR scratch
  unsigned char* msg   = (unsigned char*)ovlRegion;           // E*128B = 102.4MB
  int* degU            = (int*)ovlRegion;
  int* degV            = degU + N2;
  int* curU            = degV + N2;
  int* curV            = curU + N2;
  int* partU           = curV + N2;
  int* partV           = partU + 1024;

  PackSrc ps;
  for (int i = 0; i < 4; ++i) {
    ps.p[i] = Wu + i * 16384;
    ps.p[4 + i] = Wv + i * 16384;
    ps.p[8 + i] = eW2 + i * 16384;
    ps.p[12 + i] = eW3 + i * 16384;
  }
  for (int j = 0; j < 2; ++j) {
    ps.p[16 + j] = Wh + j * 16384;
    ps.p[18 + j] = Wa1 + j * 16384;
    ps.p[20 + j] = Wa2 + j * 16384;
    ps.p[22 + j] = uW2 + j * 16384;
  }
  repack_kernel<<<24, 256, 0, stream>>>(ps, pw);
  embed_kernel<<<12500, 256, 0, stream>>>(atom_num, emb, h0);

  // CSR build (u-sorted positions + v-side position lists, fused fill)
  {
    const int n4 = (int)(((size_t)2 * N2 * 4 + 15) / 16);
    zero_int_kernel<<<(n4 + 255) / 256, 256, 0, stream>>>((int4*)degU, n4);
    count_kernel<<<NEDGE / 256, 256, 0, stream>>>(id1u, id1v, id2u, id2v, degU, degV);
    scan_phase1<<<nparts, 256, 0, stream>>>(degU, partU, N2);
    scan_phase2<<<1, 1024, 0, stream>>>(partU, nparts);
    scan_phase3<<<nparts, 256, 0, stream>>>(degU, partU, startU, curU, N2);
    scan_phase1<<<nparts, 256, 0, stream>>>(degV, partV, N2);
    scan_phase2<<<1, 1024, 0, stream>>>(partV, nparts);
    scan_phase3<<<nparts, 256, 0, stream>>>(degV, partV, startV, curV, N2);
    fill_fused_kernel<<<1024, 256, 0, stream>>>(id1u, id1v, dis1, id2u, id2v, dis2,
                                                curU, curV, euv, listV, 4);
  }

  const int upd_grid = (NATOM + 63) / 64;   // 782
  const int AGG_GRID = NATOM / 4;
  const int nTiles = NEDGE / 64;            // 12500
  const int EDGE_GRID = 768;                // 3 blocks/CU

  const unsigned short* pWu_[4] = {pw, pw + 16384, pw + 2 * 16384, pw + 3 * 16384};
  const unsigned short* pWv_[4] = {pw + 4 * 16384, pw + 5 * 16384, pw + 6 * 16384, pw + 7 * 16384};
  const unsigned short* pW2_[4] = {pw + 8 * 16384, pw + 9 * 16384, pw + 10 * 16384, pw + 11 * 16384};
  const unsigned short* pW3_[4] = {pw + 12 * 16384, pw + 13 * 16384, pw + 14 * 16384, pw + 15 * 16384};

  for (int layer = 0; layer < 2; ++layer) {
    for (int set = 0; set < 2; ++set) {
      const int blk = layer * 2 + set;
      const int eBase = set * NEDGE;
      const int cellBase = set * NATOM;
      unsigned short* aout = set == 0 ? a1 : a2;
      pre_kernel<<<upd_grid, 256, 0, stream>>>(h0, pWu_[blk], pWv_[blk], hu, hv);
      edge_kernel<<<EDGE_GRID, 256, 0, stream>>>(hu, hv, euv,
          pW2_[blk], pW3_[blk],
          Wdis + blk * H, eb1 + blk * H, eb2 + blk * H, eb3 + blk * H,
          msg, eBase, nTiles);
      aggregate_kernel<<<AGG_GRID, 256, 0, stream>>>(startU, startV, listV, msg,
          eBase, cellBase, aout);
    }
    update_kernel<<<upd_grid, 256, 0, stream>>>(h0, a1, a2,
        pw + (16 + layer) * 16384, pw + (18 + layer) * 16384,
        pw + (20 + layer) * 16384, pw + (22 + layer) * 16384,
        ub1 + layer * H, ub2 + layer * H, h0);
  }

  out_kernel<<<12500, 256, 0, stream>>>(h0, outW, outb, (float*)d_out);
}